// Round 1
// baseline (629.356 us; speedup 1.0000x reference)
//
#include <hip/hip_runtime.h>

#define EPSF 1e-7f

// ---------------- c_sq[k] = sum_d C[k][d]^2 ----------------
__global__ __launch_bounds__(256) void csq_kernel(const float* __restrict__ C,
                                                  float* __restrict__ csq) {
    const int wave = threadIdx.x >> 6, lane = threadIdx.x & 63;
    const int row = blockIdx.x * 4 + wave;            // 128 blocks -> 512 rows
    const float* p = C + row * 512 + lane * 8;
    float4 a = *(const float4*)p;
    float4 b = *(const float4*)(p + 4);
    float s = a.x * a.x + a.y * a.y + a.z * a.z + a.w * a.w +
              b.x * b.x + b.y * b.y + b.z * b.z + b.w * b.w;
#pragma unroll
    for (int off = 1; off < 64; off <<= 1) s += __shfl_xor(s, off, 64);
    if (lane == 0) csq[row] = s;
}

// ---------------- logits L[n][k] = 2*(X@C^T)[n][k] - c_sq[k] ----------------
// M=32768, N=512, Kdim=512. Tiles 64x64x16, 256 threads, 4x4 microtile.
__global__ __launch_bounds__(256) void gemm_logits(const float* __restrict__ X,
                                                   const float* __restrict__ C,
                                                   const float* __restrict__ csq,
                                                   float* __restrict__ L) {
    __shared__ float As[16][64];   // [kk][m]
    __shared__ float Bs[16][64];   // [kk][n]
    const int tid = threadIdx.x;
    const int tx = tid & 15, ty = tid >> 4;
    const int lrow = tid >> 2;            // 0..63
    const int lcol = (tid & 3) << 2;      // 0,4,8,12
    const int m0 = blockIdx.x * 64;
    const int n0 = blockIdx.y * 64;
    const float* xg = X + (long)(m0 + lrow) * 512 + lcol;
    const float* cg = C + (long)(n0 + lrow) * 512 + lcol;
    float acc[4][4] = {};
    for (int k0 = 0; k0 < 512; k0 += 16) {
        float4 av = *(const float4*)(xg + k0);
        float4 bv = *(const float4*)(cg + k0);
        __syncthreads();
        As[lcol + 0][lrow] = av.x;
        As[lcol + 1][lrow] = av.y;
        As[lcol + 2][lrow] = av.z;
        As[lcol + 3][lrow] = av.w;
        Bs[lcol + 0][lrow] = bv.x;
        Bs[lcol + 1][lrow] = bv.y;
        Bs[lcol + 2][lrow] = bv.z;
        Bs[lcol + 3][lrow] = bv.w;
        __syncthreads();
#pragma unroll
        for (int kk = 0; kk < 16; ++kk) {
            float4 a = *(const float4*)&As[kk][ty << 2];
            float4 b = *(const float4*)&Bs[kk][tx << 2];
            float aa[4] = {a.x, a.y, a.z, a.w};
            float bb[4] = {b.x, b.y, b.z, b.w};
#pragma unroll
            for (int i = 0; i < 4; ++i)
#pragma unroll
                for (int j = 0; j < 4; ++j) acc[i][j] += aa[i] * bb[j];
        }
    }
    float cs[4];
#pragma unroll
    for (int j = 0; j < 4; ++j) cs[j] = csq[n0 + (tx << 2) + j];
#pragma unroll
    for (int i = 0; i < 4; ++i) {
        float4 o;
        o.x = 2.f * acc[i][0] - cs[0];
        o.y = 2.f * acc[i][1] - cs[1];
        o.z = 2.f * acc[i][2] - cs[2];
        o.w = 2.f * acc[i][3] - cs[3];
        *(float4*)(L + (long)(m0 + (ty << 2) + i) * 512 + n0 + (tx << 2)) = o;
    }
}

// ---------------- in-place row softmax (scale 1/T=10) + sum_w accumulation ----------------
__global__ __launch_bounds__(256) void softmax_rows(float* __restrict__ L,
                                                    float* __restrict__ sum_w) {
    __shared__ float swacc[512];
    const int tid = threadIdx.x;
    for (int i = tid; i < 512; i += 256) swacc[i] = 0.f;
    __syncthreads();
    const int wave = tid >> 6, lane = tid & 63;
    float racc[8] = {};
    for (int r = blockIdx.x * 4 + wave; r < 32768; r += 2048) {
        float* p = L + (long)r * 512 + lane * 8;
        float4 v0 = *(float4*)p;
        float4 v1 = *(float4*)(p + 4);
        float v[8] = {v0.x, v0.y, v0.z, v0.w, v1.x, v1.y, v1.z, v1.w};
        float m = v[0];
#pragma unroll
        for (int i = 1; i < 8; ++i) m = fmaxf(m, v[i]);
#pragma unroll
        for (int off = 1; off < 64; off <<= 1) m = fmaxf(m, __shfl_xor(m, off, 64));
        float e[8], s = 0.f;
#pragma unroll
        for (int i = 0; i < 8; ++i) {
            e[i] = expf((v[i] - m) * 10.0f);
            s += e[i];
        }
#pragma unroll
        for (int off = 1; off < 64; off <<= 1) s += __shfl_xor(s, off, 64);
        const float inv = 1.0f / (s + EPSF);
#pragma unroll
        for (int i = 0; i < 8; ++i) {
            e[i] *= inv;
            racc[i] += e[i];
        }
        float4 o0 = {e[0], e[1], e[2], e[3]};
        float4 o1 = {e[4], e[5], e[6], e[7]};
        *(float4*)p = o0;
        *(float4*)(p + 4) = o1;
    }
#pragma unroll
    for (int i = 0; i < 8; ++i) atomicAdd(&swacc[lane * 8 + i], racc[i]);
    __syncthreads();
    for (int i = tid; i < 512; i += 256) atomicAdd(&sum_w[i], swacc[i]);
}

// ---------------- WS[k][d] = sum_n A[n][k] * X[n][d] (split-N + atomics) ----------------
__global__ __launch_bounds__(256) void gemm_wsum(const float* __restrict__ A,
                                                 const float* __restrict__ X,
                                                 float* __restrict__ WS) {
    __shared__ float As[16][64];   // [nn][k]
    __shared__ float Xs[16][64];   // [nn][d]
    const int tid = threadIdx.x;
    const int tx = tid & 15, ty = tid >> 4;
    const int lrow = tid >> 4;            // 0..15 (n within chunk)
    const int lcol = (tid & 15) << 2;     // 0..60
    const int k0 = blockIdx.x * 64;
    const int d0 = blockIdx.y * 64;
    const int n0 = blockIdx.z * 1024;
    float acc[4][4] = {};
    for (int nc = 0; nc < 1024; nc += 16) {
        const long nrow = n0 + nc + lrow;
        float4 av = *(const float4*)(A + nrow * 512 + k0 + lcol);
        float4 xv = *(const float4*)(X + nrow * 512 + d0 + lcol);
        __syncthreads();
        *(float4*)&As[lrow][lcol] = av;
        *(float4*)&Xs[lrow][lcol] = xv;
        __syncthreads();
#pragma unroll
        for (int nn = 0; nn < 16; ++nn) {
            float4 a = *(const float4*)&As[nn][ty << 2];
            float4 x = *(const float4*)&Xs[nn][tx << 2];
            float aa[4] = {a.x, a.y, a.z, a.w};
            float xx[4] = {x.x, x.y, x.z, x.w};
#pragma unroll
            for (int i = 0; i < 4; ++i)
#pragma unroll
                for (int j = 0; j < 4; ++j) acc[i][j] += aa[i] * xx[j];
        }
    }
#pragma unroll
    for (int i = 0; i < 4; ++i)
#pragma unroll
        for (int j = 0; j < 4; ++j)
            atomicAdd(&WS[(k0 + (ty << 2) + i) * 512 + d0 + (tx << 2) + j], acc[i][j]);
}

// ---------------- repulsion + momentum update ----------------
__global__ __launch_bounds__(256) void repulse_update(const float* __restrict__ Cent,
                                                      const float* __restrict__ Mom,
                                                      const float* __restrict__ csq,
                                                      const float* __restrict__ WS,
                                                      const float* __restrict__ sum_w,
                                                      float* __restrict__ outC,
                                                      float* __restrict__ outM) {
    const int i = blockIdx.x;
    __shared__ float ci[512];
    __shared__ float rep[512];
    const int tid = threadIdx.x, wave = tid >> 6, lane = tid & 63;
    for (int d = tid; d < 512; d += 256) {
        ci[d] = Cent[i * 512 + d];
        rep[d] = 0.f;
    }
    __syncthreads();
    float cil[8];
#pragma unroll
    for (int m = 0; m < 8; ++m) cil[m] = ci[lane * 8 + m];
    const float csqi = csq[i];
    float racc[8] = {};
    for (int j = wave; j < 512; j += 4) {
        if (j == i) continue;  // wave-uniform; diagonal contributes exactly 0 in reference
        const float* cj = Cent + j * 512 + lane * 8;
        float4 c0 = *(const float4*)cj;
        float4 c1 = *(const float4*)(cj + 4);
        float cjl[8] = {c0.x, c0.y, c0.z, c0.w, c1.x, c1.y, c1.z, c1.w};
        float dot = 0.f;
#pragma unroll
        for (int m = 0; m < 8; ++m) dot += cil[m] * cjl[m];
#pragma unroll
        for (int off = 1; off < 64; off <<= 1) dot += __shfl_xor(dot, off, 64);
        float sq = csqi + csq[j] - 2.f * dot;
        float dist = sqrtf(fmaxf(sq, 0.f) + EPSF);   // clamp: identity-form sq can go slightly negative
        float w = fmaxf(0.f, 1.f - dist);            // MIN_DISTANCE = 1
        float scale = 0.1f * w / (dist + EPSF);      // REPULSION_STRENGTH = 0.1
#pragma unroll
        for (int m = 0; m < 8; ++m) racc[m] += scale * (cil[m] - cjl[m]);
    }
#pragma unroll
    for (int m = 0; m < 8; ++m) atomicAdd(&rep[lane * 8 + m], racc[m]);
    __syncthreads();
    const float invw = 1.0f / (sum_w[i] + EPSF);
    for (int d = tid; d < 512; d += 256) {
        float nc = WS[i * 512 + d] * invw;
        float upd = nc - ci[d] + rep[d];
        float mn = 0.9f * Mom[i * 512 + d] + 0.1f * upd;  // MOMENTUM=0.9
        outM[i * 512 + d] = mn;
        outC[i * 512 + d] = ci[d] + 0.1f * mn;            // CENTROID_LR=0.1
    }
}

extern "C" void kernel_launch(void* const* d_in, const int* in_sizes, int n_in,
                              void* d_out, int out_size, void* d_ws, size_t ws_size,
                              hipStream_t stream) {
    const float* X = (const float*)d_in[0];      // (32768, 512)
    const float* C = (const float*)d_in[1];      // (512, 512)
    const float* M = (const float*)d_in[2];      // (512, 512)
    float* out = (float*)d_out;
    float* assign = out;                          // 32768*512
    float* outC = out + 16777216;                 // 512*512
    float* outM = outC + 262144;                  // 512*512
    float* ws = (float*)d_ws;
    float* WS = ws;                               // 262144 floats
    float* sum_w = ws + 262144;                   // 512
    float* csq = ws + 262656;                     // 512

    // zero the atomic accumulators (ws is poisoned, not re-zeroed between replays)
    hipMemsetAsync(d_ws, 0, (262144 + 512) * sizeof(float), stream);

    csq_kernel<<<128, 256, 0, stream>>>(C, csq);
    gemm_logits<<<dim3(512, 8), 256, 0, stream>>>(X, C, csq, assign);
    softmax_rows<<<512, 256, 0, stream>>>(assign, sum_w);
    gemm_wsum<<<dim3(8, 8, 32), 256, 0, stream>>>(assign, X, WS);
    repulse_update<<<512, 256, 0, stream>>>(C, M, csq, WS, sum_w, outC, outM);
}

// Round 2
// 536.941 us; speedup vs baseline: 1.1721x; 1.1721x over previous
//
#include <hip/hip_runtime.h>
#include <hip/hip_bf16.h>

#define EPSF 1e-7f

typedef __attribute__((ext_vector_type(8))) short bf16x8;
typedef __attribute__((ext_vector_type(4))) float f32x4v;

__device__ inline ushort f2bf_bits(float x) {
    union { __hip_bfloat16 b; ushort u; } cv;
    cv.b = __float2bfloat16(x);
    return cv.u;
}
__device__ inline float bfbits2f(ushort u) {
    union { ushort u; __hip_bfloat16 b; } cv;
    cv.u = u;
    return __bfloat162float(cv.b);
}
__device__ inline void split2(float x, ushort& h, ushort& l) {
    h = f2bf_bits(x);
    l = f2bf_bits(x - bfbits2f(h));
}

// ---------------- c_sq[k] = sum_d C[k][d]^2 ----------------
__global__ __launch_bounds__(256) void csq_kernel(const float* __restrict__ C,
                                                  float* __restrict__ csq) {
    const int wave = threadIdx.x >> 6, lane = threadIdx.x & 63;
    const int row = blockIdx.x * 4 + wave;
    const float* p = C + row * 512 + lane * 8;
    float4 a = *(const float4*)p;
    float4 b = *(const float4*)(p + 4);
    float s = a.x * a.x + a.y * a.y + a.z * a.z + a.w * a.w +
              b.x * b.x + b.y * b.y + b.z * b.z + b.w * b.w;
#pragma unroll
    for (int off = 1; off < 64; off <<= 1) s += __shfl_xor(s, off, 64);
    if (lane == 0) csq[row] = s;
}

// ---------------- logits via split-bf16 MFMA ----------------
// L[n][k] = 2*(X@C^T)[n][k] - c_sq[k].  M=32768, N=512, K=512.
// Tile BM=128, BN=128, BK=64. 256 thr = 4 waves (2x2), each 64x64 out.
// cross = xh*ch + xh*cl + xl*ch  (drops lo*lo ~ 2^-18 rel).
__global__ __launch_bounds__(256) void logits_mfma(const float* __restrict__ X,
                                                   const float* __restrict__ Cm,
                                                   const float* __restrict__ csq,
                                                   float* __restrict__ L) {
    __shared__ ushort sAh[128][64];
    __shared__ ushort sAl[128][64];
    __shared__ ushort sBh[128][64];
    __shared__ ushort sBl[128][64];
    const int tid = threadIdx.x;
    const int m0 = blockIdx.x * 128;
    const int n0 = blockIdx.y * 128;
    const int wid = tid >> 6, lane = tid & 63;
    const int wm = wid >> 1, wn = wid & 1;
    const int lrow = lane & 15;   // row/col within 16x16 frag
    const int lkb = lane >> 4;    // k-block 0..3 (8 elems each)
    f32x4v acc[4][4] = {};

    for (int k0 = 0; k0 < 512; k0 += 64) {
        __syncthreads();
        // stage + convert fp32 -> bf16 hi/lo, XOR-swizzled rows (128B row, ((r&7)<<4) byte-XOR)
#pragma unroll
        for (int s = 0; s < 8; ++s) {
            const int idx = s * 256 + tid;          // 0..2047 float4-slots
            const int r = idx >> 4;                 // 0..127
            const int c4 = (idx & 15) << 2;         // k-elem offset 0..60
            const int e = c4 ^ ((r & 7) << 3);      // swizzled elem offset
            float4 va = *(const float4*)(X + (long)(m0 + r) * 512 + k0 + c4);
            ushort4 hh, ll;
            split2(va.x, hh.x, ll.x);
            split2(va.y, hh.y, ll.y);
            split2(va.z, hh.z, ll.z);
            split2(va.w, hh.w, ll.w);
            *(ushort4*)&sAh[r][e] = hh;
            *(ushort4*)&sAl[r][e] = ll;
            float4 vb = *(const float4*)(Cm + (long)(n0 + r) * 512 + k0 + c4);
            split2(vb.x, hh.x, ll.x);
            split2(vb.y, hh.y, ll.y);
            split2(vb.z, hh.z, ll.z);
            split2(vb.w, hh.w, ll.w);
            *(ushort4*)&sBh[r][e] = hh;
            *(ushort4*)&sBl[r][e] = ll;
        }
        __syncthreads();
#pragma unroll
        for (int kk = 0; kk < 2; ++kk) {
            const int ebase = kk * 32 + lkb * 8;
            bf16x8 ah[4], al[4], bh[4], bl[4];
#pragma unroll
            for (int mi = 0; mi < 4; ++mi) {
                const int R = wm * 64 + mi * 16 + lrow;
                const int e = ebase ^ ((R & 7) << 3);
                ah[mi] = *(const bf16x8*)&sAh[R][e];
                al[mi] = *(const bf16x8*)&sAl[R][e];
            }
#pragma unroll
            for (int ni = 0; ni < 4; ++ni) {
                const int Rn = wn * 64 + ni * 16 + lrow;
                const int e = ebase ^ ((Rn & 7) << 3);
                bh[ni] = *(const bf16x8*)&sBh[Rn][e];
                bl[ni] = *(const bf16x8*)&sBl[Rn][e];
            }
#pragma unroll
            for (int mi = 0; mi < 4; ++mi)
#pragma unroll
                for (int ni = 0; ni < 4; ++ni) {
                    acc[mi][ni] = __builtin_amdgcn_mfma_f32_16x16x32_bf16(ah[mi], bh[ni], acc[mi][ni], 0, 0, 0);
                    acc[mi][ni] = __builtin_amdgcn_mfma_f32_16x16x32_bf16(ah[mi], bl[ni], acc[mi][ni], 0, 0, 0);
                    acc[mi][ni] = __builtin_amdgcn_mfma_f32_16x16x32_bf16(al[mi], bh[ni], acc[mi][ni], 0, 0, 0);
                }
        }
    }
    // epilogue: C/D map col=lane&15, row=(lane>>4)*4+reg
    const int colb = n0 + wn * 64 + lrow;
    float cs[4];
#pragma unroll
    for (int ni = 0; ni < 4; ++ni) cs[ni] = csq[colb + ni * 16];
#pragma unroll
    for (int mi = 0; mi < 4; ++mi) {
        const int rowb = m0 + wm * 64 + mi * 16 + lkb * 4;
#pragma unroll
        for (int r = 0; r < 4; ++r) {
            float* Lp = L + (long)(rowb + r) * 512 + colb;
#pragma unroll
            for (int ni = 0; ni < 4; ++ni)
                Lp[ni * 16] = 2.0f * acc[mi][ni][r] - cs[ni];
        }
    }
}

// ---------------- in-place row softmax (scale 1/T=10) + sum_w ----------------
__global__ __launch_bounds__(256) void softmax_rows(float* __restrict__ L,
                                                    float* __restrict__ sum_w) {
    __shared__ float swacc[512];
    const int tid = threadIdx.x;
    for (int i = tid; i < 512; i += 256) swacc[i] = 0.f;
    __syncthreads();
    const int wave = tid >> 6, lane = tid & 63;
    float racc[8] = {};
    for (int r = blockIdx.x * 4 + wave; r < 32768; r += 2048) {
        float* p = L + (long)r * 512 + lane * 8;
        float4 v0 = *(float4*)p;
        float4 v1 = *(float4*)(p + 4);
        float v[8] = {v0.x, v0.y, v0.z, v0.w, v1.x, v1.y, v1.z, v1.w};
        float m = v[0];
#pragma unroll
        for (int i = 1; i < 8; ++i) m = fmaxf(m, v[i]);
#pragma unroll
        for (int off = 1; off < 64; off <<= 1) m = fmaxf(m, __shfl_xor(m, off, 64));
        float e[8], s = 0.f;
#pragma unroll
        for (int i = 0; i < 8; ++i) {
            e[i] = expf((v[i] - m) * 10.0f);
            s += e[i];
        }
#pragma unroll
        for (int off = 1; off < 64; off <<= 1) s += __shfl_xor(s, off, 64);
        const float inv = 1.0f / (s + EPSF);
#pragma unroll
        for (int i = 0; i < 8; ++i) {
            e[i] *= inv;
            racc[i] += e[i];
        }
        float4 o0 = {e[0], e[1], e[2], e[3]};
        float4 o1 = {e[4], e[5], e[6], e[7]};
        *(float4*)p = o0;
        *(float4*)(p + 4) = o1;
    }
#pragma unroll
    for (int i = 0; i < 8; ++i) atomicAdd(&swacc[lane * 8 + i], racc[i]);
    __syncthreads();
    for (int i = tid; i < 512; i += 256) atomicAdd(&sum_w[i], swacc[i]);
}

// ---------------- WS[k][d] = sum_n A[n][k]*X[n][d]  (fp32 VALU, 128x128 tile, 8x8 micro) ----
__global__ __launch_bounds__(256) void gemm_wsum_f32(const float* __restrict__ A,
                                                     const float* __restrict__ X,
                                                     float* __restrict__ WS) {
    __shared__ float As[16][128];
    __shared__ float Xs[16][128];
    const int tid = threadIdx.x;
    const int tx = tid & 15, ty = tid >> 4;
    const int k0 = blockIdx.x * 128, d0 = blockIdx.y * 128;
    const long n0 = (long)blockIdx.z * 1024;
    float acc[8][8] = {};
    for (int nc = 0; nc < 1024; nc += 16) {
        __syncthreads();
#pragma unroll
        for (int s = 0; s < 2; ++s) {
            const int idx = s * 256 + tid;        // 0..511 float4-slots
            const int r = idx >> 5;               // 0..15
            const int c4 = (idx & 31) << 2;       // 0..124
            const long nrow = n0 + nc + r;
            *(float4*)&As[r][c4] = *(const float4*)(A + nrow * 512 + k0 + c4);
            *(float4*)&Xs[r][c4] = *(const float4*)(X + nrow * 512 + d0 + c4);
        }
        __syncthreads();
#pragma unroll
        for (int r = 0; r < 16; ++r) {
            float4 a0 = *(const float4*)&As[r][ty * 4];
            float4 a1 = *(const float4*)&As[r][64 + ty * 4];
            float4 x0 = *(const float4*)&Xs[r][tx * 4];
            float4 x1 = *(const float4*)&Xs[r][64 + tx * 4];
            float av[8] = {a0.x, a0.y, a0.z, a0.w, a1.x, a1.y, a1.z, a1.w};
            float xv[8] = {x0.x, x0.y, x0.z, x0.w, x1.x, x1.y, x1.z, x1.w};
#pragma unroll
            for (int i = 0; i < 8; ++i)
#pragma unroll
                for (int j = 0; j < 8; ++j) acc[i][j] += av[i] * xv[j];
        }
    }
#pragma unroll
    for (int i = 0; i < 8; ++i) {
        const int k = k0 + ((i < 4) ? (ty * 4 + i) : (64 + ty * 4 + i - 4));
#pragma unroll
        for (int j = 0; j < 8; ++j) {
            const int d = d0 + ((j < 4) ? (tx * 4 + j) : (64 + tx * 4 + j - 4));
            atomicAdd(&WS[k * 512 + d], acc[i][j]);
        }
    }
}

// ---------------- repulsion + momentum update ----------------
__global__ __launch_bounds__(256) void repulse_update(const float* __restrict__ Cent,
                                                      const float* __restrict__ Mom,
                                                      const float* __restrict__ csq,
                                                      const float* __restrict__ WS,
                                                      const float* __restrict__ sum_w,
                                                      float* __restrict__ outC,
                                                      float* __restrict__ outM) {
    const int i = blockIdx.x;
    __shared__ float ci[512];
    __shared__ float rep[512];
    const int tid = threadIdx.x, wave = tid >> 6, lane = tid & 63;
    for (int d = tid; d < 512; d += 256) {
        ci[d] = Cent[i * 512 + d];
        rep[d] = 0.f;
    }
    __syncthreads();
    float cil[8];
#pragma unroll
    for (int m = 0; m < 8; ++m) cil[m] = ci[lane * 8 + m];
    const float csqi = csq[i];
    float racc[8] = {};
    for (int j = wave; j < 512; j += 4) {
        if (j == i) continue;
        const float* cj = Cent + j * 512 + lane * 8;
        float4 c0 = *(const float4*)cj;
        float4 c1 = *(const float4*)(cj + 4);
        float cjl[8] = {c0.x, c0.y, c0.z, c0.w, c1.x, c1.y, c1.z, c1.w};
        float dot = 0.f;
#pragma unroll
        for (int m = 0; m < 8; ++m) dot += cil[m] * cjl[m];
#pragma unroll
        for (int off = 1; off < 64; off <<= 1) dot += __shfl_xor(dot, off, 64);
        float sq = csqi + csq[j] - 2.f * dot;
        float dist = sqrtf(fmaxf(sq, 0.f) + EPSF);
        float w = fmaxf(0.f, 1.f - dist);
        float scale = 0.1f * w / (dist + EPSF);
#pragma unroll
        for (int m = 0; m < 8; ++m) racc[m] += scale * (cil[m] - cjl[m]);
    }
#pragma unroll
    for (int m = 0; m < 8; ++m) atomicAdd(&rep[lane * 8 + m], racc[m]);
    __syncthreads();
    const float invw = 1.0f / (sum_w[i] + EPSF);
    for (int d = tid; d < 512; d += 256) {
        float nc = WS[i * 512 + d] * invw;
        float upd = nc - ci[d] + rep[d];
        float mn = 0.9f * Mom[i * 512 + d] + 0.1f * upd;
        outM[i * 512 + d] = mn;
        outC[i * 512 + d] = ci[d] + 0.1f * mn;
    }
}

// ws_size probe: shows up in the dispatch list iff ws_size >= 70 MB
__global__ void ws_probe_big(float* p) {
    if (threadIdx.x == 0) p[0] = 0.f;
}

extern "C" void kernel_launch(void* const* d_in, const int* in_sizes, int n_in,
                              void* d_out, int out_size, void* d_ws, size_t ws_size,
                              hipStream_t stream) {
    const float* X = (const float*)d_in[0];      // (32768, 512)
    const float* C = (const float*)d_in[1];      // (512, 512)
    const float* M = (const float*)d_in[2];      // (512, 512)
    float* out = (float*)d_out;
    float* assign = out;                          // 32768*512
    float* outC = out + 16777216;                 // 512*512
    float* outM = outC + 262144;                  // 512*512
    float* ws = (float*)d_ws;
    float* WS = ws;                               // 262144 floats
    float* sum_w = ws + 262144;                   // 512
    float* csq = ws + 262656;                     // 512

    hipMemsetAsync(d_ws, 0, (262144 + 512) * sizeof(float), stream);

    csq_kernel<<<128, 256, 0, stream>>>(C, csq);
    logits_mfma<<<dim3(256, 4), 256, 0, stream>>>(X, C, csq, assign);
    softmax_rows<<<512, 256, 0, stream>>>(assign, sum_w);
    gemm_wsum_f32<<<dim3(4, 4, 32), 256, 0, stream>>>(assign, X, WS);
    repulse_update<<<512, 256, 0, stream>>>(C, M, csq, WS, sum_w, outC, outM);

    if (ws_size >= (size_t)70 * 1024 * 1024) {
        ws_probe_big<<<1, 64, 0, stream>>>(ws + (1 << 20));
    }
}

// Round 3
// 311.380 us; speedup vs baseline: 2.0212x; 1.7244x over previous
//
#include <hip/hip_runtime.h>
#include <hip/hip_bf16.h>

#define EPSF 1e-7f

typedef __attribute__((ext_vector_type(8))) short bf16x8;
typedef __attribute__((ext_vector_type(4))) float f32x4v;

__device__ inline ushort f2bf_bits(float x) {
    union { __hip_bfloat16 b; ushort u; } cv;
    cv.b = __float2bfloat16(x);
    return cv.u;
}
__device__ inline float bfbits2f(ushort u) {
    union { ushort u; __hip_bfloat16 b; } cv;
    cv.u = u;
    return __bfloat162float(cv.b);
}
__device__ inline void split2(float x, ushort& h, ushort& l) {
    h = f2bf_bits(x);
    l = f2bf_bits(x - bfbits2f(h));
}

__device__ inline void gload_lds16(const ushort* g, ushort* l) {
    __builtin_amdgcn_global_load_lds(
        (const __attribute__((address_space(1))) unsigned int*)g,
        (__attribute__((address_space(3))) unsigned int*)l, 16, 0, 0);
}

// ---------------- c_sq[k] = sum_d C[k][d]^2 ----------------
__global__ __launch_bounds__(256) void csq_kernel(const float* __restrict__ C,
                                                  float* __restrict__ csq) {
    const int wave = threadIdx.x >> 6, lane = threadIdx.x & 63;
    const int row = blockIdx.x * 4 + wave;
    const float* p = C + row * 512 + lane * 8;
    float4 a = *(const float4*)p;
    float4 b = *(const float4*)(p + 4);
    float s = a.x * a.x + a.y * a.y + a.z * a.z + a.w * a.w +
              b.x * b.x + b.y * b.y + b.z * b.z + b.w * b.w;
#pragma unroll
    for (int off = 1; off < 64; off <<= 1) s += __shfl_xor(s, off, 64);
    if (lane == 0) csq[row] = s;
}

// ---------------- logits via split-bf16 MFMA (unchanged from R2) ----------------
__global__ __launch_bounds__(256) void logits_mfma(const float* __restrict__ X,
                                                   const float* __restrict__ Cm,
                                                   const float* __restrict__ csq,
                                                   float* __restrict__ L) {
    __shared__ ushort sAh[128][64];
    __shared__ ushort sAl[128][64];
    __shared__ ushort sBh[128][64];
    __shared__ ushort sBl[128][64];
    const int tid = threadIdx.x;
    const int m0 = blockIdx.x * 128;
    const int n0 = blockIdx.y * 128;
    const int wid = tid >> 6, lane = tid & 63;
    const int wm = wid >> 1, wn = wid & 1;
    const int lrow = lane & 15;
    const int lkb = lane >> 4;
    f32x4v acc[4][4] = {};

    for (int k0 = 0; k0 < 512; k0 += 64) {
        __syncthreads();
#pragma unroll
        for (int s = 0; s < 8; ++s) {
            const int idx = s * 256 + tid;
            const int r = idx >> 4;
            const int c4 = (idx & 15) << 2;
            const int e = c4 ^ ((r & 7) << 3);
            float4 va = *(const float4*)(X + (long)(m0 + r) * 512 + k0 + c4);
            ushort4 hh, ll;
            split2(va.x, hh.x, ll.x);
            split2(va.y, hh.y, ll.y);
            split2(va.z, hh.z, ll.z);
            split2(va.w, hh.w, ll.w);
            *(ushort4*)&sAh[r][e] = hh;
            *(ushort4*)&sAl[r][e] = ll;
            float4 vb = *(const float4*)(Cm + (long)(n0 + r) * 512 + k0 + c4);
            split2(vb.x, hh.x, ll.x);
            split2(vb.y, hh.y, ll.y);
            split2(vb.z, hh.z, ll.z);
            split2(vb.w, hh.w, ll.w);
            *(ushort4*)&sBh[r][e] = hh;
            *(ushort4*)&sBl[r][e] = ll;
        }
        __syncthreads();
#pragma unroll
        for (int kk = 0; kk < 2; ++kk) {
            const int ebase = kk * 32 + lkb * 8;
            bf16x8 ah[4], al[4], bh[4], bl[4];
#pragma unroll
            for (int mi = 0; mi < 4; ++mi) {
                const int R = wm * 64 + mi * 16 + lrow;
                const int e = ebase ^ ((R & 7) << 3);
                ah[mi] = *(const bf16x8*)&sAh[R][e];
                al[mi] = *(const bf16x8*)&sAl[R][e];
            }
#pragma unroll
            for (int ni = 0; ni < 4; ++ni) {
                const int Rn = wn * 64 + ni * 16 + lrow;
                const int e = ebase ^ ((Rn & 7) << 3);
                bh[ni] = *(const bf16x8*)&sBh[Rn][e];
                bl[ni] = *(const bf16x8*)&sBl[Rn][e];
            }
#pragma unroll
            for (int mi = 0; mi < 4; ++mi)
#pragma unroll
                for (int ni = 0; ni < 4; ++ni) {
                    acc[mi][ni] = __builtin_amdgcn_mfma_f32_16x16x32_bf16(ah[mi], bh[ni], acc[mi][ni], 0, 0, 0);
                    acc[mi][ni] = __builtin_amdgcn_mfma_f32_16x16x32_bf16(ah[mi], bl[ni], acc[mi][ni], 0, 0, 0);
                    acc[mi][ni] = __builtin_amdgcn_mfma_f32_16x16x32_bf16(al[mi], bh[ni], acc[mi][ni], 0, 0, 0);
                }
        }
    }
    const int colb = n0 + wn * 64 + lrow;
    float cs[4];
#pragma unroll
    for (int ni = 0; ni < 4; ++ni) cs[ni] = csq[colb + ni * 16];
#pragma unroll
    for (int mi = 0; mi < 4; ++mi) {
        const int rowb = m0 + wm * 64 + mi * 16 + lkb * 4;
#pragma unroll
        for (int r = 0; r < 4; ++r) {
            float* Lp = L + (long)(rowb + r) * 512 + colb;
#pragma unroll
            for (int ni = 0; ni < 4; ++ni)
                Lp[ni * 16] = 2.0f * acc[mi][ni][r] - cs[ni];
        }
    }
}

// ---------------- in-place row softmax (scale 1/T=10) + sum_w ----------------
__global__ __launch_bounds__(256) void softmax_rows(float* __restrict__ L,
                                                    float* __restrict__ sum_w) {
    __shared__ float swacc[512];
    const int tid = threadIdx.x;
    for (int i = tid; i < 512; i += 256) swacc[i] = 0.f;
    __syncthreads();
    const int wave = tid >> 6, lane = tid & 63;
    float racc[8] = {};
    for (int r = blockIdx.x * 4 + wave; r < 32768; r += 2048) {
        float* p = L + (long)r * 512 + lane * 8;
        float4 v0 = *(float4*)p;
        float4 v1 = *(float4*)(p + 4);
        float v[8] = {v0.x, v0.y, v0.z, v0.w, v1.x, v1.y, v1.z, v1.w};
        float m = v[0];
#pragma unroll
        for (int i = 1; i < 8; ++i) m = fmaxf(m, v[i]);
#pragma unroll
        for (int off = 1; off < 64; off <<= 1) m = fmaxf(m, __shfl_xor(m, off, 64));
        float e[8], s = 0.f;
#pragma unroll
        for (int i = 0; i < 8; ++i) {
            e[i] = expf((v[i] - m) * 10.0f);
            s += e[i];
        }
#pragma unroll
        for (int off = 1; off < 64; off <<= 1) s += __shfl_xor(s, off, 64);
        const float inv = 1.0f / (s + EPSF);
#pragma unroll
        for (int i = 0; i < 8; ++i) {
            e[i] *= inv;
            racc[i] += e[i];
        }
        float4 o0 = {e[0], e[1], e[2], e[3]};
        float4 o1 = {e[4], e[5], e[6], e[7]};
        *(float4*)p = o0;
        *(float4*)(p + 4) = o1;
    }
#pragma unroll
    for (int i = 0; i < 8; ++i) atomicAdd(&swacc[lane * 8 + i], racc[i]);
    __syncthreads();
    for (int i = tid; i < 512; i += 256) atomicAdd(&sum_w[i], swacc[i]);
}

// ---------------- transpose f32 [R][512] -> bf16 [512][R] ----------------
// 64x64 tiles; LDS 16B-slot XOR swizzle -> conflict-free b128 writes AND reads.
__global__ __launch_bounds__(256) void transpose_to_bf16(const float* __restrict__ in,
                                                         ushort* __restrict__ out, int R) {
    __shared__ uint st[64 * 32];  // [c][slot(16B)*4 words], row = 128B
    const int t = threadIdx.x;
    const int r0 = blockIdx.x * 64;
    const int c0 = blockIdx.y * 64;
#pragma unroll
    for (int s = 0; s < 2; ++s) {
        const int idx = s * 256 + t;     // 512 tasks: c(64) x row-oct(8)
        const int c = idx & 63;
        const int ro = idx >> 6;         // 0..7
        float v[8];
#pragma unroll
        for (int j = 0; j < 8; ++j)
            v[j] = in[(long)(r0 + ro * 8 + j) * 512 + c0 + c];
        uint4 w;
        w.x = (uint)f2bf_bits(v[0]) | ((uint)f2bf_bits(v[1]) << 16);
        w.y = (uint)f2bf_bits(v[2]) | ((uint)f2bf_bits(v[3]) << 16);
        w.z = (uint)f2bf_bits(v[4]) | ((uint)f2bf_bits(v[5]) << 16);
        w.w = (uint)f2bf_bits(v[6]) | ((uint)f2bf_bits(v[7]) << 16);
        const int sl = ro ^ (c & 7);
        *(uint4*)&st[c * 32 + sl * 4] = w;
    }
    __syncthreads();
#pragma unroll
    for (int s = 0; s < 2; ++s) {
        const int idx = s * 256 + t;     // 512 tasks: c(64) x slot(8)
        const int c = idx >> 3;
        const int sl = idx & 7;
        uint4 w = *(const uint4*)&st[c * 32 + (sl ^ (c & 7)) * 4];
        *(uint4*)(out + (long)(c0 + c) * R + r0 + sl * 8) = w;
    }
}

// ---------------- WS[k][d] += sum_n AT[k][n]*XT[d][n]  (bf16 MFMA) ----------------
// AT, XT: bf16 [512][32768]. Tile 128x128, BK(n)=64, z-chunk 1024. 4 waves (2x2).
__global__ __launch_bounds__(256) void wsum_mfma(const ushort* __restrict__ AT,
                                                 const ushort* __restrict__ XT,
                                                 float* __restrict__ WS) {
    __shared__ __align__(16) ushort sA[128 * 64];
    __shared__ __align__(16) ushort sB[128 * 64];
    const int tid = threadIdx.x;
    const int k0 = blockIdx.x * 128;
    const int d0 = blockIdx.y * 128;
    const long n0 = (long)blockIdx.z * 1024;
    const int wid = tid >> 6, lane = tid & 63;
    const int wm = wid >> 1, wn = wid & 1;
    const int lrow = lane & 15;
    const int lkb = lane >> 4;
    f32x4v acc[4][4] = {};

    for (int nc = 0; nc < 1024; nc += 64) {
        __syncthreads();
        // stage: pre-swizzled global src, linear LDS dest (rule #21 pairing)
#pragma unroll
        for (int i = 0; i < 4; ++i) {
            const int sl = wid * 256 + i * 64 + lane;   // 16B slot index
            const int r = sl >> 3;                       // row 0..127
            const int s = sl & 7;                        // slot in row
            const long goff = (long)r * 32768 + n0 + nc + ((s ^ (r & 7)) << 3);
            gload_lds16(AT + (long)k0 * 32768 + goff, &sA[(wid * 256 + i * 64) * 8]);
            gload_lds16(XT + (long)d0 * 32768 + goff, &sB[(wid * 256 + i * 64) * 8]);
        }
        __syncthreads();
#pragma unroll
        for (int kk = 0; kk < 2; ++kk) {
            const int j = kk * 4 + lkb;                  // 16B slot within row
            bf16x8 af[4], bfv[4];
#pragma unroll
            for (int mi = 0; mi < 4; ++mi) {
                const int R = wm * 64 + mi * 16 + lrow;
                af[mi] = *(const bf16x8*)&sA[R * 64 + ((j ^ (R & 7)) << 3)];
            }
#pragma unroll
            for (int ni = 0; ni < 4; ++ni) {
                const int R = wn * 64 + ni * 16 + lrow;
                bfv[ni] = *(const bf16x8*)&sB[R * 64 + ((j ^ (R & 7)) << 3)];
            }
#pragma unroll
            for (int mi = 0; mi < 4; ++mi)
#pragma unroll
                for (int ni = 0; ni < 4; ++ni)
                    acc[mi][ni] = __builtin_amdgcn_mfma_f32_16x16x32_bf16(af[mi], bfv[ni], acc[mi][ni], 0, 0, 0);
        }
    }
    // epilogue: atomic f32 accumulate across z-chunks
#pragma unroll
    for (int mi = 0; mi < 4; ++mi) {
        const int k = k0 + wm * 64 + mi * 16 + lkb * 4;
#pragma unroll
        for (int ni = 0; ni < 4; ++ni) {
            const int d = d0 + wn * 64 + ni * 16 + lrow;
#pragma unroll
            for (int r = 0; r < 4; ++r)
                atomicAdd(&WS[(k + r) * 512 + d], acc[mi][ni][r]);
        }
    }
}

// ---------------- fallback fp32 wsum (R1 64-tile version) ----------------
__global__ __launch_bounds__(256) void gemm_wsum(const float* __restrict__ A,
                                                 const float* __restrict__ X,
                                                 float* __restrict__ WS) {
    __shared__ float As[16][64];
    __shared__ float Xs[16][64];
    const int tid = threadIdx.x;
    const int tx = tid & 15, ty = tid >> 4;
    const int lrow = tid >> 4;
    const int lcol = (tid & 15) << 2;
    const int k0 = blockIdx.x * 64;
    const int d0 = blockIdx.y * 64;
    const int n0 = blockIdx.z * 1024;
    float acc[4][4] = {};
    for (int nc = 0; nc < 1024; nc += 16) {
        const long nrow = n0 + nc + lrow;
        float4 av = *(const float4*)(A + nrow * 512 + k0 + lcol);
        float4 xv = *(const float4*)(X + nrow * 512 + d0 + lcol);
        __syncthreads();
        *(float4*)&As[lrow][lcol] = av;
        *(float4*)&Xs[lrow][lcol] = xv;
        __syncthreads();
#pragma unroll
        for (int nn = 0; nn < 16; ++nn) {
            float4 a = *(const float4*)&As[nn][ty << 2];
            float4 x = *(const float4*)&Xs[nn][tx << 2];
            float aa[4] = {a.x, a.y, a.z, a.w};
            float xx[4] = {x.x, x.y, x.z, x.w};
#pragma unroll
            for (int i = 0; i < 4; ++i)
#pragma unroll
                for (int j = 0; j < 4; ++j) acc[i][j] += aa[i] * xx[j];
        }
    }
#pragma unroll
    for (int i = 0; i < 4; ++i)
#pragma unroll
        for (int j = 0; j < 4; ++j)
            atomicAdd(&WS[(k0 + (ty << 2) + i) * 512 + d0 + (tx << 2) + j], acc[i][j]);
}

// ---------------- repulsion + momentum update ----------------
__global__ __launch_bounds__(256) void repulse_update(const float* __restrict__ Cent,
                                                      const float* __restrict__ Mom,
                                                      const float* __restrict__ csq,
                                                      const float* __restrict__ WS,
                                                      const float* __restrict__ sum_w,
                                                      float* __restrict__ outC,
                                                      float* __restrict__ outM) {
    const int i = blockIdx.x;
    __shared__ float ci[512];
    __shared__ float rep[512];
    const int tid = threadIdx.x, wave = tid >> 6, lane = tid & 63;
    for (int d = tid; d < 512; d += 256) {
        ci[d] = Cent[i * 512 + d];
        rep[d] = 0.f;
    }
    __syncthreads();
    float cil[8];
#pragma unroll
    for (int m = 0; m < 8; ++m) cil[m] = ci[lane * 8 + m];
    const float csqi = csq[i];
    float racc[8] = {};
    for (int j = wave; j < 512; j += 4) {
        if (j == i) continue;
        const float* cj = Cent + j * 512 + lane * 8;
        float4 c0 = *(const float4*)cj;
        float4 c1 = *(const float4*)(cj + 4);
        float cjl[8] = {c0.x, c0.y, c0.z, c0.w, c1.x, c1.y, c1.z, c1.w};
        float dot = 0.f;
#pragma unroll
        for (int m = 0; m < 8; ++m) dot += cil[m] * cjl[m];
#pragma unroll
        for (int off = 1; off < 64; off <<= 1) dot += __shfl_xor(dot, off, 64);
        float sq = csqi + csq[j] - 2.f * dot;
        float dist = sqrtf(fmaxf(sq, 0.f) + EPSF);
        float w = fmaxf(0.f, 1.f - dist);
        float scale = 0.1f * w / (dist + EPSF);
#pragma unroll
        for (int m = 0; m < 8; ++m) racc[m] += scale * (cil[m] - cjl[m]);
    }
#pragma unroll
    for (int m = 0; m < 8; ++m) atomicAdd(&rep[lane * 8 + m], racc[m]);
    __syncthreads();
    const float invw = 1.0f / (sum_w[i] + EPSF);
    for (int d = tid; d < 512; d += 256) {
        float nc = WS[i * 512 + d] * invw;
        float upd = nc - ci[d] + rep[d];
        float mn = 0.9f * Mom[i * 512 + d] + 0.1f * upd;
        outM[i * 512 + d] = mn;
        outC[i * 512 + d] = ci[d] + 0.1f * mn;
    }
}

extern "C" void kernel_launch(void* const* d_in, const int* in_sizes, int n_in,
                              void* d_out, int out_size, void* d_ws, size_t ws_size,
                              hipStream_t stream) {
    const float* X = (const float*)d_in[0];      // (32768, 512)
    const float* C = (const float*)d_in[1];      // (512, 512)
    const float* M = (const float*)d_in[2];      // (512, 512)
    float* out = (float*)d_out;
    float* assign = out;                          // 32768*512
    float* outC = out + 16777216;                 // 512*512
    float* outM = outC + 262144;                  // 512*512

    char* wsb = (char*)d_ws;
    float* WS = (float*)wsb;                      // 1 MB
    float* sum_w = (float*)(wsb + (1 << 20));     // 2 KB
    float* csq = (float*)(wsb + (1 << 20) + 4096);
    ushort* AT = (ushort*)(wsb + (2 << 20));                    // 32 MB
    ushort* XT = (ushort*)(wsb + (2 << 20) + 33554432);         // 32 MB
    const size_t need = (size_t)(2 << 20) + 2ull * 33554432ull; // ~66 MB

    hipMemsetAsync(d_ws, 0, (262144 + 512) * sizeof(float), stream);

    csq_kernel<<<128, 256, 0, stream>>>(C, csq);
    logits_mfma<<<dim3(256, 4), 256, 0, stream>>>(X, C, csq, assign);
    softmax_rows<<<512, 256, 0, stream>>>(assign, sum_w);

    if (ws_size >= need) {
        transpose_to_bf16<<<dim3(512, 8), 256, 0, stream>>>(X, XT, 32768);
        transpose_to_bf16<<<dim3(512, 8), 256, 0, stream>>>(assign, AT, 32768);
        wsum_mfma<<<dim3(4, 4, 32), 256, 0, stream>>>(AT, XT, WS);
    } else {
        gemm_wsum<<<dim3(8, 8, 32), 256, 0, stream>>>(assign, X, WS);
    }

    repulse_update<<<512, 256, 0, stream>>>(C, M, csq, WS, sum_w, outC, outM);
}

// Round 4
// 305.804 us; speedup vs baseline: 2.0580x; 1.0182x over previous
//
#include <hip/hip_runtime.h>
#include <hip/hip_bf16.h>

#define EPSF 1e-7f

typedef __attribute__((ext_vector_type(8))) short bf16x8;
typedef __attribute__((ext_vector_type(4))) float f32x4v;

__device__ inline ushort f2bf_bits(float x) {
    union { __hip_bfloat16 b; ushort u; } cv;
    cv.b = __float2bfloat16(x);
    return cv.u;
}
__device__ inline float bfbits2f(ushort u) {
    union { ushort u; __hip_bfloat16 b; } cv;
    cv.u = u;
    return __bfloat162float(cv.b);
}
__device__ inline void split2(float x, ushort& h, ushort& l) {
    h = f2bf_bits(x);
    l = f2bf_bits(x - bfbits2f(h));
}

__device__ inline void gload_lds16(const ushort* g, ushort* l) {
    __builtin_amdgcn_global_load_lds(
        (const __attribute__((address_space(1))) unsigned int*)g,
        (__attribute__((address_space(3))) unsigned int*)l, 16, 0, 0);
}

// ---------------- csq + C -> Ch/Cl bf16 split ----------------
__global__ __launch_bounds__(256) void csqc_kernel(const float* __restrict__ C,
                                                   float* __restrict__ csq,
                                                   ushort* __restrict__ Ch,
                                                   ushort* __restrict__ Cl) {
    const int wave = threadIdx.x >> 6, lane = threadIdx.x & 63;
    const int row = blockIdx.x * 4 + wave;
    const float* p = C + row * 512 + lane * 8;
    float4 a = *(const float4*)p;
    float4 b = *(const float4*)(p + 4);
    float v[8] = {a.x, a.y, a.z, a.w, b.x, b.y, b.z, b.w};
    ushort h[8], l[8];
    float s = 0.f;
#pragma unroll
    for (int i = 0; i < 8; ++i) {
        s += v[i] * v[i];
        split2(v[i], h[i], l[i]);
    }
    uint4 ph, pl;
    ph.x = (uint)h[0] | ((uint)h[1] << 16); ph.y = (uint)h[2] | ((uint)h[3] << 16);
    ph.z = (uint)h[4] | ((uint)h[5] << 16); ph.w = (uint)h[6] | ((uint)h[7] << 16);
    pl.x = (uint)l[0] | ((uint)l[1] << 16); pl.y = (uint)l[2] | ((uint)l[3] << 16);
    pl.z = (uint)l[4] | ((uint)l[5] << 16); pl.w = (uint)l[6] | ((uint)l[7] << 16);
    *(uint4*)(Ch + row * 512 + lane * 8) = ph;
    *(uint4*)(Cl + row * 512 + lane * 8) = pl;
#pragma unroll
    for (int off = 1; off < 64; off <<= 1) s += __shfl_xor(s, off, 64);
    if (lane == 0) csq[row] = s;
}

// ---------------- X -> Xh, Xl bf16 split (row-major) ----------------
__global__ __launch_bounds__(256) void convert_x(const float* __restrict__ X,
                                                 ushort* __restrict__ Xh,
                                                 ushort* __restrict__ Xl) {
    const long base = ((long)blockIdx.x * 256 + threadIdx.x) * 8;  // grid 8192 covers 16.7M elems
    float4 a = *(const float4*)(X + base);
    float4 b = *(const float4*)(X + base + 4);
    float v[8] = {a.x, a.y, a.z, a.w, b.x, b.y, b.z, b.w};
    ushort h[8], l[8];
#pragma unroll
    for (int i = 0; i < 8; ++i) split2(v[i], h[i], l[i]);
    uint4 ph, pl;
    ph.x = (uint)h[0] | ((uint)h[1] << 16); ph.y = (uint)h[2] | ((uint)h[3] << 16);
    ph.z = (uint)h[4] | ((uint)h[5] << 16); ph.w = (uint)h[6] | ((uint)h[7] << 16);
    pl.x = (uint)l[0] | ((uint)l[1] << 16); pl.y = (uint)l[2] | ((uint)l[3] << 16);
    pl.z = (uint)l[4] | ((uint)l[5] << 16); pl.w = (uint)l[6] | ((uint)l[7] << 16);
    *(uint4*)(Xh + base) = ph;
    *(uint4*)(Xl + base) = pl;
}

// ---------------- logits v2: pure bf16 3-pass GEMM, m97-style ----------------
// L[m][n] = 2*sum_k X[m][k]C[n][k] - csq[n], via (Xh,Ch)+(Xh,Cl)+(Xl,Ch).
// BM=BN=128, BK=64, 4 waves (2x2), global_load_lds w/ pre-swizzled source.
__global__ __launch_bounds__(256) void logits_v2(const ushort* __restrict__ Xh,
                                                 const ushort* __restrict__ Xl,
                                                 const ushort* __restrict__ Ch,
                                                 const ushort* __restrict__ Cl,
                                                 const float* __restrict__ csq,
                                                 float* __restrict__ L) {
    __shared__ __align__(16) ushort sA[128 * 64];
    __shared__ __align__(16) ushort sB[128 * 64];
    const int tid = threadIdx.x;
    const int n0 = blockIdx.x * 128;   // x = n (4) -> consecutive blocks share A panel
    const int m0 = blockIdx.y * 128;
    const int wid = tid >> 6, lane = tid & 63;
    const int wm = wid >> 1, wn = wid & 1;
    const int lrow = lane & 15, lkb = lane >> 4;
    f32x4v acc[4][4] = {};

#pragma unroll 1
    for (int p = 0; p < 3; ++p) {
        const ushort* Ab = (p == 2) ? Xl : Xh;
        const ushort* Bb = (p == 1) ? Cl : Ch;
#pragma unroll 1
        for (int kc = 0; kc < 8; ++kc) {
            __syncthreads();
#pragma unroll
            for (int i = 0; i < 4; ++i) {
                const int sl = i * 256 + tid;
                const int r = sl >> 3, s = sl & 7;
                const int kcol = kc * 64 + ((s ^ (r & 7)) << 3);
                gload_lds16(Ab + (long)(m0 + r) * 512 + kcol, &sA[(i * 256 + wid * 64) * 8]);
                gload_lds16(Bb + (long)(n0 + r) * 512 + kcol, &sB[(i * 256 + wid * 64) * 8]);
            }
            __syncthreads();
#pragma unroll
            for (int kk = 0; kk < 2; ++kk) {
                const int j = kk * 4 + lkb;
                bf16x8 af[4], bfv[4];
#pragma unroll
                for (int mi = 0; mi < 4; ++mi) {
                    const int R = wm * 64 + mi * 16 + lrow;
                    af[mi] = *(const bf16x8*)&sA[R * 64 + ((j ^ (R & 7)) << 3)];
                }
#pragma unroll
                for (int ni = 0; ni < 4; ++ni) {
                    const int R = wn * 64 + ni * 16 + lrow;
                    bfv[ni] = *(const bf16x8*)&sB[R * 64 + ((j ^ (R & 7)) << 3)];
                }
#pragma unroll
                for (int mi = 0; mi < 4; ++mi)
#pragma unroll
                    for (int ni = 0; ni < 4; ++ni)
                        acc[mi][ni] = __builtin_amdgcn_mfma_f32_16x16x32_bf16(af[mi], bfv[ni], acc[mi][ni], 0, 0, 0);
            }
        }
    }
    const int colb = n0 + wn * 64 + lrow;
    float cs[4];
#pragma unroll
    for (int ni = 0; ni < 4; ++ni) cs[ni] = csq[colb + ni * 16];
#pragma unroll
    for (int mi = 0; mi < 4; ++mi) {
        const int rowb = m0 + wm * 64 + mi * 16 + lkb * 4;
#pragma unroll
        for (int r = 0; r < 4; ++r) {
            float* Lp = L + (long)(rowb + r) * 512 + colb;
#pragma unroll
            for (int ni = 0; ni < 4; ++ni)
                Lp[ni * 16] = 2.0f * acc[mi][ni][r] - cs[ni];
        }
    }
}

// ---------------- legacy logits (in-kernel split) for fallback paths ----------------
__global__ __launch_bounds__(256) void logits_mfma(const float* __restrict__ X,
                                                   const float* __restrict__ Cm,
                                                   const float* __restrict__ csq,
                                                   float* __restrict__ L) {
    __shared__ ushort sAh[128][64];
    __shared__ ushort sAl[128][64];
    __shared__ ushort sBh[128][64];
    __shared__ ushort sBl[128][64];
    const int tid = threadIdx.x;
    const int m0 = blockIdx.x * 128;
    const int n0 = blockIdx.y * 128;
    const int wid = tid >> 6, lane = tid & 63;
    const int wm = wid >> 1, wn = wid & 1;
    const int lrow = lane & 15;
    const int lkb = lane >> 4;
    f32x4v acc[4][4] = {};
    for (int k0 = 0; k0 < 512; k0 += 64) {
        __syncthreads();
#pragma unroll
        for (int s = 0; s < 8; ++s) {
            const int idx = s * 256 + tid;
            const int r = idx >> 4;
            const int c4 = (idx & 15) << 2;
            const int e = c4 ^ ((r & 7) << 3);
            float4 va = *(const float4*)(X + (long)(m0 + r) * 512 + k0 + c4);
            ushort4 hh, ll;
            split2(va.x, hh.x, ll.x);
            split2(va.y, hh.y, ll.y);
            split2(va.z, hh.z, ll.z);
            split2(va.w, hh.w, ll.w);
            *(ushort4*)&sAh[r][e] = hh;
            *(ushort4*)&sAl[r][e] = ll;
            float4 vb = *(const float4*)(Cm + (long)(n0 + r) * 512 + k0 + c4);
            split2(vb.x, hh.x, ll.x);
            split2(vb.y, hh.y, ll.y);
            split2(vb.z, hh.z, ll.z);
            split2(vb.w, hh.w, ll.w);
            *(ushort4*)&sBh[r][e] = hh;
            *(ushort4*)&sBl[r][e] = ll;
        }
        __syncthreads();
#pragma unroll
        for (int kk = 0; kk < 2; ++kk) {
            const int ebase = kk * 32 + lkb * 8;
            bf16x8 ah[4], al[4], bh[4], bl[4];
#pragma unroll
            for (int mi = 0; mi < 4; ++mi) {
                const int R = wm * 64 + mi * 16 + lrow;
                const int e = ebase ^ ((R & 7) << 3);
                ah[mi] = *(const bf16x8*)&sAh[R][e];
                al[mi] = *(const bf16x8*)&sAl[R][e];
            }
#pragma unroll
            for (int ni = 0; ni < 4; ++ni) {
                const int Rn = wn * 64 + ni * 16 + lrow;
                const int e = ebase ^ ((Rn & 7) << 3);
                bh[ni] = *(const bf16x8*)&sBh[Rn][e];
                bl[ni] = *(const bf16x8*)&sBl[Rn][e];
            }
#pragma unroll
            for (int mi = 0; mi < 4; ++mi)
#pragma unroll
                for (int ni = 0; ni < 4; ++ni) {
                    acc[mi][ni] = __builtin_amdgcn_mfma_f32_16x16x32_bf16(ah[mi], bh[ni], acc[mi][ni], 0, 0, 0);
                    acc[mi][ni] = __builtin_amdgcn_mfma_f32_16x16x32_bf16(ah[mi], bl[ni], acc[mi][ni], 0, 0, 0);
                    acc[mi][ni] = __builtin_amdgcn_mfma_f32_16x16x32_bf16(al[mi], bh[ni], acc[mi][ni], 0, 0, 0);
                }
        }
    }
    const int colb = n0 + wn * 64 + lrow;
    float cs[4];
#pragma unroll
    for (int ni = 0; ni < 4; ++ni) cs[ni] = csq[colb + ni * 16];
#pragma unroll
    for (int mi = 0; mi < 4; ++mi) {
        const int rowb = m0 + wm * 64 + mi * 16 + lkb * 4;
#pragma unroll
        for (int r = 0; r < 4; ++r) {
            float* Lp = L + (long)(rowb + r) * 512 + colb;
#pragma unroll
            for (int ni = 0; ni < 4; ++ni)
                Lp[ni * 16] = 2.0f * acc[mi][ni][r] - cs[ni];
        }
    }
}

// ---------------- in-place row softmax (scale 1/T=10) + sum_w ----------------
__global__ __launch_bounds__(256) void softmax_rows(float* __restrict__ L,
                                                    float* __restrict__ sum_w) {
    __shared__ float swacc[512];
    const int tid = threadIdx.x;
    for (int i = tid; i < 512; i += 256) swacc[i] = 0.f;
    __syncthreads();
    const int wave = tid >> 6, lane = tid & 63;
    float racc[8] = {};
    for (int r = blockIdx.x * 4 + wave; r < 32768; r += 2048) {
        float* p = L + (long)r * 512 + lane * 8;
        float4 v0 = *(float4*)p;
        float4 v1 = *(float4*)(p + 4);
        float v[8] = {v0.x, v0.y, v0.z, v0.w, v1.x, v1.y, v1.z, v1.w};
        float m = v[0];
#pragma unroll
        for (int i = 1; i < 8; ++i) m = fmaxf(m, v[i]);
#pragma unroll
        for (int off = 1; off < 64; off <<= 1) m = fmaxf(m, __shfl_xor(m, off, 64));
        float e[8], s = 0.f;
#pragma unroll
        for (int i = 0; i < 8; ++i) {
            e[i] = expf((v[i] - m) * 10.0f);
            s += e[i];
        }
#pragma unroll
        for (int off = 1; off < 64; off <<= 1) s += __shfl_xor(s, off, 64);
        const float inv = 1.0f / (s + EPSF);
#pragma unroll
        for (int i = 0; i < 8; ++i) {
            e[i] *= inv;
            racc[i] += e[i];
        }
        float4 o0 = {e[0], e[1], e[2], e[3]};
        float4 o1 = {e[4], e[5], e[6], e[7]};
        *(float4*)p = o0;
        *(float4*)(p + 4) = o1;
    }
#pragma unroll
    for (int i = 0; i < 8; ++i) atomicAdd(&swacc[lane * 8 + i], racc[i]);
    __syncthreads();
    for (int i = tid; i < 512; i += 256) atomicAdd(&sum_w[i], swacc[i]);
}

// ---------------- transpose f32 [R][512] -> bf16 [512][R] ----------------
__global__ __launch_bounds__(256) void transpose_to_bf16(const float* __restrict__ in,
                                                         ushort* __restrict__ out, int R) {
    __shared__ uint st[64 * 32];
    const int t = threadIdx.x;
    const int r0 = blockIdx.x * 64;
    const int c0 = blockIdx.y * 64;
#pragma unroll
    for (int s = 0; s < 2; ++s) {
        const int idx = s * 256 + t;
        const int c = idx & 63;
        const int ro = idx >> 6;
        float v[8];
#pragma unroll
        for (int j = 0; j < 8; ++j)
            v[j] = in[(long)(r0 + ro * 8 + j) * 512 + c0 + c];
        uint4 w;
        w.x = (uint)f2bf_bits(v[0]) | ((uint)f2bf_bits(v[1]) << 16);
        w.y = (uint)f2bf_bits(v[2]) | ((uint)f2bf_bits(v[3]) << 16);
        w.z = (uint)f2bf_bits(v[4]) | ((uint)f2bf_bits(v[5]) << 16);
        w.w = (uint)f2bf_bits(v[6]) | ((uint)f2bf_bits(v[7]) << 16);
        const int sl = ro ^ (c & 7);
        *(uint4*)&st[c * 32 + sl * 4] = w;
    }
    __syncthreads();
#pragma unroll
    for (int s = 0; s < 2; ++s) {
        const int idx = s * 256 + t;
        const int c = idx >> 3;
        const int sl = idx & 7;
        uint4 w = *(const uint4*)&st[c * 32 + (sl ^ (c & 7)) * 4];
        *(uint4*)(out + (long)(c0 + c) * R + r0 + sl * 8) = w;
    }
}

// ---------------- wsum partials: WSp[z][k][d] = sum over 512-n chunk ----------------
__global__ __launch_bounds__(256) void wsum_mfma_part(const ushort* __restrict__ AT,
                                                      const ushort* __restrict__ XT,
                                                      float* __restrict__ WSp) {
    __shared__ __align__(16) ushort sA[128 * 64];
    __shared__ __align__(16) ushort sB[128 * 64];
    const int tid = threadIdx.x;
    const int k0 = blockIdx.x * 128;
    const int d0 = blockIdx.y * 128;
    const long n0 = (long)blockIdx.z * 512;
    const int wid = tid >> 6, lane = tid & 63;
    const int wm = wid >> 1, wn = wid & 1;
    const int lrow = lane & 15;
    const int lkb = lane >> 4;
    f32x4v acc[4][4] = {};

    for (int nc = 0; nc < 512; nc += 64) {
        __syncthreads();
#pragma unroll
        for (int i = 0; i < 4; ++i) {
            const int sl = wid * 256 + i * 64 + lane;
            const int r = sl >> 3;
            const int s = sl & 7;
            const long goff = (long)r * 32768 + n0 + nc + ((s ^ (r & 7)) << 3);
            gload_lds16(AT + (long)k0 * 32768 + goff, &sA[(wid * 256 + i * 64) * 8]);
            gload_lds16(XT + (long)d0 * 32768 + goff, &sB[(wid * 256 + i * 64) * 8]);
        }
        __syncthreads();
#pragma unroll
        for (int kk = 0; kk < 2; ++kk) {
            const int j = kk * 4 + lkb;
            bf16x8 af[4], bfv[4];
#pragma unroll
            for (int mi = 0; mi < 4; ++mi) {
                const int R = wm * 64 + mi * 16 + lrow;
                af[mi] = *(const bf16x8*)&sA[R * 64 + ((j ^ (R & 7)) << 3)];
            }
#pragma unroll
            for (int ni = 0; ni < 4; ++ni) {
                const int R = wn * 64 + ni * 16 + lrow;
                bfv[ni] = *(const bf16x8*)&sB[R * 64 + ((j ^ (R & 7)) << 3)];
            }
#pragma unroll
            for (int mi = 0; mi < 4; ++mi)
#pragma unroll
                for (int ni = 0; ni < 4; ++ni)
                    acc[mi][ni] = __builtin_amdgcn_mfma_f32_16x16x32_bf16(af[mi], bfv[ni], acc[mi][ni], 0, 0, 0);
        }
    }
    float* dst = WSp + (size_t)blockIdx.z * 262144;
#pragma unroll
    for (int mi = 0; mi < 4; ++mi) {
        const int k = k0 + wm * 64 + mi * 16 + lkb * 4;
#pragma unroll
        for (int ni = 0; ni < 4; ++ni) {
            const int d = d0 + wn * 64 + ni * 16 + lrow;
#pragma unroll
            for (int r = 0; r < 4; ++r)
                dst[(k + r) * 512 + d] = acc[mi][ni][r];
        }
    }
}

// legacy atomic wsum for MID fallback
__global__ __launch_bounds__(256) void wsum_mfma(const ushort* __restrict__ AT,
                                                 const ushort* __restrict__ XT,
                                                 float* __restrict__ WS) {
    __shared__ __align__(16) ushort sA[128 * 64];
    __shared__ __align__(16) ushort sB[128 * 64];
    const int tid = threadIdx.x;
    const int k0 = blockIdx.x * 128;
    const int d0 = blockIdx.y * 128;
    const long n0 = (long)blockIdx.z * 1024;
    const int wid = tid >> 6, lane = tid & 63;
    const int wm = wid >> 1, wn = wid & 1;
    const int lrow = lane & 15;
    const int lkb = lane >> 4;
    f32x4v acc[4][4] = {};
    for (int nc = 0; nc < 1024; nc += 64) {
        __syncthreads();
#pragma unroll
        for (int i = 0; i < 4; ++i) {
            const int sl = wid * 256 + i * 64 + lane;
            const int r = sl >> 3;
            const int s = sl & 7;
            const long goff = (long)r * 32768 + n0 + nc + ((s ^ (r & 7)) << 3);
            gload_lds16(AT + (long)k0 * 32768 + goff, &sA[(wid * 256 + i * 64) * 8]);
            gload_lds16(XT + (long)d0 * 32768 + goff, &sB[(wid * 256 + i * 64) * 8]);
        }
        __syncthreads();
#pragma unroll
        for (int kk = 0; kk < 2; ++kk) {
            const int j = kk * 4 + lkb;
            bf16x8 af[4], bfv[4];
#pragma unroll
            for (int mi = 0; mi < 4; ++mi) {
                const int R = wm * 64 + mi * 16 + lrow;
                af[mi] = *(const bf16x8*)&sA[R * 64 + ((j ^ (R & 7)) << 3)];
            }
#pragma unroll
            for (int ni = 0; ni < 4; ++ni) {
                const int R = wn * 64 + ni * 16 + lrow;
                bfv[ni] = *(const bf16x8*)&sB[R * 64 + ((j ^ (R & 7)) << 3)];
            }
#pragma unroll
            for (int mi = 0; mi < 4; ++mi)
#pragma unroll
                for (int ni = 0; ni < 4; ++ni)
                    acc[mi][ni] = __builtin_amdgcn_mfma_f32_16x16x32_bf16(af[mi], bfv[ni], acc[mi][ni], 0, 0, 0);
        }
    }
#pragma unroll
    for (int mi = 0; mi < 4; ++mi) {
        const int k = k0 + wm * 64 + mi * 16 + lkb * 4;
#pragma unroll
        for (int ni = 0; ni < 4; ++ni) {
            const int d = d0 + wn * 64 + ni * 16 + lrow;
#pragma unroll
            for (int r = 0; r < 4; ++r)
                atomicAdd(&WS[(k + r) * 512 + d], acc[mi][ni][r]);
        }
    }
}

// ---------------- reduce partials: WS = sum_z WSp[z] ----------------
__global__ __launch_bounds__(256) void reduce_ws(const float* __restrict__ WSp,
                                                 float* __restrict__ WS) {
    const int i4 = (blockIdx.x * 256 + threadIdx.x) * 4;  // grid 256 covers 262144 floats
    float4 s = {0.f, 0.f, 0.f, 0.f};
#pragma unroll 4
    for (int z = 0; z < 64; ++z) {
        float4 v = *(const float4*)(WSp + (size_t)z * 262144 + i4);
        s.x += v.x; s.y += v.y; s.z += v.z; s.w += v.w;
    }
    *(float4*)(WS + i4) = s;
}

// ---------------- fp32 wsum fallback ----------------
__global__ __launch_bounds__(256) void gemm_wsum(const float* __restrict__ A,
                                                 const float* __restrict__ X,
                                                 float* __restrict__ WS) {
    __shared__ float As[16][64];
    __shared__ float Xs[16][64];
    const int tid = threadIdx.x;
    const int tx = tid & 15, ty = tid >> 4;
    const int lrow = tid >> 4;
    const int lcol = (tid & 15) << 2;
    const int k0 = blockIdx.x * 64;
    const int d0 = blockIdx.y * 64;
    const int n0 = blockIdx.z * 1024;
    float acc[4][4] = {};
    for (int nc = 0; nc < 1024; nc += 16) {
        const long nrow = n0 + nc + lrow;
        float4 av = *(const float4*)(A + nrow * 512 + k0 + lcol);
        float4 xv = *(const float4*)(X + nrow * 512 + d0 + lcol);
        __syncthreads();
        *(float4*)&As[lrow][lcol] = av;
        *(float4*)&Xs[lrow][lcol] = xv;
        __syncthreads();
#pragma unroll
        for (int nn = 0; nn < 16; ++nn) {
            float4 a = *(const float4*)&As[nn][ty << 2];
            float4 x = *(const float4*)&Xs[nn][tx << 2];
            float aa[4] = {a.x, a.y, a.z, a.w};
            float xx[4] = {x.x, x.y, x.z, x.w};
#pragma unroll
            for (int i = 0; i < 4; ++i)
#pragma unroll
                for (int j = 0; j < 4; ++j) acc[i][j] += aa[i] * xx[j];
        }
    }
#pragma unroll
    for (int i = 0; i < 4; ++i)
#pragma unroll
        for (int j = 0; j < 4; ++j)
            atomicAdd(&WS[(k0 + (ty << 2) + i) * 512 + d0 + (tx << 2) + j], acc[i][j]);
}

// ---------------- repulsion + momentum update ----------------
__global__ __launch_bounds__(256) void repulse_update(const float* __restrict__ Cent,
                                                      const float* __restrict__ Mom,
                                                      const float* __restrict__ csq,
                                                      const float* __restrict__ WS,
                                                      const float* __restrict__ sum_w,
                                                      float* __restrict__ outC,
                                                      float* __restrict__ outM) {
    const int i = blockIdx.x;
    __shared__ float ci[512];
    __shared__ float rep[512];
    const int tid = threadIdx.x, wave = tid >> 6, lane = tid & 63;
    for (int d = tid; d < 512; d += 256) {
        ci[d] = Cent[i * 512 + d];
        rep[d] = 0.f;
    }
    __syncthreads();
    float cil[8];
#pragma unroll
    for (int m = 0; m < 8; ++m) cil[m] = ci[lane * 8 + m];
    const float csqi = csq[i];
    float racc[8] = {};
    for (int j = wave; j < 512; j += 4) {
        if (j == i) continue;
        const float* cj = Cent + j * 512 + lane * 8;
        float4 c0 = *(const float4*)cj;
        float4 c1 = *(const float4*)(cj + 4);
        float cjl[8] = {c0.x, c0.y, c0.z, c0.w, c1.x, c1.y, c1.z, c1.w};
        float dot = 0.f;
#pragma unroll
        for (int m = 0; m < 8; ++m) dot += cil[m] * cjl[m];
#pragma unroll
        for (int off = 1; off < 64; off <<= 1) dot += __shfl_xor(dot, off, 64);
        float sq = csqi + csq[j] - 2.f * dot;
        float dist = sqrtf(fmaxf(sq, 0.f) + EPSF);
        float w = fmaxf(0.f, 1.f - dist);
        float scale = 0.1f * w / (dist + EPSF);
#pragma unroll
        for (int m = 0; m < 8; ++m) racc[m] += scale * (cil[m] - cjl[m]);
    }
#pragma unroll
    for (int m = 0; m < 8; ++m) atomicAdd(&rep[lane * 8 + m], racc[m]);
    __syncthreads();
    const float invw = 1.0f / (sum_w[i] + EPSF);
    for (int d = tid; d < 512; d += 256) {
        float nc = WS[i * 512 + d] * invw;
        float upd = nc - ci[d] + rep[d];
        float mn = 0.9f * Mom[i * 512 + d] + 0.1f * upd;
        outM[i * 512 + d] = mn;
        outC[i * 512 + d] = ci[d] + 0.1f * mn;
    }
}

extern "C" void kernel_launch(void* const* d_in, const int* in_sizes, int n_in,
                              void* d_out, int out_size, void* d_ws, size_t ws_size,
                              hipStream_t stream) {
    const float* X = (const float*)d_in[0];      // (32768, 512)
    const float* C = (const float*)d_in[1];      // (512, 512)
    const float* M = (const float*)d_in[2];      // (512, 512)
    float* out = (float*)d_out;
    float* assign = out;                          // 32768*512
    float* outC = out + 16777216;                 // 512*512
    float* outM = outC + 262144;                  // 512*512

    char* wsb = (char*)d_ws;
    const size_t MB = 1024ull * 1024ull;
    // common header
    float* WS = (float*)wsb;                          // 1 MB
    float* sum_w = (float*)(wsb + 1 * MB);            // 2 KB
    float* csq = (float*)(wsb + 1 * MB + 4096);       // 2 KB
    ushort* Chp = (ushort*)(wsb + 1 * MB + 8192);     // 512 KB
    ushort* Clp = (ushort*)(wsb + 1 * MB + 8192 + 512 * 1024);  // 512 KB -> ends < 2.1 MB

    // BIG layout (need 132 MB): Xh@4MB, Xl@36MB (WSp overlaps Xh/Xl), XT@68MB, AT@100MB
    ushort* Xh = (ushort*)(wsb + 4 * MB);
    ushort* Xl = (ushort*)(wsb + 36 * MB);
    float* WSp = (float*)(wsb + 4 * MB);
    ushort* XTb = (ushort*)(wsb + 68 * MB);
    ushort* ATb = (ushort*)(wsb + 100 * MB);
    const size_t NEED_BIG = 132 * MB;
    // MID layout (R3-proven, need 66.1 MB): AT@2MB, XT@34MB
    ushort* ATm = (ushort*)(wsb + 2 * MB);
    ushort* XTm = (ushort*)(wsb + 2 * MB + 32 * MB);
    const size_t NEED_MID = 67 * MB;

    hipMemsetAsync(d_ws, 0, 1 * MB + 4096, stream);  // WS + sum_w
    csqc_kernel<<<128, 256, 0, stream>>>(C, csq, Chp, Clp);

    if (ws_size >= NEED_BIG) {
        convert_x<<<8192, 256, 0, stream>>>(X, Xh, Xl);
        logits_v2<<<dim3(4, 256), 256, 0, stream>>>(Xh, Xl, Chp, Clp, csq, assign);
        softmax_rows<<<512, 256, 0, stream>>>(assign, sum_w);
        transpose_to_bf16<<<dim3(512, 8), 256, 0, stream>>>(X, XTb, 32768);
        transpose_to_bf16<<<dim3(512, 8), 256, 0, stream>>>(assign, ATb, 32768);
        wsum_mfma_part<<<dim3(4, 4, 64), 256, 0, stream>>>(ATb, XTb, WSp);
        reduce_ws<<<256, 256, 0, stream>>>(WSp, WS);
    } else if (ws_size >= NEED_MID) {
        logits_mfma<<<dim3(256, 4), 256, 0, stream>>>(X, C, csq, assign);
        softmax_rows<<<512, 256, 0, stream>>>(assign, sum_w);
        transpose_to_bf16<<<dim3(512, 8), 256, 0, stream>>>(X, XTm, 32768);
        transpose_to_bf16<<<dim3(512, 8), 256, 0, stream>>>(assign, ATm, 32768);
        wsum_mfma<<<dim3(4, 4, 32), 256, 0, stream>>>(ATm, XTm, WS);
    } else {
        logits_mfma<<<dim3(256, 4), 256, 0, stream>>>(X, C, csq, assign);
        softmax_rows<<<512, 256, 0, stream>>>(assign, sum_w);
        gemm_wsum<<<dim3(8, 8, 32), 256, 0, stream>>>(assign, X, WS);
    }

    repulse_update<<<512, 256, 0, stream>>>(C, M, csq, WS, sum_w, outC, outM);
}

// Round 5
// 256.734 us; speedup vs baseline: 2.4514x; 1.1911x over previous
//
#include <hip/hip_runtime.h>
#include <hip/hip_bf16.h>

#define EPSF 1e-7f

typedef __attribute__((ext_vector_type(8))) short bf16x8;
typedef __attribute__((ext_vector_type(4))) float f32x4v;

__device__ inline ushort f2bf_bits(float x) {
    union { __hip_bfloat16 b; ushort u; } cv;
    cv.b = __float2bfloat16(x);
    return cv.u;
}
__device__ inline float bfbits2f(ushort u) {
    union { ushort u; __hip_bfloat16 b; } cv;
    cv.u = u;
    return __bfloat162float(cv.b);
}
__device__ inline void split2(float x, ushort& h, ushort& l) {
    h = f2bf_bits(x);
    l = f2bf_bits(x - bfbits2f(h));
}

__device__ inline void gload_lds16(const ushort* g, ushort* l) {
    __builtin_amdgcn_global_load_lds(
        (const __attribute__((address_space(1))) unsigned int*)g,
        (__attribute__((address_space(3))) unsigned int*)l, 16, 0, 0);
}

// ---------------- csq + C -> Ch/Cl bf16 split ----------------
__global__ __launch_bounds__(256) void csqc_kernel(const float* __restrict__ C,
                                                   float* __restrict__ csq,
                                                   ushort* __restrict__ Ch,
                                                   ushort* __restrict__ Cl) {
    const int wave = threadIdx.x >> 6, lane = threadIdx.x & 63;
    const int row = blockIdx.x * 4 + wave;
    const float* p = C + row * 512 + lane * 8;
    float4 a = *(const float4*)p;
    float4 b = *(const float4*)(p + 4);
    float v[8] = {a.x, a.y, a.z, a.w, b.x, b.y, b.z, b.w};
    ushort h[8], l[8];
    float s = 0.f;
#pragma unroll
    for (int i = 0; i < 8; ++i) {
        s += v[i] * v[i];
        split2(v[i], h[i], l[i]);
    }
    uint4 ph, pl;
    ph.x = (uint)h[0] | ((uint)h[1] << 16); ph.y = (uint)h[2] | ((uint)h[3] << 16);
    ph.z = (uint)h[4] | ((uint)h[5] << 16); ph.w = (uint)h[6] | ((uint)h[7] << 16);
    pl.x = (uint)l[0] | ((uint)l[1] << 16); pl.y = (uint)l[2] | ((uint)l[3] << 16);
    pl.z = (uint)l[4] | ((uint)l[5] << 16); pl.w = (uint)l[6] | ((uint)l[7] << 16);
    *(uint4*)(Ch + row * 512 + lane * 8) = ph;
    *(uint4*)(Cl + row * 512 + lane * 8) = pl;
#pragma unroll
    for (int off = 1; off < 64; off <<= 1) s += __shfl_xor(s, off, 64);
    if (lane == 0) csq[row] = s;
}

// ---------------- X -> Xh, Xl bf16 split (row-major) ----------------
__global__ __launch_bounds__(256) void convert_x(const float* __restrict__ X,
                                                 ushort* __restrict__ Xh,
                                                 ushort* __restrict__ Xl) {
    const long base = ((long)blockIdx.x * 256 + threadIdx.x) * 8;
    float4 a = *(const float4*)(X + base);
    float4 b = *(const float4*)(X + base + 4);
    float v[8] = {a.x, a.y, a.z, a.w, b.x, b.y, b.z, b.w};
    ushort h[8], l[8];
#pragma unroll
    for (int i = 0; i < 8; ++i) split2(v[i], h[i], l[i]);
    uint4 ph, pl;
    ph.x = (uint)h[0] | ((uint)h[1] << 16); ph.y = (uint)h[2] | ((uint)h[3] << 16);
    ph.z = (uint)h[4] | ((uint)h[5] << 16); ph.w = (uint)h[6] | ((uint)h[7] << 16);
    pl.x = (uint)l[0] | ((uint)l[1] << 16); pl.y = (uint)l[2] | ((uint)l[3] << 16);
    pl.z = (uint)l[4] | ((uint)l[5] << 16); pl.w = (uint)l[6] | ((uint)l[7] << 16);
    *(uint4*)(Xh + base) = ph;
    *(uint4*)(Xl + base) = pl;
}

// ---------------- logits v2: pure bf16 3-pass GEMM ----------------
__global__ __launch_bounds__(256) void logits_v2(const ushort* __restrict__ Xh,
                                                 const ushort* __restrict__ Xl,
                                                 const ushort* __restrict__ Ch,
                                                 const ushort* __restrict__ Cl,
                                                 const float* __restrict__ csq,
                                                 float* __restrict__ L) {
    __shared__ __align__(16) ushort sA[128 * 64];
    __shared__ __align__(16) ushort sB[128 * 64];
    const int tid = threadIdx.x;
    const int n0 = blockIdx.x * 128;
    const int m0 = blockIdx.y * 128;
    const int wid = tid >> 6, lane = tid & 63;
    const int wm = wid >> 1, wn = wid & 1;
    const int lrow = lane & 15, lkb = lane >> 4;
    f32x4v acc[4][4] = {};

#pragma unroll 1
    for (int p = 0; p < 3; ++p) {
        const ushort* Ab = (p == 2) ? Xl : Xh;
        const ushort* Bb = (p == 1) ? Cl : Ch;
#pragma unroll 1
        for (int kc = 0; kc < 8; ++kc) {
            __syncthreads();
#pragma unroll
            for (int i = 0; i < 4; ++i) {
                const int sl = i * 256 + tid;
                const int r = sl >> 3, s = sl & 7;
                const int kcol = kc * 64 + ((s ^ (r & 7)) << 3);
                gload_lds16(Ab + (long)(m0 + r) * 512 + kcol, &sA[(i * 256 + wid * 64) * 8]);
                gload_lds16(Bb + (long)(n0 + r) * 512 + kcol, &sB[(i * 256 + wid * 64) * 8]);
            }
            __syncthreads();
#pragma unroll
            for (int kk = 0; kk < 2; ++kk) {
                const int j = kk * 4 + lkb;
                bf16x8 af[4], bfv[4];
#pragma unroll
                for (int mi = 0; mi < 4; ++mi) {
                    const int R = wm * 64 + mi * 16 + lrow;
                    af[mi] = *(const bf16x8*)&sA[R * 64 + ((j ^ (R & 7)) << 3)];
                }
#pragma unroll
                for (int ni = 0; ni < 4; ++ni) {
                    const int R = wn * 64 + ni * 16 + lrow;
                    bfv[ni] = *(const bf16x8*)&sB[R * 64 + ((j ^ (R & 7)) << 3)];
                }
#pragma unroll
                for (int mi = 0; mi < 4; ++mi)
#pragma unroll
                    for (int ni = 0; ni < 4; ++ni)
                        acc[mi][ni] = __builtin_amdgcn_mfma_f32_16x16x32_bf16(af[mi], bfv[ni], acc[mi][ni], 0, 0, 0);
            }
        }
    }
    const int colb = n0 + wn * 64 + lrow;
    float cs[4];
#pragma unroll
    for (int ni = 0; ni < 4; ++ni) cs[ni] = csq[colb + ni * 16];
#pragma unroll
    for (int mi = 0; mi < 4; ++mi) {
        const int rowb = m0 + wm * 64 + mi * 16 + lkb * 4;
#pragma unroll
        for (int r = 0; r < 4; ++r) {
            float* Lp = L + (long)(rowb + r) * 512 + colb;
#pragma unroll
            for (int ni = 0; ni < 4; ++ni)
                Lp[ni * 16] = 2.0f * acc[mi][ni][r] - cs[ni];
        }
    }
}

// ---------------- gram -> repulsion S matrix + rowsum (split-bf16 MFMA) ----------------
// S[i][j] = 0.1*max(0,1-dist)/(dist+eps), dist = sqrt(max(csq_i+csq_j-2*G_ij,0)+eps); S[i][i]=0.
__global__ __launch_bounds__(256) void gram_s_mfma(const ushort* __restrict__ Ch,
                                                   const ushort* __restrict__ Cl,
                                                   const float* __restrict__ csq,
                                                   float* __restrict__ S,
                                                   float* __restrict__ rsum) {
    __shared__ __align__(16) ushort sA[128 * 64];
    __shared__ __align__(16) ushort sB[128 * 64];
    __shared__ float rs_s[128];
    const int tid = threadIdx.x;
    const int n0 = blockIdx.x * 128;
    const int m0 = blockIdx.y * 128;
    const int wid = tid >> 6, lane = tid & 63;
    const int wm = wid >> 1, wn = wid & 1;
    const int lrow = lane & 15, lkb = lane >> 4;
    f32x4v acc[4][4] = {};

#pragma unroll 1
    for (int p = 0; p < 3; ++p) {
        const ushort* Ab = (p == 2) ? Cl : Ch;
        const ushort* Bb = (p == 1) ? Cl : Ch;
#pragma unroll 1
        for (int kc = 0; kc < 8; ++kc) {
            __syncthreads();
#pragma unroll
            for (int i = 0; i < 4; ++i) {
                const int sl = i * 256 + tid;
                const int r = sl >> 3, s = sl & 7;
                const int kcol = kc * 64 + ((s ^ (r & 7)) << 3);
                gload_lds16(Ab + (long)(m0 + r) * 512 + kcol, &sA[(i * 256 + wid * 64) * 8]);
                gload_lds16(Bb + (long)(n0 + r) * 512 + kcol, &sB[(i * 256 + wid * 64) * 8]);
            }
            __syncthreads();
#pragma unroll
            for (int kk = 0; kk < 2; ++kk) {
                const int j = kk * 4 + lkb;
                bf16x8 af[4], bfv[4];
#pragma unroll
                for (int mi = 0; mi < 4; ++mi) {
                    const int R = wm * 64 + mi * 16 + lrow;
                    af[mi] = *(const bf16x8*)&sA[R * 64 + ((j ^ (R & 7)) << 3)];
                }
#pragma unroll
                for (int ni = 0; ni < 4; ++ni) {
                    const int R = wn * 64 + ni * 16 + lrow;
                    bfv[ni] = *(const bf16x8*)&sB[R * 64 + ((j ^ (R & 7)) << 3)];
                }
#pragma unroll
                for (int mi = 0; mi < 4; ++mi)
#pragma unroll
                    for (int ni = 0; ni < 4; ++ni)
                        acc[mi][ni] = __builtin_amdgcn_mfma_f32_16x16x32_bf16(af[mi], bfv[ni], acc[mi][ni], 0, 0, 0);
            }
        }
    }
    if (tid < 128) rs_s[tid] = 0.f;
    __syncthreads();
    const int colb = n0 + wn * 64 + lrow;
    float csj[4];
#pragma unroll
    for (int ni = 0; ni < 4; ++ni) csj[ni] = csq[colb + ni * 16];
#pragma unroll
    for (int mi = 0; mi < 4; ++mi) {
        const int rowb = m0 + wm * 64 + mi * 16 + lkb * 4;
#pragma unroll
        for (int r = 0; r < 4; ++r) {
            const int row = rowb + r;
            const float csi = csq[row];
            float rowpart = 0.f;
#pragma unroll
            for (int ni = 0; ni < 4; ++ni) {
                const int col = colb + ni * 16;
                float sq = csi + csj[ni] - 2.0f * acc[mi][ni][r];
                float dist = sqrtf(fmaxf(sq, 0.f) + EPSF);
                float w = fmaxf(0.f, 1.f - dist);
                float sval = (row == col) ? 0.f : (0.1f * w / (dist + EPSF));
                S[(long)row * 512 + col] = sval;
                rowpart += sval;
            }
            atomicAdd(&rs_s[row - m0], rowpart);
        }
    }
    __syncthreads();
    if (tid < 128) atomicAdd(&rsum[m0 + tid], rs_s[tid]);
}

// ---------------- fused repulsion-apply + momentum update ----------------
__global__ __launch_bounds__(256) void apply_update(const float* __restrict__ Cent,
                                                    const float* __restrict__ Mom,
                                                    const float* __restrict__ S,
                                                    const float* __restrict__ rsum,
                                                    const float* __restrict__ WS,
                                                    const float* __restrict__ sum_w,
                                                    float* __restrict__ outC,
                                                    float* __restrict__ outM) {
    const int i = blockIdx.x;
    __shared__ float srow[512];
    __shared__ int nz;
    const int tid = threadIdx.x;
    if (tid == 0) nz = 0;
    __syncthreads();
    float2 sv = *(const float2*)(S + (long)i * 512 + tid * 2);
    srow[tid * 2] = sv.x;
    srow[tid * 2 + 1] = sv.y;
    if (sv.x != 0.f || sv.y != 0.f) nz = 1;
    __syncthreads();
    const float rs = rsum[i];
    const float invw = 1.0f / (sum_w[i] + EPSF);
    const int d0 = tid * 2;
    float sc0 = 0.f, sc1 = 0.f;
    if (nz) {
        // correctness path (taken only if any repulsion weight is nonzero)
        for (int j = 0; j < 512; ++j) {
            const float s = srow[j];
            if (s != 0.f) {
                sc0 += s * Cent[(long)j * 512 + d0];
                sc1 += s * Cent[(long)j * 512 + d0 + 1];
            }
        }
    }
    float2 ci = *(const float2*)(Cent + (long)i * 512 + d0);
    float2 mo = *(const float2*)(Mom + (long)i * 512 + d0);
    float2 wsv = *(const float2*)(WS + (long)i * 512 + d0);
    float rep0 = rs * ci.x - sc0;
    float rep1 = rs * ci.y - sc1;
    float mn0 = 0.9f * mo.x + 0.1f * (wsv.x * invw - ci.x + rep0);
    float mn1 = 0.9f * mo.y + 0.1f * (wsv.y * invw - ci.y + rep1);
    float2 om = {mn0, mn1};
    float2 oc = {ci.x + 0.1f * mn0, ci.y + 0.1f * mn1};
    *(float2*)(outM + (long)i * 512 + d0) = om;
    *(float2*)(outC + (long)i * 512 + d0) = oc;
}

// ---------------- legacy logits (in-kernel split) for fallback paths ----------------
__global__ __launch_bounds__(256) void logits_mfma(const float* __restrict__ X,
                                                   const float* __restrict__ Cm,
                                                   const float* __restrict__ csq,
                                                   float* __restrict__ L) {
    __shared__ ushort sAh[128][64];
    __shared__ ushort sAl[128][64];
    __shared__ ushort sBh[128][64];
    __shared__ ushort sBl[128][64];
    const int tid = threadIdx.x;
    const int m0 = blockIdx.x * 128;
    const int n0 = blockIdx.y * 128;
    const int wid = tid >> 6, lane = tid & 63;
    const int wm = wid >> 1, wn = wid & 1;
    const int lrow = lane & 15;
    const int lkb = lane >> 4;
    f32x4v acc[4][4] = {};
    for (int k0 = 0; k0 < 512; k0 += 64) {
        __syncthreads();
#pragma unroll
        for (int s = 0; s < 8; ++s) {
            const int idx = s * 256 + tid;
            const int r = idx >> 4;
            const int c4 = (idx & 15) << 2;
            const int e = c4 ^ ((r & 7) << 3);
            float4 va = *(const float4*)(X + (long)(m0 + r) * 512 + k0 + c4);
            ushort4 hh, ll;
            split2(va.x, hh.x, ll.x);
            split2(va.y, hh.y, ll.y);
            split2(va.z, hh.z, ll.z);
            split2(va.w, hh.w, ll.w);
            *(ushort4*)&sAh[r][e] = hh;
            *(ushort4*)&sAl[r][e] = ll;
            float4 vb = *(const float4*)(Cm + (long)(n0 + r) * 512 + k0 + c4);
            split2(vb.x, hh.x, ll.x);
            split2(vb.y, hh.y, ll.y);
            split2(vb.z, hh.z, ll.z);
            split2(vb.w, hh.w, ll.w);
            *(ushort4*)&sBh[r][e] = hh;
            *(ushort4*)&sBl[r][e] = ll;
        }
        __syncthreads();
#pragma unroll
        for (int kk = 0; kk < 2; ++kk) {
            const int ebase = kk * 32 + lkb * 8;
            bf16x8 ah[4], al[4], bh[4], bl[4];
#pragma unroll
            for (int mi = 0; mi < 4; ++mi) {
                const int R = wm * 64 + mi * 16 + lrow;
                const int e = ebase ^ ((R & 7) << 3);
                ah[mi] = *(const bf16x8*)&sAh[R][e];
                al[mi] = *(const bf16x8*)&sAl[R][e];
            }
#pragma unroll
            for (int ni = 0; ni < 4; ++ni) {
                const int Rn = wn * 64 + ni * 16 + lrow;
                const int e = ebase ^ ((Rn & 7) << 3);
                bh[ni] = *(const bf16x8*)&sBh[Rn][e];
                bl[ni] = *(const bf16x8*)&sBl[Rn][e];
            }
#pragma unroll
            for (int mi = 0; mi < 4; ++mi)
#pragma unroll
                for (int ni = 0; ni < 4; ++ni) {
                    acc[mi][ni] = __builtin_amdgcn_mfma_f32_16x16x32_bf16(ah[mi], bh[ni], acc[mi][ni], 0, 0, 0);
                    acc[mi][ni] = __builtin_amdgcn_mfma_f32_16x16x32_bf16(ah[mi], bl[ni], acc[mi][ni], 0, 0, 0);
                    acc[mi][ni] = __builtin_amdgcn_mfma_f32_16x16x32_bf16(al[mi], bh[ni], acc[mi][ni], 0, 0, 0);
                }
        }
    }
    const int colb = n0 + wn * 64 + lrow;
    float cs[4];
#pragma unroll
    for (int ni = 0; ni < 4; ++ni) cs[ni] = csq[colb + ni * 16];
#pragma unroll
    for (int mi = 0; mi < 4; ++mi) {
        const int rowb = m0 + wm * 64 + mi * 16 + lkb * 4;
#pragma unroll
        for (int r = 0; r < 4; ++r) {
            float* Lp = L + (long)(rowb + r) * 512 + colb;
#pragma unroll
            for (int ni = 0; ni < 4; ++ni)
                Lp[ni * 16] = 2.0f * acc[mi][ni][r] - cs[ni];
        }
    }
}

// ---------------- in-place row softmax (scale 1/T=10) + sum_w ----------------
__global__ __launch_bounds__(256) void softmax_rows(float* __restrict__ L,
                                                    float* __restrict__ sum_w) {
    __shared__ float swacc[512];
    const int tid = threadIdx.x;
    for (int i = tid; i < 512; i += 256) swacc[i] = 0.f;
    __syncthreads();
    const int wave = tid >> 6, lane = tid & 63;
    float racc[8] = {};
    for (int r = blockIdx.x * 4 + wave; r < 32768; r += 2048) {
        float* p = L + (long)r * 512 + lane * 8;
        float4 v0 = *(float4*)p;
        float4 v1 = *(float4*)(p + 4);
        float v[8] = {v0.x, v0.y, v0.z, v0.w, v1.x, v1.y, v1.z, v1.w};
        float m = v[0];
#pragma unroll
        for (int i = 1; i < 8; ++i) m = fmaxf(m, v[i]);
#pragma unroll
        for (int off = 1; off < 64; off <<= 1) m = fmaxf(m, __shfl_xor(m, off, 64));
        float e[8], s = 0.f;
#pragma unroll
        for (int i = 0; i < 8; ++i) {
            e[i] = expf((v[i] - m) * 10.0f);
            s += e[i];
        }
#pragma unroll
        for (int off = 1; off < 64; off <<= 1) s += __shfl_xor(s, off, 64);
        const float inv = 1.0f / (s + EPSF);
#pragma unroll
        for (int i = 0; i < 8; ++i) {
            e[i] *= inv;
            racc[i] += e[i];
        }
        float4 o0 = {e[0], e[1], e[2], e[3]};
        float4 o1 = {e[4], e[5], e[6], e[7]};
        *(float4*)p = o0;
        *(float4*)(p + 4) = o1;
    }
#pragma unroll
    for (int i = 0; i < 8; ++i) atomicAdd(&swacc[lane * 8 + i], racc[i]);
    __syncthreads();
    for (int i = tid; i < 512; i += 256) atomicAdd(&sum_w[i], swacc[i]);
}

// ---------------- transpose f32 [R][512] -> bf16 [512][R] ----------------
__global__ __launch_bounds__(256) void transpose_to_bf16(const float* __restrict__ in,
                                                         ushort* __restrict__ out, int R) {
    __shared__ uint st[64 * 32];
    const int t = threadIdx.x;
    const int r0 = blockIdx.x * 64;
    const int c0 = blockIdx.y * 64;
#pragma unroll
    for (int s = 0; s < 2; ++s) {
        const int idx = s * 256 + t;
        const int c = idx & 63;
        const int ro = idx >> 6;
        float v[8];
#pragma unroll
        for (int j = 0; j < 8; ++j)
            v[j] = in[(long)(r0 + ro * 8 + j) * 512 + c0 + c];
        uint4 w;
        w.x = (uint)f2bf_bits(v[0]) | ((uint)f2bf_bits(v[1]) << 16);
        w.y = (uint)f2bf_bits(v[2]) | ((uint)f2bf_bits(v[3]) << 16);
        w.z = (uint)f2bf_bits(v[4]) | ((uint)f2bf_bits(v[5]) << 16);
        w.w = (uint)f2bf_bits(v[6]) | ((uint)f2bf_bits(v[7]) << 16);
        const int sl = ro ^ (c & 7);
        *(uint4*)&st[c * 32 + sl * 4] = w;
    }
    __syncthreads();
#pragma unroll
    for (int s = 0; s < 2; ++s) {
        const int idx = s * 256 + t;
        const int c = idx >> 3;
        const int sl = idx & 7;
        uint4 w = *(const uint4*)&st[c * 32 + (sl ^ (c & 7)) * 4];
        *(uint4*)(out + (long)(c0 + c) * R + r0 + sl * 8) = w;
    }
}

// ---------------- wsum partials ----------------
__global__ __launch_bounds__(256) void wsum_mfma_part(const ushort* __restrict__ AT,
                                                      const ushort* __restrict__ XT,
                                                      float* __restrict__ WSp) {
    __shared__ __align__(16) ushort sA[128 * 64];
    __shared__ __align__(16) ushort sB[128 * 64];
    const int tid = threadIdx.x;
    const int k0 = blockIdx.x * 128;
    const int d0 = blockIdx.y * 128;
    const long n0 = (long)blockIdx.z * 512;
    const int wid = tid >> 6, lane = tid & 63;
    const int wm = wid >> 1, wn = wid & 1;
    const int lrow = lane & 15;
    const int lkb = lane >> 4;
    f32x4v acc[4][4] = {};

    for (int nc = 0; nc < 512; nc += 64) {
        __syncthreads();
#pragma unroll
        for (int i = 0; i < 4; ++i) {
            const int sl = wid * 256 + i * 64 + lane;
            const int r = sl >> 3;
            const int s = sl & 7;
            const long goff = (long)r * 32768 + n0 + nc + ((s ^ (r & 7)) << 3);
            gload_lds16(AT + (long)k0 * 32768 + goff, &sA[(wid * 256 + i * 64) * 8]);
            gload_lds16(XT + (long)d0 * 32768 + goff, &sB[(wid * 256 + i * 64) * 8]);
        }
        __syncthreads();
#pragma unroll
        for (int kk = 0; kk < 2; ++kk) {
            const int j = kk * 4 + lkb;
            bf16x8 af[4], bfv[4];
#pragma unroll
            for (int mi = 0; mi < 4; ++mi) {
                const int R = wm * 64 + mi * 16 + lrow;
                af[mi] = *(const bf16x8*)&sA[R * 64 + ((j ^ (R & 7)) << 3)];
            }
#pragma unroll
            for (int ni = 0; ni < 4; ++ni) {
                const int R = wn * 64 + ni * 16 + lrow;
                bfv[ni] = *(const bf16x8*)&sB[R * 64 + ((j ^ (R & 7)) << 3)];
            }
#pragma unroll
            for (int mi = 0; mi < 4; ++mi)
#pragma unroll
                for (int ni = 0; ni < 4; ++ni)
                    acc[mi][ni] = __builtin_amdgcn_mfma_f32_16x16x32_bf16(af[mi], bfv[ni], acc[mi][ni], 0, 0, 0);
        }
    }
    float* dst = WSp + (size_t)blockIdx.z * 262144;
#pragma unroll
    for (int mi = 0; mi < 4; ++mi) {
        const int k = k0 + wm * 64 + mi * 16 + lkb * 4;
#pragma unroll
        for (int ni = 0; ni < 4; ++ni) {
            const int d = d0 + wn * 64 + ni * 16 + lrow;
#pragma unroll
            for (int r = 0; r < 4; ++r)
                dst[(k + r) * 512 + d] = acc[mi][ni][r];
        }
    }
}

// legacy atomic wsum for MID fallback
__global__ __launch_bounds__(256) void wsum_mfma(const ushort* __restrict__ AT,
                                                 const ushort* __restrict__ XT,
                                                 float* __restrict__ WS) {
    __shared__ __align__(16) ushort sA[128 * 64];
    __shared__ __align__(16) ushort sB[128 * 64];
    const int tid = threadIdx.x;
    const int k0 = blockIdx.x * 128;
    const int d0 = blockIdx.y * 128;
    const long n0 = (long)blockIdx.z * 1024;
    const int wid = tid >> 6, lane = tid & 63;
    const int wm = wid >> 1, wn = wid & 1;
    const int lrow = lane & 15;
    const int lkb = lane >> 4;
    f32x4v acc[4][4] = {};
    for (int nc = 0; nc < 1024; nc += 64) {
        __syncthreads();
#pragma unroll
        for (int i = 0; i < 4; ++i) {
            const int sl = wid * 256 + i * 64 + lane;
            const int r = sl >> 3;
            const int s = sl & 7;
            const long goff = (long)r * 32768 + n0 + nc + ((s ^ (r & 7)) << 3);
            gload_lds16(AT + (long)k0 * 32768 + goff, &sA[(wid * 256 + i * 64) * 8]);
            gload_lds16(XT + (long)d0 * 32768 + goff, &sB[(wid * 256 + i * 64) * 8]);
        }
        __syncthreads();
#pragma unroll
        for (int kk = 0; kk < 2; ++kk) {
            const int j = kk * 4 + lkb;
            bf16x8 af[4], bfv[4];
#pragma unroll
            for (int mi = 0; mi < 4; ++mi) {
                const int R = wm * 64 + mi * 16 + lrow;
                af[mi] = *(const bf16x8*)&sA[R * 64 + ((j ^ (R & 7)) << 3)];
            }
#pragma unroll
            for (int ni = 0; ni < 4; ++ni) {
                const int R = wn * 64 + ni * 16 + lrow;
                bfv[ni] = *(const bf16x8*)&sB[R * 64 + ((j ^ (R & 7)) << 3)];
            }
#pragma unroll
            for (int mi = 0; mi < 4; ++mi)
#pragma unroll
                for (int ni = 0; ni < 4; ++ni)
                    acc[mi][ni] = __builtin_amdgcn_mfma_f32_16x16x32_bf16(af[mi], bfv[ni], acc[mi][ni], 0, 0, 0);
        }
    }
#pragma unroll
    for (int mi = 0; mi < 4; ++mi) {
        const int k = k0 + wm * 64 + mi * 16 + lkb * 4;
#pragma unroll
        for (int ni = 0; ni < 4; ++ni) {
            const int d = d0 + wn * 64 + ni * 16 + lrow;
#pragma unroll
            for (int r = 0; r < 4; ++r)
                atomicAdd(&WS[(k + r) * 512 + d], acc[mi][ni][r]);
        }
    }
}

// ---------------- reduce partials: WS = sum_z WSp[z] ----------------
__global__ __launch_bounds__(256) void reduce_ws(const float* __restrict__ WSp,
                                                 float* __restrict__ WS) {
    const int i4 = (blockIdx.x * 256 + threadIdx.x) * 4;
    float4 s = {0.f, 0.f, 0.f, 0.f};
#pragma unroll 4
    for (int z = 0; z < 64; ++z) {
        float4 v = *(const float4*)(WSp + (size_t)z * 262144 + i4);
        s.x += v.x; s.y += v.y; s.z += v.z; s.w += v.w;
    }
    *(float4*)(WS + i4) = s;
}

// ---------------- fp32 wsum fallback ----------------
__global__ __launch_bounds__(256) void gemm_wsum(const float* __restrict__ A,
                                                 const float* __restrict__ X,
                                                 float* __restrict__ WS) {
    __shared__ float As[16][64];
    __shared__ float Xs[16][64];
    const int tid = threadIdx.x;
    const int tx = tid & 15, ty = tid >> 4;
    const int lrow = tid >> 4;
    const int lcol = (tid & 15) << 2;
    const int k0 = blockIdx.x * 64;
    const int d0 = blockIdx.y * 64;
    const int n0 = blockIdx.z * 1024;
    float acc[4][4] = {};
    for (int nc = 0; nc < 1024; nc += 16) {
        const long nrow = n0 + nc + lrow;
        float4 av = *(const float4*)(A + nrow * 512 + k0 + lcol);
        float4 xv = *(const float4*)(X + nrow * 512 + d0 + lcol);
        __syncthreads();
        *(float4*)&As[lrow][lcol] = av;
        *(float4*)&Xs[lrow][lcol] = xv;
        __syncthreads();
#pragma unroll
        for (int nn = 0; nn < 16; ++nn) {
            float4 a = *(const float4*)&As[nn][ty << 2];
            float4 x = *(const float4*)&Xs[nn][tx << 2];
            float aa[4] = {a.x, a.y, a.z, a.w};
            float xx[4] = {x.x, x.y, x.z, x.w};
#pragma unroll
            for (int i = 0; i < 4; ++i)
#pragma unroll
                for (int j = 0; j < 4; ++j) acc[i][j] += aa[i] * xx[j];
        }
    }
#pragma unroll
    for (int i = 0; i < 4; ++i)
#pragma unroll
        for (int j = 0; j < 4; ++j)
            atomicAdd(&WS[(k0 + (ty << 2) + i) * 512 + d0 + (tx << 2) + j], acc[i][j]);
}

// ---------------- legacy repulsion + momentum update (fallback paths) ----------------
__global__ __launch_bounds__(256) void repulse_update(const float* __restrict__ Cent,
                                                      const float* __restrict__ Mom,
                                                      const float* __restrict__ csq,
                                                      const float* __restrict__ WS,
                                                      const float* __restrict__ sum_w,
                                                      float* __restrict__ outC,
                                                      float* __restrict__ outM) {
    const int i = blockIdx.x;
    __shared__ float ci[512];
    __shared__ float rep[512];
    const int tid = threadIdx.x, wave = tid >> 6, lane = tid & 63;
    for (int d = tid; d < 512; d += 256) {
        ci[d] = Cent[i * 512 + d];
        rep[d] = 0.f;
    }
    __syncthreads();
    float cil[8];
#pragma unroll
    for (int m = 0; m < 8; ++m) cil[m] = ci[lane * 8 + m];
    const float csqi = csq[i];
    float racc[8] = {};
    for (int j = wave; j < 512; j += 4) {
        if (j == i) continue;
        const float* cj = Cent + j * 512 + lane * 8;
        float4 c0 = *(const float4*)cj;
        float4 c1 = *(const float4*)(cj + 4);
        float cjl[8] = {c0.x, c0.y, c0.z, c0.w, c1.x, c1.y, c1.z, c1.w};
        float dot = 0.f;
#pragma unroll
        for (int m = 0; m < 8; ++m) dot += cil[m] * cjl[m];
#pragma unroll
        for (int off = 1; off < 64; off <<= 1) dot += __shfl_xor(dot, off, 64);
        float sq = csqi + csq[j] - 2.f * dot;
        float dist = sqrtf(fmaxf(sq, 0.f) + EPSF);
        float w = fmaxf(0.f, 1.f - dist);
        float scale = 0.1f * w / (dist + EPSF);
#pragma unroll
        for (int m = 0; m < 8; ++m) racc[m] += scale * (cil[m] - cjl[m]);
    }
#pragma unroll
    for (int m = 0; m < 8; ++m) atomicAdd(&rep[lane * 8 + m], racc[m]);
    __syncthreads();
    const float invw = 1.0f / (sum_w[i] + EPSF);
    for (int d = tid; d < 512; d += 256) {
        float nc = WS[i * 512 + d] * invw;
        float upd = nc - ci[d] + rep[d];
        float mn = 0.9f * Mom[i * 512 + d] + 0.1f * upd;
        outM[i * 512 + d] = mn;
        outC[i * 512 + d] = ci[d] + 0.1f * mn;
    }
}

extern "C" void kernel_launch(void* const* d_in, const int* in_sizes, int n_in,
                              void* d_out, int out_size, void* d_ws, size_t ws_size,
                              hipStream_t stream) {
    const float* X = (const float*)d_in[0];      // (32768, 512)
    const float* C = (const float*)d_in[1];      // (512, 512)
    const float* M = (const float*)d_in[2];      // (512, 512)
    float* out = (float*)d_out;
    float* assign = out;                          // 32768*512
    float* outC = out + 16777216;                 // 512*512
    float* outM = outC + 262144;                  // 512*512

    char* wsb = (char*)d_ws;
    const size_t MB = 1024ull * 1024ull;
    // common header
    float* WS = (float*)wsb;                          // 1 MB
    float* sum_w = (float*)(wsb + 1 * MB);            // 2 KB
    float* rsum = (float*)(wsb + 1 * MB + 2048);      // 2 KB
    float* csq = (float*)(wsb + 1 * MB + 4096);       // 2 KB
    ushort* Chp = (ushort*)(wsb + 1 * MB + 8192);     // 512 KB
    ushort* Clp = (ushort*)(wsb + 1 * MB + 8192 + 512 * 1024);  // 512 KB
    float* S = (float*)(wsb + 3 * MB);                // 1 MB (repulsion weight matrix)

    // BIG layout (need 132 MB): Xh@4MB, Xl@36MB (WSp overlaps Xh/Xl), XT@68MB, AT@100MB
    ushort* Xh = (ushort*)(wsb + 4 * MB);
    ushort* Xl = (ushort*)(wsb + 36 * MB);
    float* WSp = (float*)(wsb + 4 * MB);
    ushort* XTb = (ushort*)(wsb + 68 * MB);
    ushort* ATb = (ushort*)(wsb + 100 * MB);
    const size_t NEED_BIG = 132 * MB;
    // MID layout (need 66.1 MB): AT@2MB, XT@34MB  (no S-path; uses legacy repulse)
    ushort* ATm = (ushort*)(wsb + 2 * MB);
    ushort* XTm = (ushort*)(wsb + 2 * MB + 32 * MB);
    const size_t NEED_MID = 67 * MB;

    hipMemsetAsync(d_ws, 0, 1 * MB + 4096, stream);  // WS + sum_w + rsum
    csqc_kernel<<<128, 256, 0, stream>>>(C, csq, Chp, Clp);

    if (ws_size >= NEED_BIG) {
        gram_s_mfma<<<dim3(4, 4), 256, 0, stream>>>(Chp, Clp, csq, S, rsum);
        convert_x<<<8192, 256, 0, stream>>>(X, Xh, Xl);
        logits_v2<<<dim3(4, 256), 256, 0, stream>>>(Xh, Xl, Chp, Clp, csq, assign);
        softmax_rows<<<512, 256, 0, stream>>>(assign, sum_w);
        transpose_to_bf16<<<dim3(512, 8), 256, 0, stream>>>(X, XTb, 32768);
        transpose_to_bf16<<<dim3(512, 8), 256, 0, stream>>>(assign, ATb, 32768);
        wsum_mfma_part<<<dim3(4, 4, 64), 256, 0, stream>>>(ATb, XTb, WSp);
        reduce_ws<<<256, 256, 0, stream>>>(WSp, WS);
        apply_update<<<512, 256, 0, stream>>>(C, M, S, rsum, WS, sum_w, outC, outM);
    } else if (ws_size >= NEED_MID) {
        logits_mfma<<<dim3(256, 4), 256, 0, stream>>>(X, C, csq, assign);
        softmax_rows<<<512, 256, 0, stream>>>(assign, sum_w);
        transpose_to_bf16<<<dim3(512, 8), 256, 0, stream>>>(X, XTm, 32768);
        transpose_to_bf16<<<dim3(512, 8), 256, 0, stream>>>(assign, ATm, 32768);
        wsum_mfma<<<dim3(4, 4, 32), 256, 0, stream>>>(ATm, XTm, WS);
        repulse_update<<<512, 256, 0, stream>>>(C, M, csq, WS, sum_w, outC, outM);
    } else {
        logits_mfma<<<dim3(256, 4), 256, 0, stream>>>(X, C, csq, assign);
        softmax_rows<<<512, 256, 0, stream>>>(assign, sum_w);
        gemm_wsum<<<dim3(8, 8, 32), 256, 0, stream>>>(assign, X, WS);
        repulse_update<<<512, 256, 0, stream>>>(C, M, csq, WS, sum_w, outC, outM);
    }
}

// Round 6
// 227.486 us; speedup vs baseline: 2.7666x; 1.1286x over previous
//
#include <hip/hip_runtime.h>
#include <hip/hip_bf16.h>

#define EPSF 1e-7f

typedef __attribute__((ext_vector_type(8))) short bf16x8;
typedef __attribute__((ext_vector_type(4))) float f32x4v;

__device__ inline ushort f2bf_bits(float x) {
    union { __hip_bfloat16 b; ushort u; } cv;
    cv.b = __float2bfloat16(x);
    return cv.u;
}
__device__ inline float bfbits2f(ushort u) {
    union { ushort u; __hip_bfloat16 b; } cv;
    cv.u = u;
    return __bfloat162float(cv.b);
}
__device__ inline void split2(float x, ushort& h, ushort& l) {
    h = f2bf_bits(x);
    l = f2bf_bits(x - bfbits2f(h));
}
__device__ inline uint4 pack8(const ushort* h) {
    uint4 p;
    p.x = (uint)h[0] | ((uint)h[1] << 16);
    p.y = (uint)h[2] | ((uint)h[3] << 16);
    p.z = (uint)h[4] | ((uint)h[5] << 16);
    p.w = (uint)h[6] | ((uint)h[7] << 16);
    return p;
}

__device__ inline void gload_lds16(const ushort* g, ushort* l) {
    __builtin_amdgcn_global_load_lds(
        (const __attribute__((address_space(1))) unsigned int*)g,
        (__attribute__((address_space(3))) unsigned int*)l, 16, 0, 0);
}

// ---------------- csq + C -> Chl (interleaved hi/lo per 32-k chunk) ----------------
// Chl[row][kc*64 + s*8 .. ] : s<4 -> hi oct, s-4 -> lo oct (layout: hi[32] | lo[32] per kc)
__global__ __launch_bounds__(256) void csqc_v3(const float* __restrict__ C,
                                               float* __restrict__ csq,
                                               ushort* __restrict__ Chl) {
    const int wave = threadIdx.x >> 6, lane = threadIdx.x & 63;
    const int row = blockIdx.x * 4 + wave;
    const int kc = lane >> 2, s = lane & 3;
    const float* p = C + row * 512 + lane * 8;
    float4 a = *(const float4*)p;
    float4 b = *(const float4*)(p + 4);
    float v[8] = {a.x, a.y, a.z, a.w, b.x, b.y, b.z, b.w};
    ushort h[8], l[8];
    float sqs = 0.f;
#pragma unroll
    for (int i = 0; i < 8; ++i) {
        sqs += v[i] * v[i];
        split2(v[i], h[i], l[i]);
    }
    ushort* base = Chl + (long)row * 1024 + kc * 64 + s * 8;
    *(uint4*)base = pack8(h);
    *(uint4*)(base + 32) = pack8(l);
#pragma unroll
    for (int off = 1; off < 64; off <<= 1) sqs += __shfl_xor(sqs, off, 64);
    if (lane == 0) csq[row] = sqs;
}

// ---------------- X -> Xhl (interleaved hi/lo) ----------------
__global__ __launch_bounds__(256) void convert_xhl(const float* __restrict__ X,
                                                   ushort* __restrict__ Xhl) {
    const long idx = (long)blockIdx.x * 256 + threadIdx.x;   // 2,097,152 octets
    const long row = idx >> 6;
    const int oct = (int)(idx & 63);
    const int kc = oct >> 2, s = oct & 3;
    const float* src = X + row * 512 + oct * 8;
    float4 a = *(const float4*)src;
    float4 b = *(const float4*)(src + 4);
    float v[8] = {a.x, a.y, a.z, a.w, b.x, b.y, b.z, b.w};
    ushort h[8], l[8];
#pragma unroll
    for (int i = 0; i < 8; ++i) split2(v[i], h[i], l[i]);
    ushort* base = Xhl + row * 1024 + kc * 64 + s * 8;
    *(uint4*)base = pack8(h);
    *(uint4*)(base + 32) = pack8(l);
}

// ---------------- logits v3: single-read split-bf16 GEMM ----------------
// Per 32-k chunk: stage hi+lo of A and B (32 KB LDS), 3 MFMA passes.
__global__ __launch_bounds__(256) void logits_v3(const ushort* __restrict__ Xhl,
                                                 const ushort* __restrict__ Chl,
                                                 const float* __restrict__ csq,
                                                 float* __restrict__ L) {
    __shared__ __align__(16) ushort sA[128 * 64];
    __shared__ __align__(16) ushort sB[128 * 64];
    const int tid = threadIdx.x;
    const int n0 = blockIdx.x * 128;
    const int m0 = blockIdx.y * 128;
    const int wid = tid >> 6, lane = tid & 63;
    const int wm = wid >> 1, wn = wid & 1;
    const int lrow = lane & 15, lkb = lane >> 4;
    f32x4v acc[4][4] = {};

#pragma unroll 1
    for (int kc = 0; kc < 16; ++kc) {
        __syncthreads();
#pragma unroll
        for (int i = 0; i < 4; ++i) {
            const int sl = wid * 256 + i * 64 + lane;   // 0..1023
            const int r = sl >> 3, j = sl & 7;
            const int s = j ^ (r & 7);                  // logical slot (s<4 hi, s>=4 lo)
            gload_lds16(Xhl + (long)(m0 + r) * 1024 + kc * 64 + s * 8,
                        &sA[(wid * 256 + i * 64) * 8]);
            gload_lds16(Chl + (long)(n0 + r) * 1024 + kc * 64 + s * 8,
                        &sB[(wid * 256 + i * 64) * 8]);
        }
        __syncthreads();
        bf16x8 ah[4], al[4], bh[4], bl[4];
#pragma unroll
        for (int mi = 0; mi < 4; ++mi) {
            const int R = wm * 64 + mi * 16 + lrow;
            ah[mi] = *(const bf16x8*)&sA[R * 64 + ((lkb ^ (R & 7)) << 3)];
            al[mi] = *(const bf16x8*)&sA[R * 64 + (((lkb + 4) ^ (R & 7)) << 3)];
        }
#pragma unroll
        for (int ni = 0; ni < 4; ++ni) {
            const int R = wn * 64 + ni * 16 + lrow;
            bh[ni] = *(const bf16x8*)&sB[R * 64 + ((lkb ^ (R & 7)) << 3)];
            bl[ni] = *(const bf16x8*)&sB[R * 64 + (((lkb + 4) ^ (R & 7)) << 3)];
        }
#pragma unroll
        for (int mi = 0; mi < 4; ++mi)
#pragma unroll
            for (int ni = 0; ni < 4; ++ni) {
                acc[mi][ni] = __builtin_amdgcn_mfma_f32_16x16x32_bf16(ah[mi], bh[ni], acc[mi][ni], 0, 0, 0);
                acc[mi][ni] = __builtin_amdgcn_mfma_f32_16x16x32_bf16(ah[mi], bl[ni], acc[mi][ni], 0, 0, 0);
                acc[mi][ni] = __builtin_amdgcn_mfma_f32_16x16x32_bf16(al[mi], bh[ni], acc[mi][ni], 0, 0, 0);
            }
    }
    const int colb = n0 + wn * 64 + lrow;
    float cs[4];
#pragma unroll
    for (int ni = 0; ni < 4; ++ni) cs[ni] = csq[colb + ni * 16];
#pragma unroll
    for (int mi = 0; mi < 4; ++mi) {
        const int rowb = m0 + wm * 64 + mi * 16 + lkb * 4;
#pragma unroll
        for (int r = 0; r < 4; ++r) {
            float* Lp = L + (long)(rowb + r) * 512 + colb;
#pragma unroll
            for (int ni = 0; ni < 4; ++ni)
                Lp[ni * 16] = 2.0f * acc[mi][ni][r] - cs[ni];
        }
    }
}

// ---------------- gram -> S + rowsum, on Chl ----------------
__global__ __launch_bounds__(256) void gram_s_v3(const ushort* __restrict__ Chl,
                                                 const float* __restrict__ csq,
                                                 float* __restrict__ S,
                                                 float* __restrict__ rsum) {
    __shared__ __align__(16) ushort sA[128 * 64];
    __shared__ __align__(16) ushort sB[128 * 64];
    __shared__ float rs_s[128];
    const int tid = threadIdx.x;
    const int n0 = blockIdx.x * 128;
    const int m0 = blockIdx.y * 128;
    const int wid = tid >> 6, lane = tid & 63;
    const int wm = wid >> 1, wn = wid & 1;
    const int lrow = lane & 15, lkb = lane >> 4;
    f32x4v acc[4][4] = {};

#pragma unroll 1
    for (int kc = 0; kc < 16; ++kc) {
        __syncthreads();
#pragma unroll
        for (int i = 0; i < 4; ++i) {
            const int sl = wid * 256 + i * 64 + lane;
            const int r = sl >> 3, j = sl & 7;
            const int s = j ^ (r & 7);
            gload_lds16(Chl + (long)(m0 + r) * 1024 + kc * 64 + s * 8,
                        &sA[(wid * 256 + i * 64) * 8]);
            gload_lds16(Chl + (long)(n0 + r) * 1024 + kc * 64 + s * 8,
                        &sB[(wid * 256 + i * 64) * 8]);
        }
        __syncthreads();
        bf16x8 ah[4], al[4], bh[4], bl[4];
#pragma unroll
        for (int mi = 0; mi < 4; ++mi) {
            const int R = wm * 64 + mi * 16 + lrow;
            ah[mi] = *(const bf16x8*)&sA[R * 64 + ((lkb ^ (R & 7)) << 3)];
            al[mi] = *(const bf16x8*)&sA[R * 64 + (((lkb + 4) ^ (R & 7)) << 3)];
        }
#pragma unroll
        for (int ni = 0; ni < 4; ++ni) {
            const int R = wn * 64 + ni * 16 + lrow;
            bh[ni] = *(const bf16x8*)&sB[R * 64 + ((lkb ^ (R & 7)) << 3)];
            bl[ni] = *(const bf16x8*)&sB[R * 64 + (((lkb + 4) ^ (R & 7)) << 3)];
        }
#pragma unroll
        for (int mi = 0; mi < 4; ++mi)
#pragma unroll
            for (int ni = 0; ni < 4; ++ni) {
                acc[mi][ni] = __builtin_amdgcn_mfma_f32_16x16x32_bf16(ah[mi], bh[ni], acc[mi][ni], 0, 0, 0);
                acc[mi][ni] = __builtin_amdgcn_mfma_f32_16x16x32_bf16(ah[mi], bl[ni], acc[mi][ni], 0, 0, 0);
                acc[mi][ni] = __builtin_amdgcn_mfma_f32_16x16x32_bf16(al[mi], bh[ni], acc[mi][ni], 0, 0, 0);
            }
    }
    if (tid < 128) rs_s[tid] = 0.f;
    __syncthreads();
    const int colb = n0 + wn * 64 + lrow;
    float csj[4];
#pragma unroll
    for (int ni = 0; ni < 4; ++ni) csj[ni] = csq[colb + ni * 16];
#pragma unroll
    for (int mi = 0; mi < 4; ++mi) {
        const int rowb = m0 + wm * 64 + mi * 16 + lkb * 4;
#pragma unroll
        for (int r = 0; r < 4; ++r) {
            const int row = rowb + r;
            const float csi = csq[row];
            float rowpart = 0.f;
#pragma unroll
            for (int ni = 0; ni < 4; ++ni) {
                const int col = colb + ni * 16;
                float sq = csi + csj[ni] - 2.0f * acc[mi][ni][r];
                float dist = sqrtf(fmaxf(sq, 0.f) + EPSF);
                float w = fmaxf(0.f, 1.f - dist);
                float sval = (row == col) ? 0.f : (0.1f * w / (dist + EPSF));
                S[(long)row * 512 + col] = sval;
                rowpart += sval;
            }
            atomicAdd(&rs_s[row - m0], rowpart);
        }
    }
    __syncthreads();
    if (tid < 128) atomicAdd(&rsum[m0 + tid], rs_s[tid]);
}

// ---------------- in-place row softmax (scale 1/T=10) + sum_w ----------------
__global__ __launch_bounds__(256) void softmax_rows(float* __restrict__ L,
                                                    float* __restrict__ sum_w) {
    __shared__ float swacc[512];
    const int tid = threadIdx.x;
    for (int i = tid; i < 512; i += 256) swacc[i] = 0.f;
    __syncthreads();
    const int wave = tid >> 6, lane = tid & 63;
    float racc[8] = {};
    for (int r = blockIdx.x * 4 + wave; r < 32768; r += 2048) {
        float* p = L + (long)r * 512 + lane * 8;
        float4 v0 = *(float4*)p;
        float4 v1 = *(float4*)(p + 4);
        float v[8] = {v0.x, v0.y, v0.z, v0.w, v1.x, v1.y, v1.z, v1.w};
        float m = v[0];
#pragma unroll
        for (int i = 1; i < 8; ++i) m = fmaxf(m, v[i]);
#pragma unroll
        for (int off = 1; off < 64; off <<= 1) m = fmaxf(m, __shfl_xor(m, off, 64));
        float e[8], s = 0.f;
#pragma unroll
        for (int i = 0; i < 8; ++i) {
            e[i] = expf((v[i] - m) * 10.0f);
            s += e[i];
        }
#pragma unroll
        for (int off = 1; off < 64; off <<= 1) s += __shfl_xor(s, off, 64);
        const float inv = 1.0f / (s + EPSF);
#pragma unroll
        for (int i = 0; i < 8; ++i) {
            e[i] *= inv;
            racc[i] += e[i];
        }
        float4 o0 = {e[0], e[1], e[2], e[3]};
        float4 o1 = {e[4], e[5], e[6], e[7]};
        *(float4*)p = o0;
        *(float4*)(p + 4) = o1;
    }
#pragma unroll
    for (int i = 0; i < 8; ++i) atomicAdd(&swacc[lane * 8 + i], racc[i]);
    __syncthreads();
    for (int i = tid; i < 512; i += 256) atomicAdd(&sum_w[i], racc[i] * 0.f + swacc[i]);
}

// ---------------- wsum fused: in-LDS transpose+convert, partials ----------------
// WSp[z][k][d] = sum_{n in chunk z} A[n][k] * X[n][d]; z=32 chunks of 1024 n.
__global__ __launch_bounds__(256) void wsum_fused(const float* __restrict__ A,
                                                  const float* __restrict__ X,
                                                  float* __restrict__ WSp) {
    __shared__ __align__(16) ushort sA[128 * 64];   // [k][n] bf16, swizzled n-octs
    __shared__ __align__(16) ushort sB[128 * 64];   // [d][n]
    const int tid = threadIdx.x;
    const int k0 = blockIdx.x * 128;
    const int d0 = blockIdx.y * 128;
    const long n0 = (long)blockIdx.z * 1024;
    const int wid = tid >> 6, lane = tid & 63;
    const int wm = wid >> 1, wn = wid & 1;
    const int lrow = lane & 15, lkb = lane >> 4;
    f32x4v acc[4][4] = {};

    for (int nc = 0; nc < 1024; nc += 64) {
        __syncthreads();
        // transpose+convert stage: task = (col c: 128) x (n-oct no: 8)
#pragma unroll
        for (int it = 0; it < 4; ++it) {
            const int idx = it * 256 + tid;
            const int c = idx & 127;
            const int no = idx >> 7;
            const long nb = n0 + nc + (long)no * 8;
            ushort ha[8], hx[8];
#pragma unroll
            for (int jj = 0; jj < 8; ++jj) {
                ha[jj] = f2bf_bits(A[(nb + jj) * 512 + k0 + c]);
                hx[jj] = f2bf_bits(X[(nb + jj) * 512 + d0 + c]);
            }
            const int sl = no ^ (c & 7);
            *(uint4*)&sA[c * 64 + sl * 8] = pack8(ha);
            *(uint4*)&sB[c * 64 + sl * 8] = pack8(hx);
        }
        __syncthreads();
#pragma unroll
        for (int kk = 0; kk < 2; ++kk) {
            const int j = kk * 4 + lkb;
            bf16x8 af[4], bfv[4];
#pragma unroll
            for (int mi = 0; mi < 4; ++mi) {
                const int R = wm * 64 + mi * 16 + lrow;
                af[mi] = *(const bf16x8*)&sA[R * 64 + ((j ^ (R & 7)) << 3)];
            }
#pragma unroll
            for (int ni = 0; ni < 4; ++ni) {
                const int R = wn * 64 + ni * 16 + lrow;
                bfv[ni] = *(const bf16x8*)&sB[R * 64 + ((j ^ (R & 7)) << 3)];
            }
#pragma unroll
            for (int mi = 0; mi < 4; ++mi)
#pragma unroll
                for (int ni = 0; ni < 4; ++ni)
                    acc[mi][ni] = __builtin_amdgcn_mfma_f32_16x16x32_bf16(af[mi], bfv[ni], acc[mi][ni], 0, 0, 0);
        }
    }
    float* dst = WSp + (size_t)blockIdx.z * 262144;
#pragma unroll
    for (int mi = 0; mi < 4; ++mi) {
        const int k = k0 + wm * 64 + mi * 16 + lkb * 4;
#pragma unroll
        for (int ni = 0; ni < 4; ++ni) {
            const int d = d0 + wn * 64 + ni * 16 + lrow;
#pragma unroll
            for (int r = 0; r < 4; ++r)
                dst[(k + r) * 512 + d] = acc[mi][ni][r];
        }
    }
}

// ---------------- reduce partials: WS = sum_z WSp[z], z=32 ----------------
__global__ __launch_bounds__(256) void reduce_ws32(const float* __restrict__ WSp,
                                                   float* __restrict__ WS) {
    const int i4 = (blockIdx.x * 256 + threadIdx.x) * 4;
    float4 s = {0.f, 0.f, 0.f, 0.f};
#pragma unroll 4
    for (int z = 0; z < 32; ++z) {
        float4 v = *(const float4*)(WSp + (size_t)z * 262144 + i4);
        s.x += v.x; s.y += v.y; s.z += v.z; s.w += v.w;
    }
    *(float4*)(WS + i4) = s;
}

// ---------------- fused repulsion-apply + momentum update ----------------
__global__ __launch_bounds__(256) void apply_update(const float* __restrict__ Cent,
                                                    const float* __restrict__ Mom,
                                                    const float* __restrict__ S,
                                                    const float* __restrict__ rsum,
                                                    const float* __restrict__ WS,
                                                    const float* __restrict__ sum_w,
                                                    float* __restrict__ outC,
                                                    float* __restrict__ outM) {
    const int i = blockIdx.x;
    __shared__ float srow[512];
    __shared__ int nz;
    const int tid = threadIdx.x;
    if (tid == 0) nz = 0;
    __syncthreads();
    float2 sv = *(const float2*)(S + (long)i * 512 + tid * 2);
    srow[tid * 2] = sv.x;
    srow[tid * 2 + 1] = sv.y;
    if (sv.x != 0.f || sv.y != 0.f) nz = 1;
    __syncthreads();
    const float rs = rsum[i];
    const float invw = 1.0f / (sum_w[i] + EPSF);
    const int d0 = tid * 2;
    float sc0 = 0.f, sc1 = 0.f;
    if (nz) {
        for (int j = 0; j < 512; ++j) {
            const float s = srow[j];
            if (s != 0.f) {
                sc0 += s * Cent[(long)j * 512 + d0];
                sc1 += s * Cent[(long)j * 512 + d0 + 1];
            }
        }
    }
    float2 ci = *(const float2*)(Cent + (long)i * 512 + d0);
    float2 mo = *(const float2*)(Mom + (long)i * 512 + d0);
    float2 wsv = *(const float2*)(WS + (long)i * 512 + d0);
    float rep0 = rs * ci.x - sc0;
    float rep1 = rs * ci.y - sc1;
    float mn0 = 0.9f * mo.x + 0.1f * (wsv.x * invw - ci.x + rep0);
    float mn1 = 0.9f * mo.y + 0.1f * (wsv.y * invw - ci.y + rep1);
    float2 om = {mn0, mn1};
    float2 oc = {ci.x + 0.1f * mn0, ci.y + 0.1f * mn1};
    *(float2*)(outM + (long)i * 512 + d0) = om;
    *(float2*)(outC + (long)i * 512 + d0) = oc;
}

// ================= legacy fp32 fallback kernels (small-ws path) =================
__global__ __launch_bounds__(256) void csq_only(const float* __restrict__ C,
                                                float* __restrict__ csq) {
    const int wave = threadIdx.x >> 6, lane = threadIdx.x & 63;
    const int row = blockIdx.x * 4 + wave;
    const float* p = C + row * 512 + lane * 8;
    float4 a = *(const float4*)p;
    float4 b = *(const float4*)(p + 4);
    float s = a.x * a.x + a.y * a.y + a.z * a.z + a.w * a.w +
              b.x * b.x + b.y * b.y + b.z * b.z + b.w * b.w;
#pragma unroll
    for (int off = 1; off < 64; off <<= 1) s += __shfl_xor(s, off, 64);
    if (lane == 0) csq[row] = s;
}

__global__ __launch_bounds__(256) void logits_mfma(const float* __restrict__ X,
                                                   const float* __restrict__ Cm,
                                                   const float* __restrict__ csq,
                                                   float* __restrict__ L) {
    __shared__ ushort sAh[128][64];
    __shared__ ushort sAl[128][64];
    __shared__ ushort sBh[128][64];
    __shared__ ushort sBl[128][64];
    const int tid = threadIdx.x;
    const int m0 = blockIdx.x * 128;
    const int n0 = blockIdx.y * 128;
    const int wid = tid >> 6, lane = tid & 63;
    const int wm = wid >> 1, wn = wid & 1;
    const int lrow = lane & 15;
    const int lkb = lane >> 4;
    f32x4v acc[4][4] = {};
    for (int k0 = 0; k0 < 512; k0 += 64) {
        __syncthreads();
#pragma unroll
        for (int s = 0; s < 8; ++s) {
            const int idx = s * 256 + tid;
            const int r = idx >> 4;
            const int c4 = (idx & 15) << 2;
            const int e = c4 ^ ((r & 7) << 3);
            float4 va = *(const float4*)(X + (long)(m0 + r) * 512 + k0 + c4);
            ushort4 hh, ll;
            split2(va.x, hh.x, ll.x);
            split2(va.y, hh.y, ll.y);
            split2(va.z, hh.z, ll.z);
            split2(va.w, hh.w, ll.w);
            *(ushort4*)&sAh[r][e] = hh;
            *(ushort4*)&sAl[r][e] = ll;
            float4 vb = *(const float4*)(Cm + (long)(n0 + r) * 512 + k0 + c4);
            split2(vb.x, hh.x, ll.x);
            split2(vb.y, hh.y, ll.y);
            split2(vb.z, hh.z, ll.z);
            split2(vb.w, hh.w, ll.w);
            *(ushort4*)&sBh[r][e] = hh;
            *(ushort4*)&sBl[r][e] = ll;
        }
        __syncthreads();
#pragma unroll
        for (int kk = 0; kk < 2; ++kk) {
            const int ebase = kk * 32 + lkb * 8;
            bf16x8 ah[4], al[4], bh[4], bl[4];
#pragma unroll
            for (int mi = 0; mi < 4; ++mi) {
                const int R = wm * 64 + mi * 16 + lrow;
                const int e = ebase ^ ((R & 7) << 3);
                ah[mi] = *(const bf16x8*)&sAh[R][e];
                al[mi] = *(const bf16x8*)&sAl[R][e];
            }
#pragma unroll
            for (int ni = 0; ni < 4; ++ni) {
                const int Rn = wn * 64 + ni * 16 + lrow;
                const int e = ebase ^ ((Rn & 7) << 3);
                bh[ni] = *(const bf16x8*)&sBh[Rn][e];
                bl[ni] = *(const bf16x8*)&sBl[Rn][e];
            }
#pragma unroll
            for (int mi = 0; mi < 4; ++mi)
#pragma unroll
                for (int ni = 0; ni < 4; ++ni) {
                    acc[mi][ni] = __builtin_amdgcn_mfma_f32_16x16x32_bf16(ah[mi], bh[ni], acc[mi][ni], 0, 0, 0);
                    acc[mi][ni] = __builtin_amdgcn_mfma_f32_16x16x32_bf16(ah[mi], bl[ni], acc[mi][ni], 0, 0, 0);
                    acc[mi][ni] = __builtin_amdgcn_mfma_f32_16x16x32_bf16(al[mi], bh[ni], acc[mi][ni], 0, 0, 0);
                }
        }
    }
    const int colb = n0 + wn * 64 + lrow;
    float cs[4];
#pragma unroll
    for (int ni = 0; ni < 4; ++ni) cs[ni] = csq[colb + ni * 16];
#pragma unroll
    for (int mi = 0; mi < 4; ++mi) {
        const int rowb = m0 + wm * 64 + mi * 16 + lkb * 4;
#pragma unroll
        for (int r = 0; r < 4; ++r) {
            float* Lp = L + (long)(rowb + r) * 512 + colb;
#pragma unroll
            for (int ni = 0; ni < 4; ++ni)
                Lp[ni * 16] = 2.0f * acc[mi][ni][r] - cs[ni];
        }
    }
}

__global__ __launch_bounds__(256) void gemm_wsum(const float* __restrict__ A,
                                                 const float* __restrict__ X,
                                                 float* __restrict__ WS) {
    __shared__ float As[16][64];
    __shared__ float Xs[16][64];
    const int tid = threadIdx.x;
    const int tx = tid & 15, ty = tid >> 4;
    const int lrow = tid >> 4;
    const int lcol = (tid & 15) << 2;
    const int k0 = blockIdx.x * 64;
    const int d0 = blockIdx.y * 64;
    const int n0 = blockIdx.z * 1024;
    float acc[4][4] = {};
    for (int nc = 0; nc < 1024; nc += 16) {
        const long nrow = n0 + nc + lrow;
        float4 av = *(const float4*)(A + nrow * 512 + k0 + lcol);
        float4 xv = *(const float4*)(X + nrow * 512 + d0 + lcol);
        __syncthreads();
        *(float4*)&As[lrow][lcol] = av;
        *(float4*)&Xs[lrow][lcol] = xv;
        __syncthreads();
#pragma unroll
        for (int nn = 0; nn < 16; ++nn) {
            float4 a = *(const float4*)&As[nn][ty << 2];
            float4 x = *(const float4*)&Xs[nn][tx << 2];
            float aa[4] = {a.x, a.y, a.z, a.w};
            float xx[4] = {x.x, x.y, x.z, x.w};
#pragma unroll
            for (int i = 0; i < 4; ++i)
#pragma unroll
                for (int j = 0; j < 4; ++j) acc[i][j] += aa[i] * xx[j];
        }
    }
#pragma unroll
    for (int i = 0; i < 4; ++i)
#pragma unroll
        for (int j = 0; j < 4; ++j)
            atomicAdd(&WS[(k0 + (ty << 2) + i) * 512 + d0 + (tx << 2) + j], acc[i][j]);
}

__global__ __launch_bounds__(256) void repulse_update(const float* __restrict__ Cent,
                                                      const float* __restrict__ Mom,
                                                      const float* __restrict__ csq,
                                                      const float* __restrict__ WS,
                                                      const float* __restrict__ sum_w,
                                                      float* __restrict__ outC,
                                                      float* __restrict__ outM) {
    const int i = blockIdx.x;
    __shared__ float ci[512];
    __shared__ float rep[512];
    const int tid = threadIdx.x, wave = tid >> 6, lane = tid & 63;
    for (int d = tid; d < 512; d += 256) {
        ci[d] = Cent[i * 512 + d];
        rep[d] = 0.f;
    }
    __syncthreads();
    float cil[8];
#pragma unroll
    for (int m = 0; m < 8; ++m) cil[m] = ci[lane * 8 + m];
    const float csqi = csq[i];
    float racc[8] = {};
    for (int j = wave; j < 512; j += 4) {
        if (j == i) continue;
        const float* cj = Cent + j * 512 + lane * 8;
        float4 c0 = *(const float4*)cj;
        float4 c1 = *(const float4*)(cj + 4);
        float cjl[8] = {c0.x, c0.y, c0.z, c0.w, c1.x, c1.y, c1.z, c1.w};
        float dot = 0.f;
#pragma unroll
        for (int m = 0; m < 8; ++m) dot += cil[m] * cjl[m];
#pragma unroll
        for (int off = 1; off < 64; off <<= 1) dot += __shfl_xor(dot, off, 64);
        float sq = csqi + csq[j] - 2.f * dot;
        float dist = sqrtf(fmaxf(sq, 0.f) + EPSF);
        float w = fmaxf(0.f, 1.f - dist);
        float scale = 0.1f * w / (dist + EPSF);
#pragma unroll
        for (int m = 0; m < 8; ++m) racc[m] += scale * (cil[m] - cjl[m]);
    }
#pragma unroll
    for (int m = 0; m < 8; ++m) atomicAdd(&rep[lane * 8 + m], racc[m]);
    __syncthreads();
    const float invw = 1.0f / (sum_w[i] + EPSF);
    for (int d = tid; d < 512; d += 256) {
        float nc = WS[i * 512 + d] * invw;
        float upd = nc - ci[d] + rep[d];
        float mn = 0.9f * Mom[i * 512 + d] + 0.1f * upd;
        outM[i * 512 + d] = mn;
        outC[i * 512 + d] = ci[d] + 0.1f * mn;
    }
}

extern "C" void kernel_launch(void* const* d_in, const int* in_sizes, int n_in,
                              void* d_out, int out_size, void* d_ws, size_t ws_size,
                              hipStream_t stream) {
    const float* X = (const float*)d_in[0];      // (32768, 512)
    const float* C = (const float*)d_in[1];      // (512, 512)
    const float* M = (const float*)d_in[2];      // (512, 512)
    float* out = (float*)d_out;
    float* assign = out;                          // 32768*512
    float* outC = out + 16777216;                 // 512*512
    float* outM = outC + 262144;                  // 512*512

    char* wsb = (char*)d_ws;
    const size_t MB = 1024ull * 1024ull;
    float* WS = (float*)wsb;                            // 1 MB
    float* sum_w = (float*)(wsb + 1 * MB);              // 2 KB
    float* rsum = (float*)(wsb + 1 * MB + 2048);        // 2 KB
    float* csq = (float*)(wsb + 1 * MB + 4096);         // 2 KB
    ushort* Chl = (ushort*)(wsb + 2 * MB);              // 1 MB (512 x 1024 bf16)
    float* S = (float*)(wsb + 3 * MB);                  // 1 MB
    float* WSp = (float*)(wsb + 4 * MB);                // 32 MB
    ushort* Xhl = (ushort*)(wsb + 36 * MB);             // 64 MB
    const size_t NEED = 100 * MB;

    hipMemsetAsync(d_ws, 0, 1 * MB + 8192, stream);     // WS + sum_w + rsum + csq hdr

    if (ws_size >= NEED) {
        csqc_v3<<<128, 256, 0, stream>>>(C, csq, Chl);
        gram_s_v3<<<dim3(4, 4), 256, 0, stream>>>(Chl, csq, S, rsum);
        convert_xhl<<<8192, 256, 0, stream>>>(X, Xhl);
        logits_v3<<<dim3(4, 256), 256, 0, stream>>>(Xhl, Chl, csq, assign);
        softmax_rows<<<512, 256, 0, stream>>>(assign, sum_w);
        wsum_fused<<<dim3(4, 4, 32), 256, 0, stream>>>(assign, X, WSp);
        reduce_ws32<<<256, 256, 0, stream>>>(WSp, WS);
        apply_update<<<512, 256, 0, stream>>>(C, M, S, rsum, WS, sum_w, outC, outM);
    } else {
        csq_only<<<128, 256, 0, stream>>>(C, csq);
        logits_mfma<<<dim3(256, 4), 256, 0, stream>>>(X, C, csq, assign);
        softmax_rows<<<512, 256, 0, stream>>>(assign, sum_w);
        gemm_wsum<<<dim3(8, 8, 32), 256, 0, stream>>>(assign, X, WS);
        repulse_update<<<512, 256, 0, stream>>>(C, M, csq, WS, sum_w, outC, outM);
    }
}

// Round 7
// 218.895 us; speedup vs baseline: 2.8751x; 1.0392x over previous
//
#include <hip/hip_runtime.h>
#include <hip/hip_bf16.h>

#define EPSF 1e-7f

typedef __attribute__((ext_vector_type(8))) short bf16x8;
typedef __attribute__((ext_vector_type(4))) float f32x4v;

__device__ inline ushort f2bf_bits(float x) {
    union { __hip_bfloat16 b; ushort u; } cv;
    cv.b = __float2bfloat16(x);
    return cv.u;
}
__device__ inline float bfbits2f(ushort u) {
    union { ushort u; __hip_bfloat16 b; } cv;
    cv.u = u;
    return __bfloat162float(cv.b);
}
__device__ inline void split2(float x, ushort& h, ushort& l) {
    h = f2bf_bits(x);
    l = f2bf_bits(x - bfbits2f(h));
}
__device__ inline uint4 pack8(const ushort* h) {
    uint4 p;
    p.x = (uint)h[0] | ((uint)h[1] << 16);
    p.y = (uint)h[2] | ((uint)h[3] << 16);
    p.z = (uint)h[4] | ((uint)h[5] << 16);
    p.w = (uint)h[6] | ((uint)h[7] << 16);
    return p;
}

__device__ inline void gload_lds16(const ushort* g, ushort* l) {
    __builtin_amdgcn_global_load_lds(
        (const __attribute__((address_space(1))) unsigned int*)g,
        (__attribute__((address_space(3))) unsigned int*)l, 16, 0, 0);
}

// ---------------- csq + C -> Chl (interleaved hi/lo per 32-k chunk) ----------------
__global__ __launch_bounds__(256) void csqc_v3(const float* __restrict__ C,
                                               float* __restrict__ csq,
                                               ushort* __restrict__ Chl) {
    const int wave = threadIdx.x >> 6, lane = threadIdx.x & 63;
    const int row = blockIdx.x * 4 + wave;
    const int kc = lane >> 2, s = lane & 3;
    const float* p = C + row * 512 + lane * 8;
    float4 a = *(const float4*)p;
    float4 b = *(const float4*)(p + 4);
    float v[8] = {a.x, a.y, a.z, a.w, b.x, b.y, b.z, b.w};
    ushort h[8], l[8];
    float sqs = 0.f;
#pragma unroll
    for (int i = 0; i < 8; ++i) {
        sqs += v[i] * v[i];
        split2(v[i], h[i], l[i]);
    }
    ushort* base = Chl + (long)row * 1024 + kc * 64 + s * 8;
    *(uint4*)base = pack8(h);
    *(uint4*)(base + 32) = pack8(l);
#pragma unroll
    for (int off = 1; off < 64; off <<= 1) sqs += __shfl_xor(sqs, off, 64);
    if (lane == 0) csq[row] = sqs;
}

// ---------------- X -> Xhl (interleaved hi/lo) ----------------
__global__ __launch_bounds__(256) void convert_xhl(const float* __restrict__ X,
                                                   ushort* __restrict__ Xhl) {
    const long idx = (long)blockIdx.x * 256 + threadIdx.x;   // 2,097,152 octets
    const long row = idx >> 6;
    const int oct = (int)(idx & 63);
    const int kc = oct >> 2, s = oct & 3;
    const float* src = X + row * 512 + oct * 8;
    float4 a = *(const float4*)src;
    float4 b = *(const float4*)(src + 4);
    float v[8] = {a.x, a.y, a.z, a.w, b.x, b.y, b.z, b.w};
    ushort h[8], l[8];
#pragma unroll
    for (int i = 0; i < 8; ++i) split2(v[i], h[i], l[i]);
    ushort* base = Xhl + row * 1024 + kc * 64 + s * 8;
    *(uint4*)base = pack8(h);
    *(uint4*)(base + 32) = pack8(l);
}

// ---------------- logits v3: single-read split-bf16 GEMM ----------------
__global__ __launch_bounds__(256) void logits_v3(const ushort* __restrict__ Xhl,
                                                 const ushort* __restrict__ Chl,
                                                 const float* __restrict__ csq,
                                                 float* __restrict__ L) {
    __shared__ __align__(16) ushort sA[128 * 64];
    __shared__ __align__(16) ushort sB[128 * 64];
    const int tid = threadIdx.x;
    const int n0 = blockIdx.x * 128;
    const int m0 = blockIdx.y * 128;
    const int wid = tid >> 6, lane = tid & 63;
    const int wm = wid >> 1, wn = wid & 1;
    const int lrow = lane & 15, lkb = lane >> 4;
    f32x4v acc[4][4] = {};

#pragma unroll 1
    for (int kc = 0; kc < 16; ++kc) {
        __syncthreads();
#pragma unroll
        for (int i = 0; i < 4; ++i) {
            const int sl = wid * 256 + i * 64 + lane;   // 0..1023
            const int r = sl >> 3, j = sl & 7;
            const int s = j ^ (r & 7);                  // logical slot (s<4 hi, s>=4 lo)
            gload_lds16(Xhl + (long)(m0 + r) * 1024 + kc * 64 + s * 8,
                        &sA[(wid * 256 + i * 64) * 8]);
            gload_lds16(Chl + (long)(n0 + r) * 1024 + kc * 64 + s * 8,
                        &sB[(wid * 256 + i * 64) * 8]);
        }
        __syncthreads();
        bf16x8 ah[4], al[4], bh[4], bl[4];
#pragma unroll
        for (int mi = 0; mi < 4; ++mi) {
            const int R = wm * 64 + mi * 16 + lrow;
            ah[mi] = *(const bf16x8*)&sA[R * 64 + ((lkb ^ (R & 7)) << 3)];
            al[mi] = *(const bf16x8*)&sA[R * 64 + (((lkb + 4) ^ (R & 7)) << 3)];
        }
#pragma unroll
        for (int ni = 0; ni < 4; ++ni) {
            const int R = wn * 64 + ni * 16 + lrow;
            bh[ni] = *(const bf16x8*)&sB[R * 64 + ((lkb ^ (R & 7)) << 3)];
            bl[ni] = *(const bf16x8*)&sB[R * 64 + (((lkb + 4) ^ (R & 7)) << 3)];
        }
#pragma unroll
        for (int mi = 0; mi < 4; ++mi)
#pragma unroll
            for (int ni = 0; ni < 4; ++ni) {
                acc[mi][ni] = __builtin_amdgcn_mfma_f32_16x16x32_bf16(ah[mi], bh[ni], acc[mi][ni], 0, 0, 0);
                acc[mi][ni] = __builtin_amdgcn_mfma_f32_16x16x32_bf16(ah[mi], bl[ni], acc[mi][ni], 0, 0, 0);
                acc[mi][ni] = __builtin_amdgcn_mfma_f32_16x16x32_bf16(al[mi], bh[ni], acc[mi][ni], 0, 0, 0);
            }
    }
    const int colb = n0 + wn * 64 + lrow;
    float cs[4];
#pragma unroll
    for (int ni = 0; ni < 4; ++ni) cs[ni] = csq[colb + ni * 16];
#pragma unroll
    for (int mi = 0; mi < 4; ++mi) {
        const int rowb = m0 + wm * 64 + mi * 16 + lkb * 4;
#pragma unroll
        for (int r = 0; r < 4; ++r) {
            float* Lp = L + (long)(rowb + r) * 512 + colb;
#pragma unroll
            for (int ni = 0; ni < 4; ++ni)
                Lp[ni * 16] = 2.0f * acc[mi][ni][r] - cs[ni];
        }
    }
}

// ---------------- gram -> S + rowsum, on Chl ----------------
__global__ __launch_bounds__(256) void gram_s_v3(const ushort* __restrict__ Chl,
                                                 const float* __restrict__ csq,
                                                 float* __restrict__ S,
                                                 float* __restrict__ rsum) {
    __shared__ __align__(16) ushort sA[128 * 64];
    __shared__ __align__(16) ushort sB[128 * 64];
    __shared__ float rs_s[128];
    const int tid = threadIdx.x;
    const int n0 = blockIdx.x * 128;
    const int m0 = blockIdx.y * 128;
    const int wid = tid >> 6, lane = tid & 63;
    const int wm = wid >> 1, wn = wid & 1;
    const int lrow = lane & 15, lkb = lane >> 4;
    f32x4v acc[4][4] = {};

#pragma unroll 1
    for (int kc = 0; kc < 16; ++kc) {
        __syncthreads();
#pragma unroll
        for (int i = 0; i < 4; ++i) {
            const int sl = wid * 256 + i * 64 + lane;
            const int r = sl >> 3, j = sl & 7;
            const int s = j ^ (r & 7);
            gload_lds16(Chl + (long)(m0 + r) * 1024 + kc * 64 + s * 8,
                        &sA[(wid * 256 + i * 64) * 8]);
            gload_lds16(Chl + (long)(n0 + r) * 1024 + kc * 64 + s * 8,
                        &sB[(wid * 256 + i * 64) * 8]);
        }
        __syncthreads();
        bf16x8 ah[4], al[4], bh[4], bl[4];
#pragma unroll
        for (int mi = 0; mi < 4; ++mi) {
            const int R = wm * 64 + mi * 16 + lrow;
            ah[mi] = *(const bf16x8*)&sA[R * 64 + ((lkb ^ (R & 7)) << 3)];
            al[mi] = *(const bf16x8*)&sA[R * 64 + (((lkb + 4) ^ (R & 7)) << 3)];
        }
#pragma unroll
        for (int ni = 0; ni < 4; ++ni) {
            const int R = wn * 64 + ni * 16 + lrow;
            bh[ni] = *(const bf16x8*)&sB[R * 64 + ((lkb ^ (R & 7)) << 3)];
            bl[ni] = *(const bf16x8*)&sB[R * 64 + (((lkb + 4) ^ (R & 7)) << 3)];
        }
#pragma unroll
        for (int mi = 0; mi < 4; ++mi)
#pragma unroll
            for (int ni = 0; ni < 4; ++ni) {
                acc[mi][ni] = __builtin_amdgcn_mfma_f32_16x16x32_bf16(ah[mi], bh[ni], acc[mi][ni], 0, 0, 0);
                acc[mi][ni] = __builtin_amdgcn_mfma_f32_16x16x32_bf16(ah[mi], bl[ni], acc[mi][ni], 0, 0, 0);
                acc[mi][ni] = __builtin_amdgcn_mfma_f32_16x16x32_bf16(al[mi], bh[ni], acc[mi][ni], 0, 0, 0);
            }
    }
    if (tid < 128) rs_s[tid] = 0.f;
    __syncthreads();
    const int colb = n0 + wn * 64 + lrow;
    float csj[4];
#pragma unroll
    for (int ni = 0; ni < 4; ++ni) csj[ni] = csq[colb + ni * 16];
#pragma unroll
    for (int mi = 0; mi < 4; ++mi) {
        const int rowb = m0 + wm * 64 + mi * 16 + lkb * 4;
#pragma unroll
        for (int r = 0; r < 4; ++r) {
            const int row = rowb + r;
            const float csi = csq[row];
            float rowpart = 0.f;
#pragma unroll
            for (int ni = 0; ni < 4; ++ni) {
                const int col = colb + ni * 16;
                float sq = csi + csj[ni] - 2.0f * acc[mi][ni][r];
                float dist = sqrtf(fmaxf(sq, 0.f) + EPSF);
                float w = fmaxf(0.f, 1.f - dist);
                float sval = (row == col) ? 0.f : (0.1f * w / (dist + EPSF));
                S[(long)row * 512 + col] = sval;
                rowpart += sval;
            }
            atomicAdd(&rs_s[row - m0], rowpart);
        }
    }
    __syncthreads();
    if (tid < 128) atomicAdd(&rsum[m0 + tid], rs_s[tid]);
}

// ---------------- in-place row softmax + sum_w + bf16 assignments ----------------
__global__ __launch_bounds__(256) void softmax_rows(float* __restrict__ L,
                                                    float* __restrict__ sum_w,
                                                    ushort* __restrict__ Abf) {
    __shared__ float swacc[512];
    const int tid = threadIdx.x;
    for (int i = tid; i < 512; i += 256) swacc[i] = 0.f;
    __syncthreads();
    const int wave = tid >> 6, lane = tid & 63;
    float racc[8] = {};
    for (int r = blockIdx.x * 4 + wave; r < 32768; r += 2048) {
        float* p = L + (long)r * 512 + lane * 8;
        float4 v0 = *(float4*)p;
        float4 v1 = *(float4*)(p + 4);
        float v[8] = {v0.x, v0.y, v0.z, v0.w, v1.x, v1.y, v1.z, v1.w};
        float m = v[0];
#pragma unroll
        for (int i = 1; i < 8; ++i) m = fmaxf(m, v[i]);
#pragma unroll
        for (int off = 1; off < 64; off <<= 1) m = fmaxf(m, __shfl_xor(m, off, 64));
        float e[8], s = 0.f;
#pragma unroll
        for (int i = 0; i < 8; ++i) {
            e[i] = expf((v[i] - m) * 10.0f);
            s += e[i];
        }
#pragma unroll
        for (int off = 1; off < 64; off <<= 1) s += __shfl_xor(s, off, 64);
        const float inv = 1.0f / (s + EPSF);
        ushort eb[8];
#pragma unroll
        for (int i = 0; i < 8; ++i) {
            e[i] *= inv;
            racc[i] += e[i];
            eb[i] = f2bf_bits(e[i]);
        }
        float4 o0 = {e[0], e[1], e[2], e[3]};
        float4 o1 = {e[4], e[5], e[6], e[7]};
        *(float4*)p = o0;
        *(float4*)(p + 4) = o1;
        if (Abf) *(uint4*)(Abf + (long)r * 512 + lane * 8) = pack8(eb);
    }
#pragma unroll
    for (int i = 0; i < 8; ++i) atomicAdd(&swacc[lane * 8 + i], racc[i]);
    __syncthreads();
    for (int i = tid; i < 512; i += 256) atomicAdd(&sum_w[i], swacc[i]);
}

// ---------------- wsum v3: bf16 sources, in-LDS transpose, partials ----------------
// WSp[z][k][d] = sum_{n in chunk z} A[n][k] * X[n][d]; z=32 chunks of 1024 n.
// A from Abf (bf16 row-major); X from Xhl hi-half (bf16, addr (d>>5)*64+(d&31)).
__global__ __launch_bounds__(256) void wsum_v3(const ushort* __restrict__ Abf,
                                               const ushort* __restrict__ Xhl,
                                               float* __restrict__ WSp) {
    __shared__ __align__(16) ushort sA[128 * 64];   // [k][n] bf16, swizzled n-octs
    __shared__ __align__(16) ushort sB[128 * 64];   // [d][n]
    const int tid = threadIdx.x;
    const int k0 = blockIdx.x * 128;
    const int d0 = blockIdx.y * 128;
    const long n0 = (long)blockIdx.z * 1024;
    const int wid = tid >> 6, lane = tid & 63;
    const int wm = wid >> 1, wn = wid & 1;
    const int lrow = lane & 15, lkb = lane >> 4;
    f32x4v acc[4][4] = {};

    for (int nc = 0; nc < 1024; nc += 64) {
        __syncthreads();
        // transpose stage: task = (col c: 128) x (n-oct no: 8); sources already bf16
#pragma unroll
        for (int it = 0; it < 4; ++it) {
            const int idx = it * 256 + tid;
            const int c = idx & 127;
            const int no = idx >> 7;
            const long nb = n0 + nc + (long)no * 8;
            const int dd = d0 + c;
            const long xoff = (long)((dd >> 5) * 64 + (dd & 31));
            ushort ha[8], hx[8];
#pragma unroll
            for (int jj = 0; jj < 8; ++jj) {
                ha[jj] = Abf[(nb + jj) * 512 + k0 + c];
                hx[jj] = Xhl[(nb + jj) * 1024 + xoff];
            }
            const int sl = no ^ (c & 7);
            *(uint4*)&sA[c * 64 + sl * 8] = pack8(ha);
            *(uint4*)&sB[c * 64 + sl * 8] = pack8(hx);
        }
        __syncthreads();
#pragma unroll
        for (int kk = 0; kk < 2; ++kk) {
            const int j = kk * 4 + lkb;
            bf16x8 af[4], bfv[4];
#pragma unroll
            for (int mi = 0; mi < 4; ++mi) {
                const int R = wm * 64 + mi * 16 + lrow;
                af[mi] = *(const bf16x8*)&sA[R * 64 + ((j ^ (R & 7)) << 3)];
            }
#pragma unroll
            for (int ni = 0; ni < 4; ++ni) {
                const int R = wn * 64 + ni * 16 + lrow;
                bfv[ni] = *(const bf16x8*)&sB[R * 64 + ((j ^ (R & 7)) << 3)];
            }
#pragma unroll
            for (int mi = 0; mi < 4; ++mi)
#pragma unroll
                for (int ni = 0; ni < 4; ++ni)
                    acc[mi][ni] = __builtin_amdgcn_mfma_f32_16x16x32_bf16(af[mi], bfv[ni], acc[mi][ni], 0, 0, 0);
        }
    }
    float* dst = WSp + (size_t)blockIdx.z * 262144;
#pragma unroll
    for (int mi = 0; mi < 4; ++mi) {
        const int k = k0 + wm * 64 + mi * 16 + lkb * 4;
#pragma unroll
        for (int ni = 0; ni < 4; ++ni) {
            const int d = d0 + wn * 64 + ni * 16 + lrow;
#pragma unroll
            for (int r = 0; r < 4; ++r)
                dst[(k + r) * 512 + d] = acc[mi][ni][r];
        }
    }
}

// ---------------- reduce partials: WS = sum_z WSp[z], z=32 ----------------
__global__ __launch_bounds__(256) void reduce_ws32(const float* __restrict__ WSp,
                                                   float* __restrict__ WS) {
    const int i4 = (blockIdx.x * 256 + threadIdx.x) * 4;
    float4 s = {0.f, 0.f, 0.f, 0.f};
#pragma unroll 4
    for (int z = 0; z < 32; ++z) {
        float4 v = *(const float4*)(WSp + (size_t)z * 262144 + i4);
        s.x += v.x; s.y += v.y; s.z += v.z; s.w += v.w;
    }
    *(float4*)(WS + i4) = s;
}

// ---------------- fused repulsion-apply + momentum update ----------------
__global__ __launch_bounds__(256) void apply_update(const float* __restrict__ Cent,
                                                    const float* __restrict__ Mom,
                                                    const float* __restrict__ S,
                                                    const float* __restrict__ rsum,
                                                    const float* __restrict__ WS,
                                                    const float* __restrict__ sum_w,
                                                    float* __restrict__ outC,
                                                    float* __restrict__ outM) {
    const int i = blockIdx.x;
    __shared__ float srow[512];
    __shared__ int nz;
    const int tid = threadIdx.x;
    if (tid == 0) nz = 0;
    __syncthreads();
    float2 sv = *(const float2*)(S + (long)i * 512 + tid * 2);
    srow[tid * 2] = sv.x;
    srow[tid * 2 + 1] = sv.y;
    if (sv.x != 0.f || sv.y != 0.f) nz = 1;
    __syncthreads();
    const float rs = rsum[i];
    const float invw = 1.0f / (sum_w[i] + EPSF);
    const int d0 = tid * 2;
    float sc0 = 0.f, sc1 = 0.f;
    if (nz) {
        for (int j = 0; j < 512; ++j) {
            const float s = srow[j];
            if (s != 0.f) {
                sc0 += s * Cent[(long)j * 512 + d0];
                sc1 += s * Cent[(long)j * 512 + d0 + 1];
            }
        }
    }
    float2 ci = *(const float2*)(Cent + (long)i * 512 + d0);
    float2 mo = *(const float2*)(Mom + (long)i * 512 + d0);
    float2 wsv = *(const float2*)(WS + (long)i * 512 + d0);
    float rep0 = rs * ci.x - sc0;
    float rep1 = rs * ci.y - sc1;
    float mn0 = 0.9f * mo.x + 0.1f * (wsv.x * invw - ci.x + rep0);
    float mn1 = 0.9f * mo.y + 0.1f * (wsv.y * invw - ci.y + rep1);
    float2 om = {mn0, mn1};
    float2 oc = {ci.x + 0.1f * mn0, ci.y + 0.1f * mn1};
    *(float2*)(outM + (long)i * 512 + d0) = om;
    *(float2*)(outC + (long)i * 512 + d0) = oc;
}

// ================= legacy fp32 fallback kernels (small-ws path) =================
__global__ __launch_bounds__(256) void csq_only(const float* __restrict__ C,
                                                float* __restrict__ csq) {
    const int wave = threadIdx.x >> 6, lane = threadIdx.x & 63;
    const int row = blockIdx.x * 4 + wave;
    const float* p = C + row * 512 + lane * 8;
    float4 a = *(const float4*)p;
    float4 b = *(const float4*)(p + 4);
    float s = a.x * a.x + a.y * a.y + a.z * a.z + a.w * a.w +
              b.x * b.x + b.y * b.y + b.z * b.z + b.w * b.w;
#pragma unroll
    for (int off = 1; off < 64; off <<= 1) s += __shfl_xor(s, off, 64);
    if (lane == 0) csq[row] = s;
}

__global__ __launch_bounds__(256) void logits_mfma(const float* __restrict__ X,
                                                   const float* __restrict__ Cm,
                                                   const float* __restrict__ csq,
                                                   float* __restrict__ L) {
    __shared__ ushort sAh[128][64];
    __shared__ ushort sAl[128][64];
    __shared__ ushort sBh[128][64];
    __shared__ ushort sBl[128][64];
    const int tid = threadIdx.x;
    const int m0 = blockIdx.x * 128;
    const int n0 = blockIdx.y * 128;
    const int wid = tid >> 6, lane = tid & 63;
    const int wm = wid >> 1, wn = wid & 1;
    const int lrow = lane & 15;
    const int lkb = lane >> 4;
    f32x4v acc[4][4] = {};
    for (int k0 = 0; k0 < 512; k0 += 64) {
        __syncthreads();
#pragma unroll
        for (int s = 0; s < 8; ++s) {
            const int idx = s * 256 + tid;
            const int r = idx >> 4;
            const int c4 = (idx & 15) << 2;
            const int e = c4 ^ ((r & 7) << 3);
            float4 va = *(const float4*)(X + (long)(m0 + r) * 512 + k0 + c4);
            ushort4 hh, ll;
            split2(va.x, hh.x, ll.x);
            split2(va.y, hh.y, ll.y);
            split2(va.z, hh.z, ll.z);
            split2(va.w, hh.w, ll.w);
            *(ushort4*)&sAh[r][e] = hh;
            *(ushort4*)&sAl[r][e] = ll;
            float4 vb = *(const float4*)(Cm + (long)(n0 + r) * 512 + k0 + c4);
            split2(vb.x, hh.x, ll.x);
            split2(vb.y, hh.y, ll.y);
            split2(vb.z, hh.z, ll.z);
            split2(vb.w, hh.w, ll.w);
            *(ushort4*)&sBh[r][e] = hh;
            *(ushort4*)&sBl[r][e] = ll;
        }
        __syncthreads();
#pragma unroll
        for (int kk = 0; kk < 2; ++kk) {
            const int ebase = kk * 32 + lkb * 8;
            bf16x8 ah[4], al[4], bh[4], bl[4];
#pragma unroll
            for (int mi = 0; mi < 4; ++mi) {
                const int R = wm * 64 + mi * 16 + lrow;
                const int e = ebase ^ ((R & 7) << 3);
                ah[mi] = *(const bf16x8*)&sAh[R][e];
                al[mi] = *(const bf16x8*)&sAl[R][e];
            }
#pragma unroll
            for (int ni = 0; ni < 4; ++ni) {
                const int Rn = wn * 64 + ni * 16 + lrow;
                const int e = ebase ^ ((Rn & 7) << 3);
                bh[ni] = *(const bf16x8*)&sBh[Rn][e];
                bl[ni] = *(const bf16x8*)&sBl[Rn][e];
            }
#pragma unroll
            for (int mi = 0; mi < 4; ++mi)
#pragma unroll
                for (int ni = 0; ni < 4; ++ni) {
                    acc[mi][ni] = __builtin_amdgcn_mfma_f32_16x16x32_bf16(ah[mi], bh[ni], acc[mi][ni], 0, 0, 0);
                    acc[mi][ni] = __builtin_amdgcn_mfma_f32_16x16x32_bf16(ah[mi], bl[ni], acc[mi][ni], 0, 0, 0);
                    acc[mi][ni] = __builtin_amdgcn_mfma_f32_16x16x32_bf16(al[mi], bh[ni], acc[mi][ni], 0, 0, 0);
                }
        }
    }
    const int colb = n0 + wn * 64 + lrow;
    float cs[4];
#pragma unroll
    for (int ni = 0; ni < 4; ++ni) cs[ni] = csq[colb + ni * 16];
#pragma unroll
    for (int mi = 0; mi < 4; ++mi) {
        const int rowb = m0 + wm * 64 + mi * 16 + lkb * 4;
#pragma unroll
        for (int r = 0; r < 4; ++r) {
            float* Lp = L + (long)(rowb + r) * 512 + colb;
#pragma unroll
            for (int ni = 0; ni < 4; ++ni)
                Lp[ni * 16] = 2.0f * acc[mi][ni][r] - cs[ni];
        }
    }
}

__global__ __launch_bounds__(256) void gemm_wsum(const float* __restrict__ A,
                                                 const float* __restrict__ X,
                                                 float* __restrict__ WS) {
    __shared__ float As[16][64];
    __shared__ float Xs[16][64];
    const int tid = threadIdx.x;
    const int tx = tid & 15, ty = tid >> 4;
    const int lrow = tid >> 4;
    const int lcol = (tid & 15) << 2;
    const int k0 = blockIdx.x * 64;
    const int d0 = blockIdx.y * 64;
    const int n0 = blockIdx.z * 1024;
    float acc[4][4] = {};
    for (int nc = 0; nc < 1024; nc += 16) {
        const long nrow = n0 + nc + lrow;
        float4 av = *(const float4*)(A + nrow * 512 + k0 + lcol);
        float4 xv = *(const float4*)(X + nrow * 512 + d0 + lcol);
        __syncthreads();
        *(float4*)&As[lrow][lcol] = av;
        *(float4*)&Xs[lrow][lcol] = xv;
        __syncthreads();
#pragma unroll
        for (int nn = 0; nn < 16; ++nn) {
            float4 a = *(const float4*)&As[nn][ty << 2];
            float4 x = *(const float4*)&Xs[nn][tx << 2];
            float aa[4] = {a.x, a.y, a.z, a.w};
            float xx[4] = {x.x, x.y, x.z, x.w};
#pragma unroll
            for (int i = 0; i < 4; ++i)
#pragma unroll
                for (int j = 0; j < 4; ++j) acc[i][j] += aa[i] * xx[j];
        }
    }
#pragma unroll
    for (int i = 0; i < 4; ++i)
#pragma unroll
        for (int j = 0; j < 4; ++j)
            atomicAdd(&WS[(k0 + (ty << 2) + i) * 512 + d0 + (tx << 2) + j], acc[i][j]);
}

__global__ __launch_bounds__(256) void repulse_update(const float* __restrict__ Cent,
                                                      const float* __restrict__ Mom,
                                                      const float* __restrict__ csq,
                                                      const float* __restrict__ WS,
                                                      const float* __restrict__ sum_w,
                                                      float* __restrict__ outC,
                                                      float* __restrict__ outM) {
    const int i = blockIdx.x;
    __shared__ float ci[512];
    __shared__ float rep[512];
    const int tid = threadIdx.x, wave = tid >> 6, lane = tid & 63;
    for (int d = tid; d < 512; d += 256) {
        ci[d] = Cent[i * 512 + d];
        rep[d] = 0.f;
    }
    __syncthreads();
    float cil[8];
#pragma unroll
    for (int m = 0; m < 8; ++m) cil[m] = ci[lane * 8 + m];
    const float csqi = csq[i];
    float racc[8] = {};
    for (int j = wave; j < 512; j += 4) {
        if (j == i) continue;
        const float* cj = Cent + j * 512 + lane * 8;
        float4 c0 = *(const float4*)cj;
        float4 c1 = *(const float4*)(cj + 4);
        float cjl[8] = {c0.x, c0.y, c0.z, c0.w, c1.x, c1.y, c1.z, c1.w};
        float dot = 0.f;
#pragma unroll
        for (int m = 0; m < 8; ++m) dot += cil[m] * cjl[m];
#pragma unroll
        for (int off = 1; off < 64; off <<= 1) dot += __shfl_xor(dot, off, 64);
        float sq = csqi + csq[j] - 2.f * dot;
        float dist = sqrtf(fmaxf(sq, 0.f) + EPSF);
        float w = fmaxf(0.f, 1.f - dist);
        float scale = 0.1f * w / (dist + EPSF);
#pragma unroll
        for (int m = 0; m < 8; ++m) racc[m] += scale * (cil[m] - cjl[m]);
    }
#pragma unroll
    for (int m = 0; m < 8; ++m) atomicAdd(&rep[lane * 8 + m], racc[m]);
    __syncthreads();
    const float invw = 1.0f / (sum_w[i] + EPSF);
    for (int d = tid; d < 512; d += 256) {
        float nc = WS[i * 512 + d] * invw;
        float upd = nc - ci[d] + rep[d];
        float mn = 0.9f * Mom[i * 512 + d] + 0.1f * upd;
        outM[i * 512 + d] = mn;
        outC[i * 512 + d] = ci[d] + 0.1f * mn;
    }
}

extern "C" void kernel_launch(void* const* d_in, const int* in_sizes, int n_in,
                              void* d_out, int out_size, void* d_ws, size_t ws_size,
                              hipStream_t stream) {
    const float* X = (const float*)d_in[0];      // (32768, 512)
    const float* C = (const float*)d_in[1];      // (512, 512)
    const float* M = (const float*)d_in[2];      // (512, 512)
    float* out = (float*)d_out;
    float* assign = out;                          // 32768*512
    float* outC = out + 16777216;                 // 512*512
    float* outM = outC + 262144;                  // 512*512

    char* wsb = (char*)d_ws;
    const size_t MB = 1024ull * 1024ull;
    float* WS = (float*)wsb;                            // 1 MB
    float* sum_w = (float*)(wsb + 1 * MB);              // 2 KB
    float* rsum = (float*)(wsb + 1 * MB + 2048);        // 2 KB
    float* csq = (float*)(wsb + 1 * MB + 4096);         // 2 KB
    ushort* Chl = (ushort*)(wsb + 2 * MB);              // 1 MB (512 x 1024 bf16)
    float* S = (float*)(wsb + 3 * MB);                  // 1 MB
    float* WSp = (float*)(wsb + 4 * MB);                // 32 MB
    ushort* Xhl = (ushort*)(wsb + 36 * MB);             // 64 MB
    ushort* Abf = (ushort*)(wsb + 100 * MB);            // 32 MB
    const size_t NEED = 132 * MB;                       // proven available (R4/R5 BIG path ran)

    hipMemsetAsync(d_ws, 0, 1 * MB + 8192, stream);     // WS + sum_w + rsum + csq hdr

    if (ws_size >= NEED) {
        csqc_v3<<<128, 256, 0, stream>>>(C, csq, Chl);
        gram_s_v3<<<dim3(4, 4), 256, 0, stream>>>(Chl, csq, S, rsum);
        convert_xhl<<<8192, 256, 0, stream>>>(X, Xhl);
        logits_v3<<<dim3(4, 256), 256, 0, stream>>>(Xhl, Chl, csq, assign);
        softmax_rows<<<512, 256, 0, stream>>>(assign, sum_w, Abf);
        wsum_v3<<<dim3(4, 4, 32), 256, 0, stream>>>(Abf, Xhl, WSp);
        reduce_ws32<<<256, 256, 0, stream>>>(WSp, WS);
        apply_update<<<512, 256, 0, stream>>>(C, M, S, rsum, WS, sum_w, outC, outM);
    } else {
        csq_only<<<128, 256, 0, stream>>>(C, csq);
        logits_mfma<<<dim3(256, 4), 256, 0, stream>>>(X, C, csq, assign);
        softmax_rows<<<512, 256, 0, stream>>>(assign, sum_w, nullptr);
        gemm_wsum<<<dim3(8, 8, 32), 256, 0, stream>>>(assign, X, WS);
        repulse_update<<<512, 256, 0, stream>>>(C, M, csq, WS, sum_w, outC, outM);
    }
}

// Round 8
// 191.990 us; speedup vs baseline: 3.2781x; 1.1401x over previous
//
#include <hip/hip_runtime.h>
#include <hip/hip_bf16.h>

#define EPSF 1e-7f

typedef __attribute__((ext_vector_type(8))) short bf16x8;
typedef __attribute__((ext_vector_type(4))) float f32x4v;

__device__ inline ushort f2bf_bits(float x) {
    union { __hip_bfloat16 b; ushort u; } cv;
    cv.b = __float2bfloat16(x);
    return cv.u;
}
__device__ inline float bfbits2f(ushort u) {
    union { ushort u; __hip_bfloat16 b; } cv;
    cv.u = u;
    return __bfloat162float(cv.b);
}
__device__ inline void split2(float x, ushort& h, ushort& l) {
    h = f2bf_bits(x);
    l = f2bf_bits(x - bfbits2f(h));
}
__device__ inline uint4 pack8(const ushort* h) {
    uint4 p;
    p.x = (uint)h[0] | ((uint)h[1] << 16);
    p.y = (uint)h[2] | ((uint)h[3] << 16);
    p.z = (uint)h[4] | ((uint)h[5] << 16);
    p.w = (uint)h[6] | ((uint)h[7] << 16);
    return p;
}

__device__ inline void gload_lds16(const ushort* g, ushort* l) {
    __builtin_amdgcn_global_load_lds(
        (const __attribute__((address_space(1))) unsigned int*)g,
        (__attribute__((address_space(3))) unsigned int*)l, 16, 0, 0);
}

// ---------------- csq + C -> Chl (interleaved hi/lo per 32-k chunk) ----------------
__global__ __launch_bounds__(256) void csqc_v3(const float* __restrict__ C,
                                               float* __restrict__ csq,
                                               ushort* __restrict__ Chl) {
    const int wave = threadIdx.x >> 6, lane = threadIdx.x & 63;
    const int row = blockIdx.x * 4 + wave;
    const int kc = lane >> 2, s = lane & 3;
    const float* p = C + row * 512 + lane * 8;
    float4 a = *(const float4*)p;
    float4 b = *(const float4*)(p + 4);
    float v[8] = {a.x, a.y, a.z, a.w, b.x, b.y, b.z, b.w};
    ushort h[8], l[8];
    float sqs = 0.f;
#pragma unroll
    for (int i = 0; i < 8; ++i) {
        sqs += v[i] * v[i];
        split2(v[i], h[i], l[i]);
    }
    ushort* base = Chl + (long)row * 1024 + kc * 64 + s * 8;
    *(uint4*)base = pack8(h);
    *(uint4*)(base + 32) = pack8(l);
#pragma unroll
    for (int off = 1; off < 64; off <<= 1) sqs += __shfl_xor(sqs, off, 64);
    if (lane == 0) csq[row] = sqs;
}

// ---------------- X -> Xhl (interleaved hi/lo) ----------------
__global__ __launch_bounds__(256) void convert_xhl(const float* __restrict__ X,
                                                   ushort* __restrict__ Xhl) {
    const long idx = (long)blockIdx.x * 256 + threadIdx.x;   // 2,097,152 octets
    const long row = idx >> 6;
    const int oct = (int)(idx & 63);
    const int kc = oct >> 2, s = oct & 3;
    const float* src = X + row * 512 + oct * 8;
    float4 a = *(const float4*)src;
    float4 b = *(const float4*)(src + 4);
    float v[8] = {a.x, a.y, a.z, a.w, b.x, b.y, b.z, b.w};
    ushort h[8], l[8];
#pragma unroll
    for (int i = 0; i < 8; ++i) split2(v[i], h[i], l[i]);
    ushort* base = Xhl + row * 1024 + kc * 64 + s * 8;
    *(uint4*)base = pack8(h);
    *(uint4*)(base + 32) = pack8(l);
}

// ---------------- logits v3: single-read split-bf16 GEMM, XCD-swizzled ----------------
__global__ __launch_bounds__(256) void logits_v3(const ushort* __restrict__ Xhl,
                                                 const ushort* __restrict__ Chl,
                                                 const float* __restrict__ csq,
                                                 float* __restrict__ L) {
    __shared__ __align__(16) ushort sA[128 * 64];
    __shared__ __align__(16) ushort sB[128 * 64];
    const int tid = threadIdx.x;
    // XCD-aware bijective swizzle: nwg=1024, blocks sharing an m-panel -> same XCD
    const int lin = blockIdx.x + (blockIdx.y << 2);
    const int T = (lin & 7) * 128 + (lin >> 3);
    const int n0 = (T & 3) * 128;
    const int m0 = (T >> 2) * 128;
    const int wid = tid >> 6, lane = tid & 63;
    const int wm = wid >> 1, wn = wid & 1;
    const int lrow = lane & 15, lkb = lane >> 4;
    f32x4v acc[4][4] = {};

#pragma unroll 1
    for (int kc = 0; kc < 16; ++kc) {
        __syncthreads();
#pragma unroll
        for (int i = 0; i < 4; ++i) {
            const int sl = wid * 256 + i * 64 + lane;   // 0..1023
            const int r = sl >> 3, j = sl & 7;
            const int s = j ^ (r & 7);                  // logical slot (s<4 hi, s>=4 lo)
            gload_lds16(Xhl + (long)(m0 + r) * 1024 + kc * 64 + s * 8,
                        &sA[(wid * 256 + i * 64) * 8]);
            gload_lds16(Chl + (long)(n0 + r) * 1024 + kc * 64 + s * 8,
                        &sB[(wid * 256 + i * 64) * 8]);
        }
        __syncthreads();
        bf16x8 ah[4], al[4], bh[4], bl[4];
#pragma unroll
        for (int mi = 0; mi < 4; ++mi) {
            const int R = wm * 64 + mi * 16 + lrow;
            ah[mi] = *(const bf16x8*)&sA[R * 64 + ((lkb ^ (R & 7)) << 3)];
            al[mi] = *(const bf16x8*)&sA[R * 64 + (((lkb + 4) ^ (R & 7)) << 3)];
        }
#pragma unroll
        for (int ni = 0; ni < 4; ++ni) {
            const int R = wn * 64 + ni * 16 + lrow;
            bh[ni] = *(const bf16x8*)&sB[R * 64 + ((lkb ^ (R & 7)) << 3)];
            bl[ni] = *(const bf16x8*)&sB[R * 64 + (((lkb + 4) ^ (R & 7)) << 3)];
        }
#pragma unroll
        for (int mi = 0; mi < 4; ++mi)
#pragma unroll
            for (int ni = 0; ni < 4; ++ni) {
                acc[mi][ni] = __builtin_amdgcn_mfma_f32_16x16x32_bf16(ah[mi], bh[ni], acc[mi][ni], 0, 0, 0);
                acc[mi][ni] = __builtin_amdgcn_mfma_f32_16x16x32_bf16(ah[mi], bl[ni], acc[mi][ni], 0, 0, 0);
                acc[mi][ni] = __builtin_amdgcn_mfma_f32_16x16x32_bf16(al[mi], bh[ni], acc[mi][ni], 0, 0, 0);
            }
    }
    const int colb = n0 + wn * 64 + lrow;
    float cs[4];
#pragma unroll
    for (int ni = 0; ni < 4; ++ni) cs[ni] = csq[colb + ni * 16];
#pragma unroll
    for (int mi = 0; mi < 4; ++mi) {
        const int rowb = m0 + wm * 64 + mi * 16 + lkb * 4;
#pragma unroll
        for (int r = 0; r < 4; ++r) {
            float* Lp = L + (long)(rowb + r) * 512 + colb;
#pragma unroll
            for (int ni = 0; ni < 4; ++ni)
                Lp[ni * 16] = 2.0f * acc[mi][ni][r] - cs[ni];
        }
    }
}

// ---------------- gram -> S + rowsum, on Chl ----------------
__global__ __launch_bounds__(256) void gram_s_v3(const ushort* __restrict__ Chl,
                                                 const float* __restrict__ csq,
                                                 float* __restrict__ S,
                                                 float* __restrict__ rsum) {
    __shared__ __align__(16) ushort sA[128 * 64];
    __shared__ __align__(16) ushort sB[128 * 64];
    __shared__ float rs_s[128];
    const int tid = threadIdx.x;
    const int n0 = blockIdx.x * 128;
    const int m0 = blockIdx.y * 128;
    const int wid = tid >> 6, lane = tid & 63;
    const int wm = wid >> 1, wn = wid & 1;
    const int lrow = lane & 15, lkb = lane >> 4;
    f32x4v acc[4][4] = {};

#pragma unroll 1
    for (int kc = 0; kc < 16; ++kc) {
        __syncthreads();
#pragma unroll
        for (int i = 0; i < 4; ++i) {
            const int sl = wid * 256 + i * 64 + lane;
            const int r = sl >> 3, j = sl & 7;
            const int s = j ^ (r & 7);
            gload_lds16(Chl + (long)(m0 + r) * 1024 + kc * 64 + s * 8,
                        &sA[(wid * 256 + i * 64) * 8]);
            gload_lds16(Chl + (long)(n0 + r) * 1024 + kc * 64 + s * 8,
                        &sB[(wid * 256 + i * 64) * 8]);
        }
        __syncthreads();
        bf16x8 ah[4], al[4], bh[4], bl[4];
#pragma unroll
        for (int mi = 0; mi < 4; ++mi) {
            const int R = wm * 64 + mi * 16 + lrow;
            ah[mi] = *(const bf16x8*)&sA[R * 64 + ((lkb ^ (R & 7)) << 3)];
            al[mi] = *(const bf16x8*)&sA[R * 64 + (((lkb + 4) ^ (R & 7)) << 3)];
        }
#pragma unroll
        for (int ni = 0; ni < 4; ++ni) {
            const int R = wn * 64 + ni * 16 + lrow;
            bh[ni] = *(const bf16x8*)&sB[R * 64 + ((lkb ^ (R & 7)) << 3)];
            bl[ni] = *(const bf16x8*)&sB[R * 64 + (((lkb + 4) ^ (R & 7)) << 3)];
        }
#pragma unroll
        for (int mi = 0; mi < 4; ++mi)
#pragma unroll
            for (int ni = 0; ni < 4; ++ni) {
                acc[mi][ni] = __builtin_amdgcn_mfma_f32_16x16x32_bf16(ah[mi], bh[ni], acc[mi][ni], 0, 0, 0);
                acc[mi][ni] = __builtin_amdgcn_mfma_f32_16x16x32_bf16(ah[mi], bl[ni], acc[mi][ni], 0, 0, 0);
                acc[mi][ni] = __builtin_amdgcn_mfma_f32_16x16x32_bf16(al[mi], bh[ni], acc[mi][ni], 0, 0, 0);
            }
    }
    if (tid < 128) rs_s[tid] = 0.f;
    __syncthreads();
    const int colb = n0 + wn * 64 + lrow;
    float csj[4];
#pragma unroll
    for (int ni = 0; ni < 4; ++ni) csj[ni] = csq[colb + ni * 16];
#pragma unroll
    for (int mi = 0; mi < 4; ++mi) {
        const int rowb = m0 + wm * 64 + mi * 16 + lkb * 4;
#pragma unroll
        for (int r = 0; r < 4; ++r) {
            const int row = rowb + r;
            const float csi = csq[row];
            float rowpart = 0.f;
#pragma unroll
            for (int ni = 0; ni < 4; ++ni) {
                const int col = colb + ni * 16;
                float sq = csi + csj[ni] - 2.0f * acc[mi][ni][r];
                float dist = sqrtf(fmaxf(sq, 0.f) + EPSF);
                float w = fmaxf(0.f, 1.f - dist);
                float sval = (row == col) ? 0.f : (0.1f * w / (dist + EPSF));
                S[(long)row * 512 + col] = sval;
                rowpart += sval;
            }
            atomicAdd(&rs_s[row - m0], rowpart);
        }
    }
    __syncthreads();
    if (tid < 128) atomicAdd(&rsum[m0 + tid], rs_s[tid]);
}

// ---------------- in-place row softmax + sum_w + bf16 assignments ----------------
__global__ __launch_bounds__(256) void softmax_rows(float* __restrict__ L,
                                                    float* __restrict__ sum_w,
                                                    ushort* __restrict__ Abf) {
    __shared__ float swacc[512];
    const int tid = threadIdx.x;
    for (int i = tid; i < 512; i += 256) swacc[i] = 0.f;
    __syncthreads();
    const int wave = tid >> 6, lane = tid & 63;
    float racc[8] = {};
    for (int r = blockIdx.x * 4 + wave; r < 32768; r += 2048) {
        float* p = L + (long)r * 512 + lane * 8;
        float4 v0 = *(float4*)p;
        float4 v1 = *(float4*)(p + 4);
        float v[8] = {v0.x, v0.y, v0.z, v0.w, v1.x, v1.y, v1.z, v1.w};
        float m = v[0];
#pragma unroll
        for (int i = 1; i < 8; ++i) m = fmaxf(m, v[i]);
#pragma unroll
        for (int off = 1; off < 64; off <<= 1) m = fmaxf(m, __shfl_xor(m, off, 64));
        float e[8], s = 0.f;
#pragma unroll
        for (int i = 0; i < 8; ++i) {
            e[i] = expf((v[i] - m) * 10.0f);
            s += e[i];
        }
#pragma unroll
        for (int off = 1; off < 64; off <<= 1) s += __shfl_xor(s, off, 64);
        const float inv = 1.0f / (s + EPSF);
        ushort eb[8];
#pragma unroll
        for (int i = 0; i < 8; ++i) {
            e[i] *= inv;
            racc[i] += e[i];
            eb[i] = f2bf_bits(e[i]);
        }
        float4 o0 = {e[0], e[1], e[2], e[3]};
        float4 o1 = {e[4], e[5], e[6], e[7]};
        *(float4*)p = o0;
        *(float4*)(p + 4) = o1;
        if (Abf) *(uint4*)(Abf + (long)r * 512 + lane * 8) = pack8(eb);
    }
#pragma unroll
    for (int i = 0; i < 8; ++i) atomicAdd(&swacc[lane * 8 + i], racc[i]);
    __syncthreads();
    for (int i = tid; i < 512; i += 256) atomicAdd(&sum_w[i], swacc[i]);
}

// ---------------- wsum v3: bf16 sources, in-LDS transpose, XCD-swizzled ----------------
__global__ __launch_bounds__(256) void wsum_v3(const ushort* __restrict__ Abf,
                                               const ushort* __restrict__ Xhl,
                                               float* __restrict__ WSp) {
    __shared__ __align__(16) ushort sA[128 * 64];   // [k][n] bf16, swizzled n-octs
    __shared__ __align__(16) ushort sB[128 * 64];   // [d][n]
    const int tid = threadIdx.x;
    // XCD-aware bijective swizzle: nwg=512, the 16 blocks of one z-chunk -> same XCD
    const int lin = blockIdx.x + blockIdx.y * 4 + blockIdx.z * 16;
    const int T = (lin & 7) * 64 + (lin >> 3);
    const int k0 = (T & 3) * 128;
    const int d0 = ((T >> 2) & 3) * 128;
    const int zc = T >> 4;
    const long n0 = (long)zc * 1024;
    const int wid = tid >> 6, lane = tid & 63;
    const int wm = wid >> 1, wn = wid & 1;
    const int lrow = lane & 15, lkb = lane >> 4;
    f32x4v acc[4][4] = {};

    for (int nc = 0; nc < 1024; nc += 64) {
        __syncthreads();
        // transpose stage: task = (col c: 128) x (n-oct no: 8); sources already bf16
#pragma unroll
        for (int it = 0; it < 4; ++it) {
            const int idx = it * 256 + tid;
            const int c = idx & 127;
            const int no = idx >> 7;
            const long nb = n0 + nc + (long)no * 8;
            const int dd = d0 + c;
            const long xoff = (long)((dd >> 5) * 64 + (dd & 31));
            ushort ha[8], hx[8];
#pragma unroll
            for (int jj = 0; jj < 8; ++jj) {
                ha[jj] = Abf[(nb + jj) * 512 + k0 + c];
                hx[jj] = Xhl[(nb + jj) * 1024 + xoff];
            }
            const int sl = no ^ (c & 7);
            *(uint4*)&sA[c * 64 + sl * 8] = pack8(ha);
            *(uint4*)&sB[c * 64 + sl * 8] = pack8(hx);
        }
        __syncthreads();
#pragma unroll
        for (int kk = 0; kk < 2; ++kk) {
            const int j = kk * 4 + lkb;
            bf16x8 af[4], bfv[4];
#pragma unroll
            for (int mi = 0; mi < 4; ++mi) {
                const int R = wm * 64 + mi * 16 + lrow;
                af[mi] = *(const bf16x8*)&sA[R * 64 + ((j ^ (R & 7)) << 3)];
            }
#pragma unroll
            for (int ni = 0; ni < 4; ++ni) {
                const int R = wn * 64 + ni * 16 + lrow;
                bfv[ni] = *(const bf16x8*)&sB[R * 64 + ((j ^ (R & 7)) << 3)];
            }
#pragma unroll
            for (int mi = 0; mi < 4; ++mi)
#pragma unroll
                for (int ni = 0; ni < 4; ++ni)
                    acc[mi][ni] = __builtin_amdgcn_mfma_f32_16x16x32_bf16(af[mi], bfv[ni], acc[mi][ni], 0, 0, 0);
        }
    }
    float* dst = WSp + (size_t)zc * 262144;
#pragma unroll
    for (int mi = 0; mi < 4; ++mi) {
        const int k = k0 + wm * 64 + mi * 16 + lkb * 4;
#pragma unroll
        for (int ni = 0; ni < 4; ++ni) {
            const int d = d0 + wn * 64 + ni * 16 + lrow;
#pragma unroll
            for (int r = 0; r < 4; ++r)
                dst[(k + r) * 512 + d] = acc[mi][ni][r];
        }
    }
}

// ---------------- reduce partials: WS = sum_z WSp[z], z=32 ----------------
__global__ __launch_bounds__(256) void reduce_ws32(const float* __restrict__ WSp,
                                                   float* __restrict__ WS) {
    const int i4 = (blockIdx.x * 256 + threadIdx.x) * 4;
    float4 s = {0.f, 0.f, 0.f, 0.f};
#pragma unroll 4
    for (int z = 0; z < 32; ++z) {
        float4 v = *(const float4*)(WSp + (size_t)z * 262144 + i4);
        s.x += v.x; s.y += v.y; s.z += v.z; s.w += v.w;
    }
    *(float4*)(WS + i4) = s;
}

// ---------------- fused repulsion-apply + momentum update ----------------
__global__ __launch_bounds__(256) void apply_update(const float* __restrict__ Cent,
                                                    const float* __restrict__ Mom,
                                                    const float* __restrict__ S,
                                                    const float* __restrict__ rsum,
                                                    const float* __restrict__ WS,
                                                    const float* __restrict__ sum_w,
                                                    float* __restrict__ outC,
                                                    float* __restrict__ outM) {
    const int i = blockIdx.x;
    __shared__ float srow[512];
    __shared__ int nz;
    const int tid = threadIdx.x;
    if (tid == 0) nz = 0;
    __syncthreads();
    float2 sv = *(const float2*)(S + (long)i * 512 + tid * 2);
    srow[tid * 2] = sv.x;
    srow[tid * 2 + 1] = sv.y;
    if (sv.x != 0.f || sv.y != 0.f) nz = 1;
    __syncthreads();
    const float rs = rsum[i];
    const float invw = 1.0f / (sum_w[i] + EPSF);
    const int d0 = tid * 2;
    float sc0 = 0.f, sc1 = 0.f;
    if (nz) {
        for (int j = 0; j < 512; ++j) {
            const float s = srow[j];
            if (s != 0.f) {
                sc0 += s * Cent[(long)j * 512 + d0];
                sc1 += s * Cent[(long)j * 512 + d0 + 1];
            }
        }
    }
    float2 ci = *(const float2*)(Cent + (long)i * 512 + d0);
    float2 mo = *(const float2*)(Mom + (long)i * 512 + d0);
    float2 wsv = *(const float2*)(WS + (long)i * 512 + d0);
    float rep0 = rs * ci.x - sc0;
    float rep1 = rs * ci.y - sc1;
    float mn0 = 0.9f * mo.x + 0.1f * (wsv.x * invw - ci.x + rep0);
    float mn1 = 0.9f * mo.y + 0.1f * (wsv.y * invw - ci.y + rep1);
    float2 om = {mn0, mn1};
    float2 oc = {ci.x + 0.1f * mn0, ci.y + 0.1f * mn1};
    *(float2*)(outM + (long)i * 512 + d0) = om;
    *(float2*)(outC + (long)i * 512 + d0) = oc;
}

// ================= legacy fp32 fallback kernels (small-ws path) =================
__global__ __launch_bounds__(256) void csq_only(const float* __restrict__ C,
                                                float* __restrict__ csq) {
    const int wave = threadIdx.x >> 6, lane = threadIdx.x & 63;
    const int row = blockIdx.x * 4 + wave;
    const float* p = C + row * 512 + lane * 8;
    float4 a = *(const float4*)p;
    float4 b = *(const float4*)(p + 4);
    float s = a.x * a.x + a.y * a.y + a.z * a.z + a.w * a.w +
              b.x * b.x + b.y * b.y + b.z * b.z + b.w * b.w;
#pragma unroll
    for (int off = 1; off < 64; off <<= 1) s += __shfl_xor(s, off, 64);
    if (lane == 0) csq[row] = s;
}

__global__ __launch_bounds__(256) void logits_mfma(const float* __restrict__ X,
                                                   const float* __restrict__ Cm,
                                                   const float* __restrict__ csq,
                                                   float* __restrict__ L) {
    __shared__ ushort sAh[128][64];
    __shared__ ushort sAl[128][64];
    __shared__ ushort sBh[128][64];
    __shared__ ushort sBl[128][64];
    const int tid = threadIdx.x;
    const int m0 = blockIdx.x * 128;
    const int n0 = blockIdx.y * 128;
    const int wid = tid >> 6, lane = tid & 63;
    const int wm = wid >> 1, wn = wid & 1;
    const int lrow = lane & 15;
    const int lkb = lane >> 4;
    f32x4v acc[4][4] = {};
    for (int k0 = 0; k0 < 512; k0 += 64) {
        __syncthreads();
#pragma unroll
        for (int s = 0; s < 8; ++s) {
            const int idx = s * 256 + tid;
            const int r = idx >> 4;
            const int c4 = (idx & 15) << 2;
            const int e = c4 ^ ((r & 7) << 3);
            float4 va = *(const float4*)(X + (long)(m0 + r) * 512 + k0 + c4);
            ushort4 hh, ll;
            split2(va.x, hh.x, ll.x);
            split2(va.y, hh.y, ll.y);
            split2(va.z, hh.z, ll.z);
            split2(va.w, hh.w, ll.w);
            *(ushort4*)&sAh[r][e] = hh;
            *(ushort4*)&sAl[r][e] = ll;
            float4 vb = *(const float4*)(Cm + (long)(n0 + r) * 512 + k0 + c4);
            split2(vb.x, hh.x, ll.x);
            split2(vb.y, hh.y, ll.y);
            split2(vb.z, hh.z, ll.z);
            split2(vb.w, hh.w, ll.w);
            *(ushort4*)&sBh[r][e] = hh;
            *(ushort4*)&sBl[r][e] = ll;
        }
        __syncthreads();
#pragma unroll
        for (int kk = 0; kk < 2; ++kk) {
            const int ebase = kk * 32 + lkb * 8;
            bf16x8 ah[4], al[4], bh[4], bl[4];
#pragma unroll
            for (int mi = 0; mi < 4; ++mi) {
                const int R = wm * 64 + mi * 16 + lrow;
                const int e = ebase ^ ((R & 7) << 3);
                ah[mi] = *(const bf16x8*)&sAh[R][e];
                al[mi] = *(const bf16x8*)&sAl[R][e];
            }
#pragma unroll
            for (int ni = 0; ni < 4; ++ni) {
                const int Rn = wn * 64 + ni * 16 + lrow;
                const int e = ebase ^ ((Rn & 7) << 3);
                bh[ni] = *(const bf16x8*)&sBh[Rn][e];
                bl[ni] = *(const bf16x8*)&sBl[Rn][e];
            }
#pragma unroll
            for (int mi = 0; mi < 4; ++mi)
#pragma unroll
                for (int ni = 0; ni < 4; ++ni) {
                    acc[mi][ni] = __builtin_amdgcn_mfma_f32_16x16x32_bf16(ah[mi], bh[ni], acc[mi][ni], 0, 0, 0);
                    acc[mi][ni] = __builtin_amdgcn_mfma_f32_16x16x32_bf16(ah[mi], bl[ni], acc[mi][ni], 0, 0, 0);
                    acc[mi][ni] = __builtin_amdgcn_mfma_f32_16x16x32_bf16(al[mi], bh[ni], acc[mi][ni], 0, 0, 0);
                }
        }
    }
    const int colb = n0 + wn * 64 + lrow;
    float cs[4];
#pragma unroll
    for (int ni = 0; ni < 4; ++ni) cs[ni] = csq[colb + ni * 16];
#pragma unroll
    for (int mi = 0; mi < 4; ++mi) {
        const int rowb = m0 + wm * 64 + mi * 16 + lkb * 4;
#pragma unroll
        for (int r = 0; r < 4; ++r) {
            float* Lp = L + (long)(rowb + r) * 512 + colb;
#pragma unroll
            for (int ni = 0; ni < 4; ++ni)
                Lp[ni * 16] = 2.0f * acc[mi][ni][r] - cs[ni];
        }
    }
}

__global__ __launch_bounds__(256) void gemm_wsum(const float* __restrict__ A,
                                                 const float* __restrict__ X,
                                                 float* __restrict__ WS) {
    __shared__ float As[16][64];
    __shared__ float Xs[16][64];
    const int tid = threadIdx.x;
    const int tx = tid & 15, ty = tid >> 4;
    const int lrow = tid >> 4;
    const int lcol = (tid & 15) << 2;
    const int k0 = blockIdx.x * 64;
    const int d0 = blockIdx.y * 64;
    const int n0 = blockIdx.z * 1024;
    float acc[4][4] = {};
    for (int nc = 0; nc < 1024; nc += 16) {
        const long nrow = n0 + nc + lrow;
        float4 av = *(const float4*)(A + nrow * 512 + k0 + lcol);
        float4 xv = *(const float4*)(X + nrow * 512 + d0 + lcol);
        __syncthreads();
        *(float4*)&As[lrow][lcol] = av;
        *(float4*)&Xs[lrow][lcol] = xv;
        __syncthreads();
#pragma unroll
        for (int nn = 0; nn < 16; ++nn) {
            float4 a = *(const float4*)&As[nn][ty << 2];
            float4 x = *(const float4*)&Xs[nn][tx << 2];
            float aa[4] = {a.x, a.y, a.z, a.w};
            float xx[4] = {x.x, x.y, x.z, x.w};
#pragma unroll
            for (int i = 0; i < 4; ++i)
#pragma unroll
                for (int j = 0; j < 4; ++j) acc[i][j] += aa[i] * xx[j];
        }
    }
#pragma unroll
    for (int i = 0; i < 4; ++i)
#pragma unroll
        for (int j = 0; j < 4; ++j)
            atomicAdd(&WS[(k0 + (ty << 2) + i) * 512 + d0 + (tx << 2) + j], acc[i][j]);
}

__global__ __launch_bounds__(256) void repulse_update(const float* __restrict__ Cent,
                                                      const float* __restrict__ Mom,
                                                      const float* __restrict__ csq,
                                                      const float* __restrict__ WS,
                                                      const float* __restrict__ sum_w,
                                                      float* __restrict__ outC,
                                                      float* __restrict__ outM) {
    const int i = blockIdx.x;
    __shared__ float ci[512];
    __shared__ float rep[512];
    const int tid = threadIdx.x, wave = tid >> 6, lane = tid & 63;
    for (int d = tid; d < 512; d += 256) {
        ci[d] = Cent[i * 512 + d];
        rep[d] = 0.f;
    }
    __syncthreads();
    float cil[8];
#pragma unroll
    for (int m = 0; m < 8; ++m) cil[m] = ci[lane * 8 + m];
    const float csqi = csq[i];
    float racc[8] = {};
    for (int j = wave; j < 512; j += 4) {
        if (j == i) continue;
        const float* cj = Cent + j * 512 + lane * 8;
        float4 c0 = *(const float4*)cj;
        float4 c1 = *(const float4*)(cj + 4);
        float cjl[8] = {c0.x, c0.y, c0.z, c0.w, c1.x, c1.y, c1.z, c1.w};
        float dot = 0.f;
#pragma unroll
        for (int m = 0; m < 8; ++m) dot += cil[m] * cjl[m];
#pragma unroll
        for (int off = 1; off < 64; off <<= 1) dot += __shfl_xor(dot, off, 64);
        float sq = csqi + csq[j] - 2.f * dot;
        float dist = sqrtf(fmaxf(sq, 0.f) + EPSF);
        float w = fmaxf(0.f, 1.f - dist);
        float scale = 0.1f * w / (dist + EPSF);
#pragma unroll
        for (int m = 0; m < 8; ++m) racc[m] += scale * (cil[m] - cjl[m]);
    }
#pragma unroll
    for (int m = 0; m < 8; ++m) atomicAdd(&rep[lane * 8 + m], racc[m]);
    __syncthreads();
    const float invw = 1.0f / (sum_w[i] + EPSF);
    for (int d = tid; d < 512; d += 256) {
        float nc = WS[i * 512 + d] * invw;
        float upd = nc - ci[d] + rep[d];
        float mn = 0.9f * Mom[i * 512 + d] + 0.1f * upd;
        outM[i * 512 + d] = mn;
        outC[i * 512 + d] = ci[d] + 0.1f * mn;
    }
}

extern "C" void kernel_launch(void* const* d_in, const int* in_sizes, int n_in,
                              void* d_out, int out_size, void* d_ws, size_t ws_size,
                              hipStream_t stream) {
    const float* X = (const float*)d_in[0];      // (32768, 512)
    const float* C = (const float*)d_in[1];      // (512, 512)
    const float* M = (const float*)d_in[2];      // (512, 512)
    float* out = (float*)d_out;
    float* assign = out;                          // 32768*512
    float* outC = out + 16777216;                 // 512*512
    float* outM = outC + 262144;                  // 512*512

    char* wsb = (char*)d_ws;
    const size_t MB = 1024ull * 1024ull;
    float* WS = (float*)wsb;                            // 1 MB
    float* sum_w = (float*)(wsb + 1 * MB);              // 2 KB
    float* rsum = (float*)(wsb + 1 * MB + 2048);        // 2 KB
    float* csq = (float*)(wsb + 1 * MB + 4096);         // 2 KB
    ushort* Chl = (ushort*)(wsb + 2 * MB);              // 1 MB (512 x 1024 bf16)
    float* S = (float*)(wsb + 3 * MB);                  // 1 MB
    float* WSp = (float*)(wsb + 4 * MB);                // 32 MB
    ushort* Xhl = (ushort*)(wsb + 36 * MB);             // 64 MB
    ushort* Abf = (ushort*)(wsb + 100 * MB);            // 32 MB
    const size_t NEED = 132 * MB;                       // proven available

    hipMemsetAsync(d_ws, 0, 1 * MB + 8192, stream);     // WS + sum_w + rsum hdr

    if (ws_size >= NEED) {
        csqc_v3<<<128, 256, 0, stream>>>(C, csq, Chl);
        gram_s_v3<<<dim3(4, 4), 256, 0, stream>>>(Chl, csq, S, rsum);
        convert_xhl<<<8192, 256, 0, stream>>>(X, Xhl);
        logits_v3<<<dim3(4, 256), 256, 0, stream>>>(Xhl, Chl, csq, assign);
        softmax_rows<<<512, 256, 0, stream>>>(assign, sum_w, Abf);
        wsum_v3<<<dim3(4, 4, 32), 256, 0, stream>>>(Abf, Xhl, WSp);
        reduce_ws32<<<256, 256, 0, stream>>>(WSp, WS);
        apply_update<<<512, 256, 0, stream>>>(C, M, S, rsum, WS, sum_w, outC, outM);
    } else {
        csq_only<<<128, 256, 0, stream>>>(C, csq);
        logits_mfma<<<dim3(256, 4), 256, 0, stream>>>(X, C, csq, assign);
        softmax_rows<<<512, 256, 0, stream>>>(assign, sum_w, nullptr);
        gemm_wsum<<<dim3(8, 8, 32), 256, 0, stream>>>(assign, X, WS);
        repulse_update<<<512, 256, 0, stream>>>(C, M, csq, WS, sum_w, outC, outM);
    }
}

// Round 9
// 187.076 us; speedup vs baseline: 3.3642x; 1.0263x over previous
//
#include <hip/hip_runtime.h>
#include <hip/hip_bf16.h>

#define EPSF 1e-7f

typedef __attribute__((ext_vector_type(8))) short bf16x8;
typedef __attribute__((ext_vector_type(4))) float f32x4v;

__device__ inline ushort f2bf_bits(float x) {
    union { __hip_bfloat16 b; ushort u; } cv;
    cv.b = __float2bfloat16(x);
    return cv.u;
}
__device__ inline float bfbits2f(ushort u) {
    union { ushort u; __hip_bfloat16 b; } cv;
    cv.u = u;
    return __bfloat162float(cv.b);
}
__device__ inline void split2(float x, ushort& h, ushort& l) {
    h = f2bf_bits(x);
    l = f2bf_bits(x - bfbits2f(h));
}
__device__ inline uint4 pack8(const ushort* h) {
    uint4 p;
    p.x = (uint)h[0] | ((uint)h[1] << 16);
    p.y = (uint)h[2] | ((uint)h[3] << 16);
    p.z = (uint)h[4] | ((uint)h[5] << 16);
    p.w = (uint)h[6] | ((uint)h[7] << 16);
    return p;
}

__device__ inline void gload_lds16(const ushort* g, ushort* l) {
    __builtin_amdgcn_global_load_lds(
        (const __attribute__((address_space(1))) unsigned int*)g,
        (__attribute__((address_space(3))) unsigned int*)l, 16, 0, 0);
}

// ---------------- csq + C -> Chl (interleaved hi/lo per 32-k chunk) ----------------
__global__ __launch_bounds__(256) void csqc_v3(const float* __restrict__ C,
                                               float* __restrict__ csq,
                                               ushort* __restrict__ Chl) {
    const int wave = threadIdx.x >> 6, lane = threadIdx.x & 63;
    const int row = blockIdx.x * 4 + wave;
    const int kc = lane >> 2, s = lane & 3;
    const float* p = C + row * 512 + lane * 8;
    float4 a = *(const float4*)p;
    float4 b = *(const float4*)(p + 4);
    float v[8] = {a.x, a.y, a.z, a.w, b.x, b.y, b.z, b.w};
    ushort h[8], l[8];
    float sqs = 0.f;
#pragma unroll
    for (int i = 0; i < 8; ++i) {
        sqs += v[i] * v[i];
        split2(v[i], h[i], l[i]);
    }
    ushort* base = Chl + (long)row * 1024 + kc * 64 + s * 8;
    *(uint4*)base = pack8(h);
    *(uint4*)(base + 32) = pack8(l);
#pragma unroll
    for (int off = 1; off < 64; off <<= 1) sqs += __shfl_xor(sqs, off, 64);
    if (lane == 0) csq[row] = sqs;
}

// ---------------- X -> Xhl (interleaved hi/lo) ----------------
__global__ __launch_bounds__(256) void convert_xhl(const float* __restrict__ X,
                                                   ushort* __restrict__ Xhl) {
    const long idx = (long)blockIdx.x * 256 + threadIdx.x;   // 2,097,152 octets
    const long row = idx >> 6;
    const int oct = (int)(idx & 63);
    const int kc = oct >> 2, s = oct & 3;
    const float* src = X + row * 512 + oct * 8;
    float4 a = *(const float4*)src;
    float4 b = *(const float4*)(src + 4);
    float v[8] = {a.x, a.y, a.z, a.w, b.x, b.y, b.z, b.w};
    ushort h[8], l[8];
#pragma unroll
    for (int i = 0; i < 8; ++i) split2(v[i], h[i], l[i]);
    ushort* base = Xhl + row * 1024 + kc * 64 + s * 8;
    *(uint4*)base = pack8(h);
    *(uint4*)(base + 32) = pack8(l);
}

// ---------------- logsm: fused logits GEMM + row softmax ----------------
// BM=64 rows, BN=512 (full row). 512 thr = 8 waves (2m x 4n); per-wave 32x128.
// 3-pass split-bf16 per 32-k chunk; epilogue does softmax + writes assign/Abf/sum_w.
__global__ __launch_bounds__(512) void logsm(const ushort* __restrict__ Xhl,
                                             const ushort* __restrict__ Chl,
                                             const float* __restrict__ csq,
                                             float* __restrict__ assign,
                                             ushort* __restrict__ Abf,
                                             float* __restrict__ sum_w) {
    __shared__ __align__(16) ushort sA[64 * 64];      // 8 KB
    __shared__ __align__(16) ushort sB[512 * 64];     // 64 KB
    __shared__ float rmaxs[64][4];
    __shared__ float rsums[64][4];
    __shared__ float swacc[512];
    const int tid = threadIdx.x;
    // XCD-aware bijective swizzle over 512 m-tiles (512 % 8 == 0)
    const int m0 = ((blockIdx.x & 7) * 64 + (blockIdx.x >> 3)) * 64;
    const int wid = tid >> 6, lane = tid & 63;
    const int wm = wid >> 2, wn = wid & 3;
    const int lrow = lane & 15, lkb = lane >> 4;
    swacc[tid] = 0.f;
    f32x4v acc[2][8] = {};

#pragma unroll 1
    for (int kc = 0; kc < 16; ++kc) {
        __syncthreads();
        {   // stage A: 64 rows x 64 k-elems = 512 16B-slots, 1/thread
            const int r = tid >> 3, j = tid & 7;
            const int s = j ^ (r & 7);
            gload_lds16(Xhl + (long)(m0 + r) * 1024 + kc * 64 + s * 8,
                        &sA[(wid * 64) * 8]);
        }
#pragma unroll
        for (int i = 0; i < 8; ++i) {   // stage B: 512 rows = 4096 slots, 8/thread
            const int sl = i * 512 + tid;
            const int r = sl >> 3, j = sl & 7;
            const int s = j ^ (r & 7);
            gload_lds16(Chl + (long)r * 1024 + kc * 64 + s * 8,
                        &sB[(i * 512 + wid * 64) * 8]);
        }
        __syncthreads();
        bf16x8 ah[2], al[2];
#pragma unroll
        for (int mi = 0; mi < 2; ++mi) {
            const int R = wm * 32 + mi * 16 + lrow;
            ah[mi] = *(const bf16x8*)&sA[R * 64 + ((lkb ^ (R & 7)) << 3)];
            al[mi] = *(const bf16x8*)&sA[R * 64 + (((lkb + 4) ^ (R & 7)) << 3)];
        }
#pragma unroll
        for (int ni = 0; ni < 8; ++ni) {
            const int Rn = wn * 128 + ni * 16 + lrow;
            bf16x8 bh = *(const bf16x8*)&sB[Rn * 64 + ((lkb ^ (Rn & 7)) << 3)];
            bf16x8 bl = *(const bf16x8*)&sB[Rn * 64 + (((lkb + 4) ^ (Rn & 7)) << 3)];
#pragma unroll
            for (int mi = 0; mi < 2; ++mi) {
                acc[mi][ni] = __builtin_amdgcn_mfma_f32_16x16x32_bf16(ah[mi], bh, acc[mi][ni], 0, 0, 0);
                acc[mi][ni] = __builtin_amdgcn_mfma_f32_16x16x32_bf16(ah[mi], bl, acc[mi][ni], 0, 0, 0);
                acc[mi][ni] = __builtin_amdgcn_mfma_f32_16x16x32_bf16(al[mi], bh, acc[mi][ni], 0, 0, 0);
            }
        }
    }
    // ---- epilogue: logits -> softmax -> outputs ----
    const int colb = wn * 128 + lrow;
    float cs[8];
#pragma unroll
    for (int ni = 0; ni < 8; ++ni) cs[ni] = csq[colb + ni * 16];
    // logits into acc; lane-local row max over ni
    float mx[2][4];
#pragma unroll
    for (int mi = 0; mi < 2; ++mi)
#pragma unroll
        for (int r = 0; r < 4; ++r) {
            float m = -3.0e38f;
#pragma unroll
            for (int ni = 0; ni < 8; ++ni) {
                float l = 2.0f * acc[mi][ni][r] - cs[ni];
                acc[mi][ni][r] = l;
                m = fmaxf(m, l);
            }
            mx[mi][r] = m;
        }
#pragma unroll
    for (int off = 1; off < 16; off <<= 1)
#pragma unroll
        for (int mi = 0; mi < 2; ++mi)
#pragma unroll
            for (int r = 0; r < 4; ++r) mx[mi][r] = fmaxf(mx[mi][r], __shfl_xor(mx[mi][r], off, 64));
    if (lrow == 0) {
#pragma unroll
        for (int mi = 0; mi < 2; ++mi)
#pragma unroll
            for (int r = 0; r < 4; ++r) rmaxs[wm * 32 + mi * 16 + lkb * 4 + r][wn] = mx[mi][r];
    }
    __syncthreads();
    float gmax[2][4];
#pragma unroll
    for (int mi = 0; mi < 2; ++mi)
#pragma unroll
        for (int r = 0; r < 4; ++r) {
            const int row = wm * 32 + mi * 16 + lkb * 4 + r;
            gmax[mi][r] = fmaxf(fmaxf(rmaxs[row][0], rmaxs[row][1]),
                                fmaxf(rmaxs[row][2], rmaxs[row][3]));
        }
    float sm[2][4] = {};
#pragma unroll
    for (int mi = 0; mi < 2; ++mi)
#pragma unroll
        for (int ni = 0; ni < 8; ++ni)
#pragma unroll
            for (int r = 0; r < 4; ++r) {
                float e = expf((acc[mi][ni][r] - gmax[mi][r]) * 10.0f);
                acc[mi][ni][r] = e;
                sm[mi][r] += e;
            }
#pragma unroll
    for (int off = 1; off < 16; off <<= 1)
#pragma unroll
        for (int mi = 0; mi < 2; ++mi)
#pragma unroll
            for (int r = 0; r < 4; ++r) sm[mi][r] += __shfl_xor(sm[mi][r], off, 64);
    if (lrow == 0) {
#pragma unroll
        for (int mi = 0; mi < 2; ++mi)
#pragma unroll
            for (int r = 0; r < 4; ++r) rsums[wm * 32 + mi * 16 + lkb * 4 + r][wn] = sm[mi][r];
    }
    __syncthreads();
    float inv[2][4];
#pragma unroll
    for (int mi = 0; mi < 2; ++mi)
#pragma unroll
        for (int r = 0; r < 4; ++r) {
            const int row = wm * 32 + mi * 16 + lkb * 4 + r;
            float t = rsums[row][0] + rsums[row][1] + rsums[row][2] + rsums[row][3];
            inv[mi][r] = 1.0f / (t + EPSF);
        }
    float csum[8] = {};
#pragma unroll
    for (int mi = 0; mi < 2; ++mi)
#pragma unroll
        for (int ni = 0; ni < 8; ++ni) {
            const int col = colb + ni * 16;
#pragma unroll
            for (int r = 0; r < 4; ++r) {
                const int row = wm * 32 + mi * 16 + lkb * 4 + r;
                float a = acc[mi][ni][r] * inv[mi][r];
                assign[(long)(m0 + row) * 512 + col] = a;
                Abf[(long)(m0 + row) * 512 + col] = f2bf_bits(a);
                csum[ni] += a;
            }
        }
#pragma unroll
    for (int off = 16; off < 64; off <<= 1)
#pragma unroll
        for (int ni = 0; ni < 8; ++ni) csum[ni] += __shfl_xor(csum[ni], off, 64);
    if (lkb == 0) {
#pragma unroll
        for (int ni = 0; ni < 8; ++ni) atomicAdd(&swacc[colb + ni * 16], csum[ni]);
    }
    __syncthreads();
    atomicAdd(&sum_w[tid], swacc[tid]);
}

// ---------------- gram -> S + rowsum, on Chl ----------------
__global__ __launch_bounds__(256) void gram_s_v3(const ushort* __restrict__ Chl,
                                                 const float* __restrict__ csq,
                                                 float* __restrict__ S,
                                                 float* __restrict__ rsum) {
    __shared__ __align__(16) ushort sA[128 * 64];
    __shared__ __align__(16) ushort sB[128 * 64];
    __shared__ float rs_s[128];
    const int tid = threadIdx.x;
    const int n0 = blockIdx.x * 128;
    const int m0 = blockIdx.y * 128;
    const int wid = tid >> 6, lane = tid & 63;
    const int wm = wid >> 1, wn = wid & 1;
    const int lrow = lane & 15, lkb = lane >> 4;
    f32x4v acc[4][4] = {};

#pragma unroll 1
    for (int kc = 0; kc < 16; ++kc) {
        __syncthreads();
#pragma unroll
        for (int i = 0; i < 4; ++i) {
            const int sl = wid * 256 + i * 64 + lane;
            const int r = sl >> 3, j = sl & 7;
            const int s = j ^ (r & 7);
            gload_lds16(Chl + (long)(m0 + r) * 1024 + kc * 64 + s * 8,
                        &sA[(wid * 256 + i * 64) * 8]);
            gload_lds16(Chl + (long)(n0 + r) * 1024 + kc * 64 + s * 8,
                        &sB[(wid * 256 + i * 64) * 8]);
        }
        __syncthreads();
        bf16x8 ah[4], al[4], bh[4], bl[4];
#pragma unroll
        for (int mi = 0; mi < 4; ++mi) {
            const int R = wm * 64 + mi * 16 + lrow;
            ah[mi] = *(const bf16x8*)&sA[R * 64 + ((lkb ^ (R & 7)) << 3)];
            al[mi] = *(const bf16x8*)&sA[R * 64 + (((lkb + 4) ^ (R & 7)) << 3)];
        }
#pragma unroll
        for (int ni = 0; ni < 4; ++ni) {
            const int R = wn * 64 + ni * 16 + lrow;
            bh[ni] = *(const bf16x8*)&sB[R * 64 + ((lkb ^ (R & 7)) << 3)];
            bl[ni] = *(const bf16x8*)&sB[R * 64 + (((lkb + 4) ^ (R & 7)) << 3)];
        }
#pragma unroll
        for (int mi = 0; mi < 4; ++mi)
#pragma unroll
            for (int ni = 0; ni < 4; ++ni) {
                acc[mi][ni] = __builtin_amdgcn_mfma_f32_16x16x32_bf16(ah[mi], bh[ni], acc[mi][ni], 0, 0, 0);
                acc[mi][ni] = __builtin_amdgcn_mfma_f32_16x16x32_bf16(ah[mi], bl[ni], acc[mi][ni], 0, 0, 0);
                acc[mi][ni] = __builtin_amdgcn_mfma_f32_16x16x32_bf16(al[mi], bh[ni], acc[mi][ni], 0, 0, 0);
            }
    }
    if (tid < 128) rs_s[tid] = 0.f;
    __syncthreads();
    const int colb = n0 + wn * 64 + lrow;
    float csj[4];
#pragma unroll
    for (int ni = 0; ni < 4; ++ni) csj[ni] = csq[colb + ni * 16];
#pragma unroll
    for (int mi = 0; mi < 4; ++mi) {
        const int rowb = m0 + wm * 64 + mi * 16 + lkb * 4;
#pragma unroll
        for (int r = 0; r < 4; ++r) {
            const int row = rowb + r;
            const float csi = csq[row];
            float rowpart = 0.f;
#pragma unroll
            for (int ni = 0; ni < 4; ++ni) {
                const int col = colb + ni * 16;
                float sq = csi + csj[ni] - 2.0f * acc[mi][ni][r];
                float dist = sqrtf(fmaxf(sq, 0.f) + EPSF);
                float w = fmaxf(0.f, 1.f - dist);
                float sval = (row == col) ? 0.f : (0.1f * w / (dist + EPSF));
                S[(long)row * 512 + col] = sval;
                rowpart += sval;
            }
            atomicAdd(&rs_s[row - m0], rowpart);
        }
    }
    __syncthreads();
    if (tid < 128) atomicAdd(&rsum[m0 + tid], rs_s[tid]);
}

// ---------------- wsum v3: bf16 sources, in-LDS transpose, XCD-swizzled, z=16 ----------------
__global__ __launch_bounds__(256) void wsum_v3(const ushort* __restrict__ Abf,
                                               const ushort* __restrict__ Xhl,
                                               float* __restrict__ WSp) {
    __shared__ __align__(16) ushort sA[128 * 64];   // [k][n] bf16, swizzled n-octs
    __shared__ __align__(16) ushort sB[128 * 64];   // [d][n]
    const int tid = threadIdx.x;
    // nwg=256: bijective swizzle, one z-chunk's 16 blocks -> same XCD
    const int lin = blockIdx.x + blockIdx.y * 4 + blockIdx.z * 16;
    const int T = (lin & 7) * 32 + (lin >> 3);
    const int k0 = (T & 3) * 128;
    const int d0 = ((T >> 2) & 3) * 128;
    const int zc = T >> 4;                 // 0..15
    const long n0 = (long)zc * 2048;
    const int wid = tid >> 6, lane = tid & 63;
    const int wm = wid >> 1, wn = wid & 1;
    const int lrow = lane & 15, lkb = lane >> 4;
    f32x4v acc[4][4] = {};

    for (int nc = 0; nc < 2048; nc += 64) {
        __syncthreads();
#pragma unroll
        for (int it = 0; it < 4; ++it) {
            const int idx = it * 256 + tid;
            const int c = idx & 127;
            const int no = idx >> 7;
            const long nb = n0 + nc + (long)no * 8;
            const int dd = d0 + c;
            const long xoff = (long)((dd >> 5) * 64 + (dd & 31));
            ushort ha[8], hx[8];
#pragma unroll
            for (int jj = 0; jj < 8; ++jj) {
                ha[jj] = Abf[(nb + jj) * 512 + k0 + c];
                hx[jj] = Xhl[(nb + jj) * 1024 + xoff];
            }
            const int sl = no ^ (c & 7);
            *(uint4*)&sA[c * 64 + sl * 8] = pack8(ha);
            *(uint4*)&sB[c * 64 + sl * 8] = pack8(hx);
        }
        __syncthreads();
#pragma unroll
        for (int kk = 0; kk < 2; ++kk) {
            const int j = kk * 4 + lkb;
            bf16x8 af[4], bfv[4];
#pragma unroll
            for (int mi = 0; mi < 4; ++mi) {
                const int R = wm * 64 + mi * 16 + lrow;
                af[mi] = *(const bf16x8*)&sA[R * 64 + ((j ^ (R & 7)) << 3)];
            }
#pragma unroll
            for (int ni = 0; ni < 4; ++ni) {
                const int R = wn * 64 + ni * 16 + lrow;
                bfv[ni] = *(const bf16x8*)&sB[R * 64 + ((j ^ (R & 7)) << 3)];
            }
#pragma unroll
            for (int mi = 0; mi < 4; ++mi)
#pragma unroll
                for (int ni = 0; ni < 4; ++ni)
                    acc[mi][ni] = __builtin_amdgcn_mfma_f32_16x16x32_bf16(af[mi], bfv[ni], acc[mi][ni], 0, 0, 0);
        }
    }
    float* dst = WSp + (size_t)zc * 262144;
#pragma unroll
    for (int mi = 0; mi < 4; ++mi) {
        const int k = k0 + wm * 64 + mi * 16 + lkb * 4;
#pragma unroll
        for (int ni = 0; ni < 4; ++ni) {
            const int d = d0 + wn * 64 + ni * 16 + lrow;
#pragma unroll
            for (int r = 0; r < 4; ++r)
                dst[(k + r) * 512 + d] = acc[mi][ni][r];
        }
    }
}

// ---------------- reduce partials: WS = sum_z WSp[z], z=16 ----------------
__global__ __launch_bounds__(256) void reduce_ws16(const float* __restrict__ WSp,
                                                   float* __restrict__ WS) {
    const int i4 = (blockIdx.x * 256 + threadIdx.x) * 4;
    float4 s = {0.f, 0.f, 0.f, 0.f};
#pragma unroll 4
    for (int z = 0; z < 16; ++z) {
        float4 v = *(const float4*)(WSp + (size_t)z * 262144 + i4);
        s.x += v.x; s.y += v.y; s.z += v.z; s.w += v.w;
    }
    *(float4*)(WS + i4) = s;
}

// ---------------- fused repulsion-apply + momentum update ----------------
__global__ __launch_bounds__(256) void apply_update(const float* __restrict__ Cent,
                                                    const float* __restrict__ Mom,
                                                    const float* __restrict__ S,
                                                    const float* __restrict__ rsum,
                                                    const float* __restrict__ WS,
                                                    const float* __restrict__ sum_w,
                                                    float* __restrict__ outC,
                                                    float* __restrict__ outM) {
    const int i = blockIdx.x;
    __shared__ float srow[512];
    __shared__ int nz;
    const int tid = threadIdx.x;
    if (tid == 0) nz = 0;
    __syncthreads();
    float2 sv = *(const float2*)(S + (long)i * 512 + tid * 2);
    srow[tid * 2] = sv.x;
    srow[tid * 2 + 1] = sv.y;
    if (sv.x != 0.f || sv.y != 0.f) nz = 1;
    __syncthreads();
    const float rs = rsum[i];
    const float invw = 1.0f / (sum_w[i] + EPSF);
    const int d0 = tid * 2;
    float sc0 = 0.f, sc1 = 0.f;
    if (nz) {
        for (int j = 0; j < 512; ++j) {
            const float s = srow[j];
            if (s != 0.f) {
                sc0 += s * Cent[(long)j * 512 + d0];
                sc1 += s * Cent[(long)j * 512 + d0 + 1];
            }
        }
    }
    float2 ci = *(const float2*)(Cent + (long)i * 512 + d0);
    float2 mo = *(const float2*)(Mom + (long)i * 512 + d0);
    float2 wsv = *(const float2*)(WS + (long)i * 512 + d0);
    float rep0 = rs * ci.x - sc0;
    float rep1 = rs * ci.y - sc1;
    float mn0 = 0.9f * mo.x + 0.1f * (wsv.x * invw - ci.x + rep0);
    float mn1 = 0.9f * mo.y + 0.1f * (wsv.y * invw - ci.y + rep1);
    float2 om = {mn0, mn1};
    float2 oc = {ci.x + 0.1f * mn0, ci.y + 0.1f * mn1};
    *(float2*)(outM + (long)i * 512 + d0) = om;
    *(float2*)(outC + (long)i * 512 + d0) = oc;
}

// ================= legacy fp32 fallback kernels (small-ws path) =================
__global__ __launch_bounds__(256) void csq_only(const float* __restrict__ C,
                                                float* __restrict__ csq) {
    const int wave = threadIdx.x >> 6, lane = threadIdx.x & 63;
    const int row = blockIdx.x * 4 + wave;
    const float* p = C + row * 512 + lane * 8;
    float4 a = *(const float4*)p;
    float4 b = *(const float4*)(p + 4);
    float s = a.x * a.x + a.y * a.y + a.z * a.z + a.w * a.w +
              b.x * b.x + b.y * b.y + b.z * b.z + b.w * b.w;
#pragma unroll
    for (int off = 1; off < 64; off <<= 1) s += __shfl_xor(s, off, 64);
    if (lane == 0) csq[row] = s;
}

__global__ __launch_bounds__(256) void logits_mfma(const float* __restrict__ X,
                                                   const float* __restrict__ Cm,
                                                   const float* __restrict__ csq,
                                                   float* __restrict__ L) {
    __shared__ ushort sAh[128][64];
    __shared__ ushort sAl[128][64];
    __shared__ ushort sBh[128][64];
    __shared__ ushort sBl[128][64];
    const int tid = threadIdx.x;
    const int m0 = blockIdx.x * 128;
    const int n0 = blockIdx.y * 128;
    const int wid = tid >> 6, lane = tid & 63;
    const int wm = wid >> 1, wn = wid & 1;
    const int lrow = lane & 15;
    const int lkb = lane >> 4;
    f32x4v acc[4][4] = {};
    for (int k0 = 0; k0 < 512; k0 += 64) {
        __syncthreads();
#pragma unroll
        for (int s = 0; s < 8; ++s) {
            const int idx = s * 256 + tid;
            const int r = idx >> 4;
            const int c4 = (idx & 15) << 2;
            const int e = c4 ^ ((r & 7) << 3);
            float4 va = *(const float4*)(X + (long)(m0 + r) * 512 + k0 + c4);
            ushort4 hh, ll;
            split2(va.x, hh.x, ll.x);
            split2(va.y, hh.y, ll.y);
            split2(va.z, hh.z, ll.z);
            split2(va.w, hh.w, ll.w);
            *(ushort4*)&sAh[r][e] = hh;
            *(ushort4*)&sAl[r][e] = ll;
            float4 vb = *(const float4*)(Cm + (long)(n0 + r) * 512 + k0 + c4);
            split2(vb.x, hh.x, ll.x);
            split2(vb.y, hh.y, ll.y);
            split2(vb.z, hh.z, ll.z);
            split2(vb.w, hh.w, ll.w);
            *(ushort4*)&sBh[r][e] = hh;
            *(ushort4*)&sBl[r][e] = ll;
        }
        __syncthreads();
#pragma unroll
        for (int kk = 0; kk < 2; ++kk) {
            const int ebase = kk * 32 + lkb * 8;
            bf16x8 ah[4], al[4], bh[4], bl[4];
#pragma unroll
            for (int mi = 0; mi < 4; ++mi) {
                const int R = wm * 64 + mi * 16 + lrow;
                const int e = ebase ^ ((R & 7) << 3);
                ah[mi] = *(const bf16x8*)&sAh[R][e];
                al[mi] = *(const bf16x8*)&sAl[R][e];
            }
#pragma unroll
            for (int ni = 0; ni < 4; ++ni) {
                const int Rn = wn * 64 + ni * 16 + lrow;
                const int e = ebase ^ ((Rn & 7) << 3);
                bh[ni] = *(const bf16x8*)&sBh[Rn][e];
                bl[ni] = *(const bf16x8*)&sBl[Rn][e];
            }
#pragma unroll
            for (int mi = 0; mi < 4; ++mi)
#pragma unroll
                for (int ni = 0; ni < 4; ++ni) {
                    acc[mi][ni] = __builtin_amdgcn_mfma_f32_16x16x32_bf16(ah[mi], bh[ni], acc[mi][ni], 0, 0, 0);
                    acc[mi][ni] = __builtin_amdgcn_mfma_f32_16x16x32_bf16(ah[mi], bl[ni], acc[mi][ni], 0, 0, 0);
                    acc[mi][ni] = __builtin_amdgcn_mfma_f32_16x16x32_bf16(al[mi], bh[ni], acc[mi][ni], 0, 0, 0);
                }
        }
    }
    const int colb = n0 + wn * 64 + lrow;
    float cs[4];
#pragma unroll
    for (int ni = 0; ni < 4; ++ni) cs[ni] = csq[colb + ni * 16];
#pragma unroll
    for (int mi = 0; mi < 4; ++mi) {
        const int rowb = m0 + wm * 64 + mi * 16 + lkb * 4;
#pragma unroll
        for (int r = 0; r < 4; ++r) {
            float* Lp = L + (long)(rowb + r) * 512 + colb;
#pragma unroll
            for (int ni = 0; ni < 4; ++ni)
                Lp[ni * 16] = 2.0f * acc[mi][ni][r] - cs[ni];
        }
    }
}

__global__ __launch_bounds__(256) void softmax_rows(float* __restrict__ L,
                                                    float* __restrict__ sum_w,
                                                    ushort* __restrict__ Abf) {
    __shared__ float swacc[512];
    const int tid = threadIdx.x;
    for (int i = tid; i < 512; i += 256) swacc[i] = 0.f;
    __syncthreads();
    const int wave = tid >> 6, lane = tid & 63;
    float racc[8] = {};
    for (int r = blockIdx.x * 4 + wave; r < 32768; r += 2048) {
        float* p = L + (long)r * 512 + lane * 8;
        float4 v0 = *(float4*)p;
        float4 v1 = *(float4*)(p + 4);
        float v[8] = {v0.x, v0.y, v0.z, v0.w, v1.x, v1.y, v1.z, v1.w};
        float m = v[0];
#pragma unroll
        for (int i = 1; i < 8; ++i) m = fmaxf(m, v[i]);
#pragma unroll
        for (int off = 1; off < 64; off <<= 1) m = fmaxf(m, __shfl_xor(m, off, 64));
        float e[8], s = 0.f;
#pragma unroll
        for (int i = 0; i < 8; ++i) {
            e[i] = expf((v[i] - m) * 10.0f);
            s += e[i];
        }
#pragma unroll
        for (int off = 1; off < 64; off <<= 1) s += __shfl_xor(s, off, 64);
        const float inv = 1.0f / (s + EPSF);
        ushort eb[8];
#pragma unroll
        for (int i = 0; i < 8; ++i) {
            e[i] *= inv;
            racc[i] += e[i];
            eb[i] = f2bf_bits(e[i]);
        }
        float4 o0 = {e[0], e[1], e[2], e[3]};
        float4 o1 = {e[4], e[5], e[6], e[7]};
        *(float4*)p = o0;
        *(float4*)(p + 4) = o1;
        if (Abf) *(uint4*)(Abf + (long)r * 512 + lane * 8) = pack8(eb);
    }
#pragma unroll
    for (int i = 0; i < 8; ++i) atomicAdd(&swacc[lane * 8 + i], racc[i]);
    __syncthreads();
    for (int i = tid; i < 512; i += 256) atomicAdd(&sum_w[i], swacc[i]);
}

__global__ __launch_bounds__(256) void gemm_wsum(const float* __restrict__ A,
                                                 const float* __restrict__ X,
                                                 float* __restrict__ WS) {
    __shared__ float As[16][64];
    __shared__ float Xs[16][64];
    const int tid = threadIdx.x;
    const int tx = tid & 15, ty = tid >> 4;
    const int lrow = tid >> 4;
    const int lcol = (tid & 15) << 2;
    const int k0 = blockIdx.x * 64;
    const int d0 = blockIdx.y * 64;
    const int n0 = blockIdx.z * 1024;
    float acc[4][4] = {};
    for (int nc = 0; nc < 1024; nc += 16) {
        const long nrow = n0 + nc + lrow;
        float4 av = *(const float4*)(A + nrow * 512 + k0 + lcol);
        float4 xv = *(const float4*)(X + nrow * 512 + d0 + lcol);
        __syncthreads();
        *(float4*)&As[lrow][lcol] = av;
        *(float4*)&Xs[lrow][lcol] = xv;
        __syncthreads();
#pragma unroll
        for (int nn = 0; nn < 16; ++nn) {
            float4 a = *(const float4*)&As[nn][ty << 2];
            float4 x = *(const float4*)&Xs[nn][tx << 2];
            float aa[4] = {a.x, a.y, a.z, a.w};
            float xx[4] = {x.x, x.y, x.z, x.w};
#pragma unroll
            for (int i = 0; i < 4; ++i)
#pragma unroll
                for (int j = 0; j < 4; ++j) acc[i][j] += aa[i] * xx[j];
        }
    }
#pragma unroll
    for (int i = 0; i < 4; ++i)
#pragma unroll
        for (int j = 0; j < 4; ++j)
            atomicAdd(&WS[(k0 + (ty << 2) + i) * 512 + d0 + (tx << 2) + j], acc[i][j]);
}

__global__ __launch_bounds__(256) void repulse_update(const float* __restrict__ Cent,
                                                      const float* __restrict__ Mom,
                                                      const float* __restrict__ csq,
                                                      const float* __restrict__ WS,
                                                      const float* __restrict__ sum_w,
                                                      float* __restrict__ outC,
                                                      float* __restrict__ outM) {
    const int i = blockIdx.x;
    __shared__ float ci[512];
    __shared__ float rep[512];
    const int tid = threadIdx.x, wave = tid >> 6, lane = tid & 63;
    for (int d = tid; d < 512; d += 256) {
        ci[d] = Cent[i * 512 + d];
        rep[d] = 0.f;
    }
    __syncthreads();
    float cil[8];
#pragma unroll
    for (int m = 0; m < 8; ++m) cil[m] = ci[lane * 8 + m];
    const float csqi = csq[i];
    float racc[8] = {};
    for (int j = wave; j < 512; j += 4) {
        if (j == i) continue;
        const float* cj = Cent + j * 512 + lane * 8;
        float4 c0 = *(const float4*)cj;
        float4 c1 = *(const float4*)(cj + 4);
        float cjl[8] = {c0.x, c0.y, c0.z, c0.w, c1.x, c1.y, c1.z, c1.w};
        float dot = 0.f;
#pragma unroll
        for (int m = 0; m < 8; ++m) dot += cil[m] * cjl[m];
#pragma unroll
        for (int off = 1; off < 64; off <<= 1) dot += __shfl_xor(dot, off, 64);
        float sq = csqi + csq[j] - 2.f * dot;
        float dist = sqrtf(fmaxf(sq, 0.f) + EPSF);
        float w = fmaxf(0.f, 1.f - dist);
        float scale = 0.1f * w / (dist + EPSF);
#pragma unroll
        for (int m = 0; m < 8; ++m) racc[m] += scale * (cil[m] - cjl[m]);
    }
#pragma unroll
    for (int m = 0; m < 8; ++m) atomicAdd(&rep[lane * 8 + m], racc[m]);
    __syncthreads();
    const float invw = 1.0f / (sum_w[i] + EPSF);
    for (int d = tid; d < 512; d += 256) {
        float nc = WS[i * 512 + d] * invw;
        float upd = nc - ci[d] + rep[d];
        float mn = 0.9f * Mom[i * 512 + d] + 0.1f * upd;
        outM[i * 512 + d] = mn;
        outC[i * 512 + d] = ci[d] + 0.1f * mn;
    }
}

extern "C" void kernel_launch(void* const* d_in, const int* in_sizes, int n_in,
                              void* d_out, int out_size, void* d_ws, size_t ws_size,
                              hipStream_t stream) {
    const float* X = (const float*)d_in[0];      // (32768, 512)
    const float* C = (const float*)d_in[1];      // (512, 512)
    const float* M = (const float*)d_in[2];      // (512, 512)
    float* out = (float*)d_out;
    float* assign = out;                          // 32768*512
    float* outC = out + 16777216;                 // 512*512
    float* outM = outC + 262144;                  // 512*512

    char* wsb = (char*)d_ws;
    const size_t MB = 1024ull * 1024ull;
    float* WS = (float*)wsb;                            // 1 MB
    float* sum_w = (float*)(wsb + 1 * MB);              // 2 KB
    float* rsum = (float*)(wsb + 1 * MB + 2048);        // 2 KB
    float* csq = (float*)(wsb + 1 * MB + 4096);         // 2 KB
    ushort* Chl = (ushort*)(wsb + 2 * MB);              // 1 MB (512 x 1024 bf16)
    float* S = (float*)(wsb + 3 * MB);                  // 1 MB
    float* WSp = (float*)(wsb + 4 * MB);                // 16 MB (z=16)
    ushort* Xhl = (ushort*)(wsb + 36 * MB);             // 64 MB
    ushort* Abf = (ushort*)(wsb + 100 * MB);            // 32 MB
    const size_t NEED = 132 * MB;                       // proven available

    hipMemsetAsync(d_ws, 0, 1 * MB + 8192, stream);     // WS + sum_w + rsum hdr

    if (ws_size >= NEED) {
        csqc_v3<<<128, 256, 0, stream>>>(C, csq, Chl);
        gram_s_v3<<<dim3(4, 4), 256, 0, stream>>>(Chl, csq, S, rsum);
        convert_xhl<<<8192, 256, 0, stream>>>(X, Xhl);
        logsm<<<512, 512, 0, stream>>>(Xhl, Chl, csq, assign, Abf, sum_w);
        wsum_v3<<<dim3(4, 4, 16), 256, 0, stream>>>(Abf, Xhl, WSp);
        reduce_ws16<<<256, 256, 0, stream>>>(WSp, WS);
        apply_update<<<512, 256, 0, stream>>>(C, M, S, rsum, WS, sum_w, outC, outM);
    } else {
        csq_only<<<128, 256, 0, stream>>>(C, csq);
        logits_mfma<<<dim3(256, 4), 256, 0, stream>>>(X, C, csq, assign);
        softmax_rows<<<512, 256, 0, stream>>>(assign, sum_w, nullptr);
        gemm_wsum<<<dim3(8, 8, 32), 256, 0, stream>>>(assign, X, WS);
        repulse_update<<<512, 256, 0, stream>>>(C, M, csq, WS, sum_w, outC, outM);
    }
}

// Round 10
// 172.095 us; speedup vs baseline: 3.6570x; 1.0871x over previous
//
#include <hip/hip_runtime.h>
#include <hip/hip_bf16.h>

#define EPSF 1e-7f

typedef __attribute__((ext_vector_type(8))) short bf16x8;
typedef __attribute__((ext_vector_type(4))) float f32x4v;

__device__ inline ushort f2bf_bits(float x) {
    union { __hip_bfloat16 b; ushort u; } cv;
    cv.b = __float2bfloat16(x);
    return cv.u;
}
__device__ inline float bfbits2f(ushort u) {
    union { ushort u; __hip_bfloat16 b; } cv;
    cv.u = u;
    return __bfloat162float(cv.b);
}
__device__ inline void split2(float x, ushort& h, ushort& l) {
    h = f2bf_bits(x);
    l = f2bf_bits(x - bfbits2f(h));
}
__device__ inline uint4 pack8(const ushort* h) {
    uint4 p;
    p.x = (uint)h[0] | ((uint)h[1] << 16);
    p.y = (uint)h[2] | ((uint)h[3] << 16);
    p.z = (uint)h[4] | ((uint)h[5] << 16);
    p.w = (uint)h[6] | ((uint)h[7] << 16);
    return p;
}

__device__ inline void gload_lds16(const ushort* g, ushort* l) {
    __builtin_amdgcn_global_load_lds(
        (const __attribute__((address_space(1))) unsigned int*)g,
        (__attribute__((address_space(3))) unsigned int*)l, 16, 0, 0);
}

// ---------------- csq + C -> Chl (interleaved hi/lo per 32-k chunk) ----------------
__global__ __launch_bounds__(256) void csqc_v3(const float* __restrict__ C,
                                               float* __restrict__ csq,
                                               ushort* __restrict__ Chl) {
    const int wave = threadIdx.x >> 6, lane = threadIdx.x & 63;
    const int row = blockIdx.x * 4 + wave;
    const int kc = lane >> 2, s = lane & 3;
    const float* p = C + row * 512 + lane * 8;
    float4 a = *(const float4*)p;
    float4 b = *(const float4*)(p + 4);
    float v[8] = {a.x, a.y, a.z, a.w, b.x, b.y, b.z, b.w};
    ushort h[8], l[8];
    float sqs = 0.f;
#pragma unroll
    for (int i = 0; i < 8; ++i) {
        sqs += v[i] * v[i];
        split2(v[i], h[i], l[i]);
    }
    ushort* base = Chl + (long)row * 1024 + kc * 64 + s * 8;
    *(uint4*)base = pack8(h);
    *(uint4*)(base + 32) = pack8(l);
#pragma unroll
    for (int off = 1; off < 64; off <<= 1) sqs += __shfl_xor(sqs, off, 64);
    if (lane == 0) csq[row] = sqs;
}

// ---------------- X -> Xhl (interleaved hi/lo) ----------------
__global__ __launch_bounds__(256) void convert_xhl(const float* __restrict__ X,
                                                   ushort* __restrict__ Xhl) {
    const long idx = (long)blockIdx.x * 256 + threadIdx.x;   // 2,097,152 octets
    const long row = idx >> 6;
    const int oct = (int)(idx & 63);
    const int kc = oct >> 2, s = oct & 3;
    const float* src = X + row * 512 + oct * 8;
    float4 a = *(const float4*)src;
    float4 b = *(const float4*)(src + 4);
    float v[8] = {a.x, a.y, a.z, a.w, b.x, b.y, b.z, b.w};
    ushort h[8], l[8];
#pragma unroll
    for (int i = 0; i < 8; ++i) split2(v[i], h[i], l[i]);
    ushort* base = Xhl + row * 1024 + kc * 64 + s * 8;
    *(uint4*)base = pack8(h);
    *(uint4*)(base + 32) = pack8(l);
}

// ---------------- logsm v2: fused logits GEMM + row softmax, half-staged B ----------------
// BM=64 rows, BN=512 (full row). 512 thr = 8 waves (2m x 4n).
// B staged in 2 halves of 256 rows (32 KB) -> LDS ~44 KB -> 3 blocks/CU.
// Wave wn owns cols {wn*64..+63} U {256+wn*64..+63}: ni<4 -> half0, ni>=4 -> half1.
__global__ __launch_bounds__(512) void logsm(const ushort* __restrict__ Xhl,
                                             const ushort* __restrict__ Chl,
                                             const float* __restrict__ csq,
                                             float* __restrict__ assign,
                                             ushort* __restrict__ Abf,
                                             float* __restrict__ sum_w) {
    __shared__ __align__(16) ushort sA[64 * 64];      // 8 KB
    __shared__ __align__(16) ushort sB[256 * 64];     // 32 KB
    __shared__ float rmaxs[64][4];
    __shared__ float rsums[64][4];
    __shared__ float swacc[512];
    const int tid = threadIdx.x;
    // XCD-aware bijective swizzle over 512 m-tiles (512 % 8 == 0)
    const int m0 = ((blockIdx.x & 7) * 64 + (blockIdx.x >> 3)) * 64;
    const int wid = tid >> 6, lane = tid & 63;
    const int wm = wid >> 2, wn = wid & 3;
    const int lrow = lane & 15, lkb = lane >> 4;
    swacc[tid] = 0.f;
    f32x4v acc[2][8] = {};

#pragma unroll 1
    for (int kc = 0; kc < 16; ++kc) {
        bf16x8 ah[2], al[2];
        // ---- half 0: stage A + B rows 0..255 ----
        __syncthreads();
        {   // A: 64 rows x 8 slots = 512 slots, 1/thread
            const int r = tid >> 3, j = tid & 7;
            const int s = j ^ (r & 7);
            gload_lds16(Xhl + (long)(m0 + r) * 1024 + kc * 64 + s * 8,
                        &sA[(wid * 64) * 8]);
        }
#pragma unroll
        for (int i = 0; i < 4; ++i) {   // B half0: 256 rows = 2048 slots, 4/thread
            const int sl = i * 512 + tid;
            const int r = sl >> 3, j = sl & 7;
            const int s = j ^ (r & 7);
            gload_lds16(Chl + (long)r * 1024 + kc * 64 + s * 8,
                        &sB[(i * 512 + wid * 64) * 8]);
        }
        __syncthreads();
#pragma unroll
        for (int mi = 0; mi < 2; ++mi) {
            const int R = wm * 32 + mi * 16 + lrow;
            ah[mi] = *(const bf16x8*)&sA[R * 64 + ((lkb ^ (R & 7)) << 3)];
            al[mi] = *(const bf16x8*)&sA[R * 64 + (((lkb + 4) ^ (R & 7)) << 3)];
        }
#pragma unroll
        for (int ni = 0; ni < 4; ++ni) {
            const int Rl = wn * 64 + ni * 16 + lrow;   // LDS row = global col (half0)
            bf16x8 bh = *(const bf16x8*)&sB[Rl * 64 + ((lkb ^ (Rl & 7)) << 3)];
            bf16x8 bl = *(const bf16x8*)&sB[Rl * 64 + (((lkb + 4) ^ (Rl & 7)) << 3)];
#pragma unroll
            for (int mi = 0; mi < 2; ++mi) {
                acc[mi][ni] = __builtin_amdgcn_mfma_f32_16x16x32_bf16(ah[mi], bh, acc[mi][ni], 0, 0, 0);
                acc[mi][ni] = __builtin_amdgcn_mfma_f32_16x16x32_bf16(ah[mi], bl, acc[mi][ni], 0, 0, 0);
                acc[mi][ni] = __builtin_amdgcn_mfma_f32_16x16x32_bf16(al[mi], bh, acc[mi][ni], 0, 0, 0);
            }
        }
        // ---- half 1: stage B rows 256..511 ----
        __syncthreads();
#pragma unroll
        for (int i = 0; i < 4; ++i) {
            const int sl = i * 512 + tid;
            const int r = sl >> 3, j = sl & 7;
            const int s = j ^ (r & 7);
            gload_lds16(Chl + (long)(256 + r) * 1024 + kc * 64 + s * 8,
                        &sB[(i * 512 + wid * 64) * 8]);
        }
        __syncthreads();
#pragma unroll
        for (int ni = 0; ni < 4; ++ni) {
            const int Rl = wn * 64 + ni * 16 + lrow;   // LDS row = global col - 256
            bf16x8 bh = *(const bf16x8*)&sB[Rl * 64 + ((lkb ^ (Rl & 7)) << 3)];
            bf16x8 bl = *(const bf16x8*)&sB[Rl * 64 + (((lkb + 4) ^ (Rl & 7)) << 3)];
#pragma unroll
            for (int mi = 0; mi < 2; ++mi) {
                acc[mi][4 + ni] = __builtin_amdgcn_mfma_f32_16x16x32_bf16(ah[mi], bh, acc[mi][4 + ni], 0, 0, 0);
                acc[mi][4 + ni] = __builtin_amdgcn_mfma_f32_16x16x32_bf16(ah[mi], bl, acc[mi][4 + ni], 0, 0, 0);
                acc[mi][4 + ni] = __builtin_amdgcn_mfma_f32_16x16x32_bf16(al[mi], bh, acc[mi][4 + ni], 0, 0, 0);
            }
        }
    }
    // ---- epilogue: logits -> softmax -> outputs ----
    // col(ni) = (ni>>2)*256 + wn*64 + (ni&3)*16 + lrow
    float cs[8];
#pragma unroll
    for (int ni = 0; ni < 8; ++ni)
        cs[ni] = csq[(ni >> 2) * 256 + wn * 64 + (ni & 3) * 16 + lrow];
    float mx[2][4];
#pragma unroll
    for (int mi = 0; mi < 2; ++mi)
#pragma unroll
        for (int r = 0; r < 4; ++r) {
            float m = -3.0e38f;
#pragma unroll
            for (int ni = 0; ni < 8; ++ni) {
                float l = 2.0f * acc[mi][ni][r] - cs[ni];
                acc[mi][ni][r] = l;
                m = fmaxf(m, l);
            }
            mx[mi][r] = m;
        }
#pragma unroll
    for (int off = 1; off < 16; off <<= 1)
#pragma unroll
        for (int mi = 0; mi < 2; ++mi)
#pragma unroll
            for (int r = 0; r < 4; ++r) mx[mi][r] = fmaxf(mx[mi][r], __shfl_xor(mx[mi][r], off, 64));
    if (lrow == 0) {
#pragma unroll
        for (int mi = 0; mi < 2; ++mi)
#pragma unroll
            for (int r = 0; r < 4; ++r) rmaxs[wm * 32 + mi * 16 + lkb * 4 + r][wn] = mx[mi][r];
    }
    __syncthreads();
    float gmax[2][4];
#pragma unroll
    for (int mi = 0; mi < 2; ++mi)
#pragma unroll
        for (int r = 0; r < 4; ++r) {
            const int row = wm * 32 + mi * 16 + lkb * 4 + r;
            gmax[mi][r] = fmaxf(fmaxf(rmaxs[row][0], rmaxs[row][1]),
                                fmaxf(rmaxs[row][2], rmaxs[row][3]));
        }
    float sm[2][4] = {};
#pragma unroll
    for (int mi = 0; mi < 2; ++mi)
#pragma unroll
        for (int ni = 0; ni < 8; ++ni)
#pragma unroll
            for (int r = 0; r < 4; ++r) {
                float e = expf((acc[mi][ni][r] - gmax[mi][r]) * 10.0f);
                acc[mi][ni][r] = e;
                sm[mi][r] += e;
            }
#pragma unroll
    for (int off = 1; off < 16; off <<= 1)
#pragma unroll
        for (int mi = 0; mi < 2; ++mi)
#pragma unroll
            for (int r = 0; r < 4; ++r) sm[mi][r] += __shfl_xor(sm[mi][r], off, 64);
    if (lrow == 0) {
#pragma unroll
        for (int mi = 0; mi < 2; ++mi)
#pragma unroll
            for (int r = 0; r < 4; ++r) rsums[wm * 32 + mi * 16 + lkb * 4 + r][wn] = sm[mi][r];
    }
    __syncthreads();
    float inv[2][4];
#pragma unroll
    for (int mi = 0; mi < 2; ++mi)
#pragma unroll
        for (int r = 0; r < 4; ++r) {
            const int row = wm * 32 + mi * 16 + lkb * 4 + r;
            float t = rsums[row][0] + rsums[row][1] + rsums[row][2] + rsums[row][3];
            inv[mi][r] = 1.0f / (t + EPSF);
        }
    float csum[8] = {};
#pragma unroll
    for (int mi = 0; mi < 2; ++mi)
#pragma unroll
        for (int ni = 0; ni < 8; ++ni) {
            const int col = (ni >> 2) * 256 + wn * 64 + (ni & 3) * 16 + lrow;
#pragma unroll
            for (int r = 0; r < 4; ++r) {
                const int row = wm * 32 + mi * 16 + lkb * 4 + r;
                float a = acc[mi][ni][r] * inv[mi][r];
                assign[(long)(m0 + row) * 512 + col] = a;
                Abf[(long)(m0 + row) * 512 + col] = f2bf_bits(a);
                csum[ni] += a;
            }
        }
#pragma unroll
    for (int off = 16; off < 64; off <<= 1)
#pragma unroll
        for (int ni = 0; ni < 8; ++ni) csum[ni] += __shfl_xor(csum[ni], off, 64);
    if (lkb == 0) {
#pragma unroll
        for (int ni = 0; ni < 8; ++ni) {
            const int col = (ni >> 2) * 256 + wn * 64 + (ni & 3) * 16 + lrow;
            atomicAdd(&swacc[col], csum[ni]);
        }
    }
    __syncthreads();
    atomicAdd(&sum_w[tid], swacc[tid]);
}

// ---------------- gram -> S + rowsum, on Chl ----------------
__global__ __launch_bounds__(256) void gram_s_v3(const ushort* __restrict__ Chl,
                                                 const float* __restrict__ csq,
                                                 float* __restrict__ S,
                                                 float* __restrict__ rsum) {
    __shared__ __align__(16) ushort sA[128 * 64];
    __shared__ __align__(16) ushort sB[128 * 64];
    __shared__ float rs_s[128];
    const int tid = threadIdx.x;
    const int n0 = blockIdx.x * 128;
    const int m0 = blockIdx.y * 128;
    const int wid = tid >> 6, lane = tid & 63;
    const int wm = wid >> 1, wn = wid & 1;
    const int lrow = lane & 15, lkb = lane >> 4;
    f32x4v acc[4][4] = {};

#pragma unroll 1
    for (int kc = 0; kc < 16; ++kc) {
        __syncthreads();
#pragma unroll
        for (int i = 0; i < 4; ++i) {
            const int sl = wid * 256 + i * 64 + lane;
            const int r = sl >> 3, j = sl & 7;
            const int s = j ^ (r & 7);
            gload_lds16(Chl + (long)(m0 + r) * 1024 + kc * 64 + s * 8,
                        &sA[(wid * 256 + i * 64) * 8]);
            gload_lds16(Chl + (long)(n0 + r) * 1024 + kc * 64 + s * 8,
                        &sB[(wid * 256 + i * 64) * 8]);
        }
        __syncthreads();
        bf16x8 ah[4], al[4], bh[4], bl[4];
#pragma unroll
        for (int mi = 0; mi < 4; ++mi) {
            const int R = wm * 64 + mi * 16 + lrow;
            ah[mi] = *(const bf16x8*)&sA[R * 64 + ((lkb ^ (R & 7)) << 3)];
            al[mi] = *(const bf16x8*)&sA[R * 64 + (((lkb + 4) ^ (R & 7)) << 3)];
        }
#pragma unroll
        for (int ni = 0; ni < 4; ++ni) {
            const int R = wn * 64 + ni * 16 + lrow;
            bh[ni] = *(const bf16x8*)&sB[R * 64 + ((lkb ^ (R & 7)) << 3)];
            bl[ni] = *(const bf16x8*)&sB[R * 64 + (((lkb + 4) ^ (R & 7)) << 3)];
        }
#pragma unroll
        for (int mi = 0; mi < 4; ++mi)
#pragma unroll
            for (int ni = 0; ni < 4; ++ni) {
                acc[mi][ni] = __builtin_amdgcn_mfma_f32_16x16x32_bf16(ah[mi], bh[ni], acc[mi][ni], 0, 0, 0);
                acc[mi][ni] = __builtin_amdgcn_mfma_f32_16x16x32_bf16(ah[mi], bl[ni], acc[mi][ni], 0, 0, 0);
                acc[mi][ni] = __builtin_amdgcn_mfma_f32_16x16x32_bf16(al[mi], bh[ni], acc[mi][ni], 0, 0, 0);
            }
    }
    if (tid < 128) rs_s[tid] = 0.f;
    __syncthreads();
    const int colb = n0 + wn * 64 + lrow;
    float csj[4];
#pragma unroll
    for (int ni = 0; ni < 4; ++ni) csj[ni] = csq[colb + ni * 16];
#pragma unroll
    for (int mi = 0; mi < 4; ++mi) {
        const int rowb = m0 + wm * 64 + mi * 16 + lkb * 4;
#pragma unroll
        for (int r = 0; r < 4; ++r) {
            const int row = rowb + r;
            const float csi = csq[row];
            float rowpart = 0.f;
#pragma unroll
            for (int ni = 0; ni < 4; ++ni) {
                const int col = colb + ni * 16;
                float sq = csi + csj[ni] - 2.0f * acc[mi][ni][r];
                float dist = sqrtf(fmaxf(sq, 0.f) + EPSF);
                float w = fmaxf(0.f, 1.f - dist);
                float sval = (row == col) ? 0.f : (0.1f * w / (dist + EPSF));
                S[(long)row * 512 + col] = sval;
                rowpart += sval;
            }
            atomicAdd(&rs_s[row - m0], rowpart);
        }
    }
    __syncthreads();
    if (tid < 128) atomicAdd(&rsum[m0 + tid], rs_s[tid]);
}

// ---------------- wsum v3: bf16 sources, in-LDS transpose, XCD-swizzled, z=32 ----------------
__global__ __launch_bounds__(256) void wsum_v3(const ushort* __restrict__ Abf,
                                               const ushort* __restrict__ Xhl,
                                               float* __restrict__ WSp) {
    __shared__ __align__(16) ushort sA[128 * 64];   // [k][n] bf16, swizzled n-octs
    __shared__ __align__(16) ushort sB[128 * 64];   // [d][n]
    const int tid = threadIdx.x;
    // nwg=512: bijective swizzle, one z-chunk's 16 blocks -> same XCD
    const int lin = blockIdx.x + blockIdx.y * 4 + blockIdx.z * 16;
    const int T = (lin & 7) * 64 + (lin >> 3);
    const int k0 = (T & 3) * 128;
    const int d0 = ((T >> 2) & 3) * 128;
    const int zc = T >> 4;                 // 0..31
    const long n0 = (long)zc * 1024;
    const int wid = tid >> 6, lane = tid & 63;
    const int wm = wid >> 1, wn = wid & 1;
    const int lrow = lane & 15, lkb = lane >> 4;
    f32x4v acc[4][4] = {};

    for (int nc = 0; nc < 1024; nc += 64) {
        __syncthreads();
#pragma unroll
        for (int it = 0; it < 4; ++it) {
            const int idx = it * 256 + tid;
            const int c = idx & 127;
            const int no = idx >> 7;
            const long nb = n0 + nc + (long)no * 8;
            const int dd = d0 + c;
            const long xoff = (long)((dd >> 5) * 64 + (dd & 31));
            ushort ha[8], hx[8];
#pragma unroll
            for (int jj = 0; jj < 8; ++jj) {
                ha[jj] = Abf[(nb + jj) * 512 + k0 + c];
                hx[jj] = Xhl[(nb + jj) * 1024 + xoff];
            }
            const int sl = no ^ (c & 7);
            *(uint4*)&sA[c * 64 + sl * 8] = pack8(ha);
            *(uint4*)&sB[c * 64 + sl * 8] = pack8(hx);
        }
        __syncthreads();
#pragma unroll
        for (int kk = 0; kk < 2; ++kk) {
            const int j = kk * 4 + lkb;
            bf16x8 af[4], bfv[4];
#pragma unroll
            for (int mi = 0; mi < 4; ++mi) {
                const int R = wm * 64 + mi * 16 + lrow;
                af[mi] = *(const bf16x8*)&sA[R * 64 + ((j ^ (R & 7)) << 3)];
            }
#pragma unroll
            for (int ni = 0; ni < 4; ++ni) {
                const int R = wn * 64 + ni * 16 + lrow;
                bfv[ni] = *(const bf16x8*)&sB[R * 64 + ((j ^ (R & 7)) << 3)];
            }
#pragma unroll
            for (int mi = 0; mi < 4; ++mi)
#pragma unroll
                for (int ni = 0; ni < 4; ++ni)
                    acc[mi][ni] = __builtin_amdgcn_mfma_f32_16x16x32_bf16(af[mi], bfv[ni], acc[mi][ni], 0, 0, 0);
        }
    }
    float* dst = WSp + (size_t)zc * 262144;
#pragma unroll
    for (int mi = 0; mi < 4; ++mi) {
        const int k = k0 + wm * 64 + mi * 16 + lkb * 4;
#pragma unroll
        for (int ni = 0; ni < 4; ++ni) {
            const int d = d0 + wn * 64 + ni * 16 + lrow;
#pragma unroll
            for (int r = 0; r < 4; ++r)
                dst[(k + r) * 512 + d] = acc[mi][ni][r];
        }
    }
}

// ---------------- reduce partials: WS = sum_z WSp[z], z=32 ----------------
__global__ __launch_bounds__(256) void reduce_ws32(const float* __restrict__ WSp,
                                                   float* __restrict__ WS) {
    const int i4 = (blockIdx.x * 256 + threadIdx.x) * 4;
    float4 s = {0.f, 0.f, 0.f, 0.f};
#pragma unroll 4
    for (int z = 0; z < 32; ++z) {
        float4 v = *(const float4*)(WSp + (size_t)z * 262144 + i4);
        s.x += v.x; s.y += v.y; s.z += v.z; s.w += v.w;
    }
    *(float4*)(WS + i4) = s;
}

// ---------------- fused repulsion-apply + momentum update ----------------
__global__ __launch_bounds__(256) void apply_update(const float* __restrict__ Cent,
                                                    const float* __restrict__ Mom,
                                                    const float* __restrict__ S,
                                                    const float* __restrict__ rsum,
                                                    const float* __restrict__ WS,
                                                    const float* __restrict__ sum_w,
                                                    float* __restrict__ outC,
                                                    float* __restrict__ outM) {
    const int i = blockIdx.x;
    __shared__ float srow[512];
    __shared__ int nz;
    const int tid = threadIdx.x;
    if (tid == 0) nz = 0;
    __syncthreads();
    float2 sv = *(const float2*)(S + (long)i * 512 + tid * 2);
    srow[tid * 2] = sv.x;
    srow[tid * 2 + 1] = sv.y;
    if (sv.x != 0.f || sv.y != 0.f) nz = 1;
    __syncthreads();
    const float rs = rsum[i];
    const float invw = 1.0f / (sum_w[i] + EPSF);
    const int d0 = tid * 2;
    float sc0 = 0.f, sc1 = 0.f;
    if (nz) {
        for (int j = 0; j < 512; ++j) {
            const float s = srow[j];
            if (s != 0.f) {
                sc0 += s * Cent[(long)j * 512 + d0];
                sc1 += s * Cent[(long)j * 512 + d0 + 1];
            }
        }
    }
    float2 ci = *(const float2*)(Cent + (long)i * 512 + d0);
    float2 mo = *(const float2*)(Mom + (long)i * 512 + d0);
    float2 wsv = *(const float2*)(WS + (long)i * 512 + d0);
    float rep0 = rs * ci.x - sc0;
    float rep1 = rs * ci.y - sc1;
    float mn0 = 0.9f * mo.x + 0.1f * (wsv.x * invw - ci.x + rep0);
    float mn1 = 0.9f * mo.y + 0.1f * (wsv.y * invw - ci.y + rep1);
    float2 om = {mn0, mn1};
    float2 oc = {ci.x + 0.1f * mn0, ci.y + 0.1f * mn1};
    *(float2*)(outM + (long)i * 512 + d0) = om;
    *(float2*)(outC + (long)i * 512 + d0) = oc;
}

// ================= legacy fp32 fallback kernels (small-ws path) =================
__global__ __launch_bounds__(256) void csq_only(const float* __restrict__ C,
                                                float* __restrict__ csq) {
    const int wave = threadIdx.x >> 6, lane = threadIdx.x & 63;
    const int row = blockIdx.x * 4 + wave;
    const float* p = C + row * 512 + lane * 8;
    float4 a = *(const float4*)p;
    float4 b = *(const float4*)(p + 4);
    float s = a.x * a.x + a.y * a.y + a.z * a.z + a.w * a.w +
              b.x * b.x + b.y * b.y + b.z * b.z + b.w * b.w;
#pragma unroll
    for (int off = 1; off < 64; off <<= 1) s += __shfl_xor(s, off, 64);
    if (lane == 0) csq[row] = s;
}

__global__ __launch_bounds__(256) void logits_mfma(const float* __restrict__ X,
                                                   const float* __restrict__ Cm,
                                                   const float* __restrict__ csq,
                                                   float* __restrict__ L) {
    __shared__ ushort sAh[128][64];
    __shared__ ushort sAl[128][64];
    __shared__ ushort sBh[128][64];
    __shared__ ushort sBl[128][64];
    const int tid = threadIdx.x;
    const int m0 = blockIdx.x * 128;
    const int n0 = blockIdx.y * 128;
    const int wid = tid >> 6, lane = tid & 63;
    const int wm = wid >> 1, wn = wid & 1;
    const int lrow = lane & 15;
    const int lkb = lane >> 4;
    f32x4v acc[4][4] = {};
    for (int k0 = 0; k0 < 512; k0 += 64) {
        __syncthreads();
#pragma unroll
        for (int s = 0; s < 8; ++s) {
            const int idx = s * 256 + tid;
            const int r = idx >> 4;
            const int c4 = (idx & 15) << 2;
            const int e = c4 ^ ((r & 7) << 3);
            float4 va = *(const float4*)(X + (long)(m0 + r) * 512 + k0 + c4);
            ushort4 hh, ll;
            split2(va.x, hh.x, ll.x);
            split2(va.y, hh.y, ll.y);
            split2(va.z, hh.z, ll.z);
            split2(va.w, hh.w, ll.w);
            *(ushort4*)&sAh[r][e] = hh;
            *(ushort4*)&sAl[r][e] = ll;
            float4 vb = *(const float4*)(Cm + (long)(n0 + r) * 512 + k0 + c4);
            split2(vb.x, hh.x, ll.x);
            split2(vb.y, hh.y, ll.y);
            split2(vb.z, hh.z, ll.z);
            split2(vb.w, hh.w, ll.w);
            *(ushort4*)&sBh[r][e] = hh;
            *(ushort4*)&sBl[r][e] = ll;
        }
        __syncthreads();
#pragma unroll
        for (int kk = 0; kk < 2; ++kk) {
            const int ebase = kk * 32 + lkb * 8;
            bf16x8 ah[4], al[4], bh[4], bl[4];
#pragma unroll
            for (int mi = 0; mi < 4; ++mi) {
                const int R = wm * 64 + mi * 16 + lrow;
                const int e = ebase ^ ((R & 7) << 3);
                ah[mi] = *(const bf16x8*)&sAh[R][e];
                al[mi] = *(const bf16x8*)&sAl[R][e];
            }
#pragma unroll
            for (int ni = 0; ni < 4; ++ni) {
                const int Rn = wn * 64 + ni * 16 + lrow;
                const int e = ebase ^ ((Rn & 7) << 3);
                bh[ni] = *(const bf16x8*)&sBh[Rn][e];
                bl[ni] = *(const bf16x8*)&sBl[Rn][e];
            }
#pragma unroll
            for (int mi = 0; mi < 4; ++mi)
#pragma unroll
                for (int ni = 0; ni < 4; ++ni) {
                    acc[mi][ni] = __builtin_amdgcn_mfma_f32_16x16x32_bf16(ah[mi], bh[ni], acc[mi][ni], 0, 0, 0);
                    acc[mi][ni] = __builtin_amdgcn_mfma_f32_16x16x32_bf16(ah[mi], bl[ni], acc[mi][ni], 0, 0, 0);
                    acc[mi][ni] = __builtin_amdgcn_mfma_f32_16x16x32_bf16(al[mi], bh[ni], acc[mi][ni], 0, 0, 0);
                }
        }
    }
    const int colb = n0 + wn * 64 + lrow;
    float cs[4];
#pragma unroll
    for (int ni = 0; ni < 4; ++ni) cs[ni] = csq[colb + ni * 16];
#pragma unroll
    for (int mi = 0; mi < 4; ++mi) {
        const int rowb = m0 + wm * 64 + mi * 16 + lkb * 4;
#pragma unroll
        for (int r = 0; r < 4; ++r) {
            float* Lp = L + (long)(rowb + r) * 512 + colb;
#pragma unroll
            for (int ni = 0; ni < 4; ++ni)
                Lp[ni * 16] = 2.0f * acc[mi][ni][r] - cs[ni];
        }
    }
}

__global__ __launch_bounds__(256) void softmax_rows(float* __restrict__ L,
                                                    float* __restrict__ sum_w,
                                                    ushort* __restrict__ Abf) {
    __shared__ float swacc[512];
    const int tid = threadIdx.x;
    for (int i = tid; i < 512; i += 256) swacc[i] = 0.f;
    __syncthreads();
    const int wave = tid >> 6, lane = tid & 63;
    float racc[8] = {};
    for (int r = blockIdx.x * 4 + wave; r < 32768; r += 2048) {
        float* p = L + (long)r * 512 + lane * 8;
        float4 v0 = *(float4*)p;
        float4 v1 = *(float4*)(p + 4);
        float v[8] = {v0.x, v0.y, v0.z, v0.w, v1.x, v1.y, v1.z, v1.w};
        float m = v[0];
#pragma unroll
        for (int i = 1; i < 8; ++i) m = fmaxf(m, v[i]);
#pragma unroll
        for (int off = 1; off < 64; off <<= 1) m = fmaxf(m, __shfl_xor(m, off, 64));
        float e[8], s = 0.f;
#pragma unroll
        for (int i = 0; i < 8; ++i) {
            e[i] = expf((v[i] - m) * 10.0f);
            s += e[i];
        }
#pragma unroll
        for (int off = 1; off < 64; off <<= 1) s += __shfl_xor(s, off, 64);
        const float inv = 1.0f / (s + EPSF);
        ushort eb[8];
#pragma unroll
        for (int i = 0; i < 8; ++i) {
            e[i] *= inv;
            racc[i] += e[i];
            eb[i] = f2bf_bits(e[i]);
        }
        float4 o0 = {e[0], e[1], e[2], e[3]};
        float4 o1 = {e[4], e[5], e[6], e[7]};
        *(float4*)p = o0;
        *(float4*)(p + 4) = o1;
        if (Abf) *(uint4*)(Abf + (long)r * 512 + lane * 8) = pack8(eb);
    }
#pragma unroll
    for (int i = 0; i < 8; ++i) atomicAdd(&swacc[lane * 8 + i], racc[i]);
    __syncthreads();
    for (int i = tid; i < 512; i += 256) atomicAdd(&sum_w[i], swacc[i]);
}

__global__ __launch_bounds__(256) void gemm_wsum(const float* __restrict__ A,
                                                 const float* __restrict__ X,
                                                 float* __restrict__ WS) {
    __shared__ float As[16][64];
    __shared__ float Xs[16][64];
    const int tid = threadIdx.x;
    const int tx = tid & 15, ty = tid >> 4;
    const int lrow = tid >> 4;
    const int lcol = (tid & 15) << 2;
    const int k0 = blockIdx.x * 64;
    const int d0 = blockIdx.y * 64;
    const int n0 = blockIdx.z * 1024;
    float acc[4][4] = {};
    for (int nc = 0; nc < 1024; nc += 16) {
        const long nrow = n0 + nc + lrow;
        float4 av = *(const float4*)(A + nrow * 512 + k0 + lcol);
        float4 xv = *(const float4*)(X + nrow * 512 + d0 + lcol);
        __syncthreads();
        *(float4*)&As[lrow][lcol] = av;
        *(float4*)&Xs[lrow][lcol] = xv;
        __syncthreads();
#pragma unroll
        for (int nn = 0; nn < 16; ++nn) {
            float4 a = *(const float4*)&As[nn][ty << 2];
            float4 x = *(const float4*)&Xs[nn][tx << 2];
            float aa[4] = {a.x, a.y, a.z, a.w};
            float xx[4] = {x.x, x.y, x.z, x.w};
#pragma unroll
            for (int i = 0; i < 4; ++i)
#pragma unroll
                for (int j = 0; j < 4; ++j) acc[i][j] += aa[i] * xx[j];
        }
    }
#pragma unroll
    for (int i = 0; i < 4; ++i)
#pragma unroll
        for (int j = 0; j < 4; ++j)
            atomicAdd(&WS[(k0 + (ty << 2) + i) * 512 + d0 + (tx << 2) + j], acc[i][j]);
}

__global__ __launch_bounds__(256) void repulse_update(const float* __restrict__ Cent,
                                                      const float* __restrict__ Mom,
                                                      const float* __restrict__ csq,
                                                      const float* __restrict__ WS,
                                                      const float* __restrict__ sum_w,
                                                      float* __restrict__ outC,
                                                      float* __restrict__ outM) {
    const int i = blockIdx.x;
    __shared__ float ci[512];
    __shared__ float rep[512];
    const int tid = threadIdx.x, wave = tid >> 6, lane = tid & 63;
    for (int d = tid; d < 512; d += 256) {
        ci[d] = Cent[i * 512 + d];
        rep[d] = 0.f;
    }
    __syncthreads();
    float cil[8];
#pragma unroll
    for (int m = 0; m < 8; ++m) cil[m] = ci[lane * 8 + m];
    const float csqi = csq[i];
    float racc[8] = {};
    for (int j = wave; j < 512; j += 4) {
        if (j == i) continue;
        const float* cj = Cent + j * 512 + lane * 8;
        float4 c0 = *(const float4*)cj;
        float4 c1 = *(const float4*)(cj + 4);
        float cjl[8] = {c0.x, c0.y, c0.z, c0.w, c1.x, c1.y, c1.z, c1.w};
        float dot = 0.f;
#pragma unroll
        for (int m = 0; m < 8; ++m) dot += cil[m] * cjl[m];
#pragma unroll
        for (int off = 1; off < 64; off <<= 1) dot += __shfl_xor(dot, off, 64);
        float sq = csqi + csq[j] - 2.f * dot;
        float dist = sqrtf(fmaxf(sq, 0.f) + EPSF);
        float w = fmaxf(0.f, 1.f - dist);
        float scale = 0.1f * w / (dist + EPSF);
#pragma unroll
        for (int m = 0; m < 8; ++m) racc[m] += scale * (cil[m] - cjl[m]);
    }
#pragma unroll
    for (int m = 0; m < 8; ++m) atomicAdd(&rep[lane * 8 + m], racc[m]);
    __syncthreads();
    const float invw = 1.0f / (sum_w[i] + EPSF);
    for (int d = tid; d < 512; d += 256) {
        float nc = WS[i * 512 + d] * invw;
        float upd = nc - ci[d] + rep[d];
        float mn = 0.9f * Mom[i * 512 + d] + 0.1f * upd;
        outM[i * 512 + d] = mn;
        outC[i * 512 + d] = ci[d] + 0.1f * mn;
    }
}

extern "C" void kernel_launch(void* const* d_in, const int* in_sizes, int n_in,
                              void* d_out, int out_size, void* d_ws, size_t ws_size,
                              hipStream_t stream) {
    const float* X = (const float*)d_in[0];      // (32768, 512)
    const float* C = (const float*)d_in[1];      // (512, 512)
    const float* M = (const float*)d_in[2];      // (512, 512)
    float* out = (float*)d_out;
    float* assign = out;                          // 32768*512
    float* outC = out + 16777216;                 // 512*512
    float* outM = outC + 262144;                  // 512*512

    char* wsb = (char*)d_ws;
    const size_t MB = 1024ull * 1024ull;
    float* WS = (float*)wsb;                            // 1 MB
    float* sum_w = (float*)(wsb + 1 * MB);              // 2 KB
    float* rsum = (float*)(wsb + 1 * MB + 2048);        // 2 KB
    float* csq = (float*)(wsb + 1 * MB + 4096);         // 2 KB
    ushort* Chl = (ushort*)(wsb + 2 * MB);              // 1 MB (512 x 1024 bf16)
    float* S = (float*)(wsb + 3 * MB);                  // 1 MB
    float* WSp = (float*)(wsb + 4 * MB);                // 32 MB (z=32)
    ushort* Xhl = (ushort*)(wsb + 36 * MB);             // 64 MB
    ushort* Abf = (ushort*)(wsb + 100 * MB);            // 32 MB
    const size_t NEED = 132 * MB;                       // proven available

    hipMemsetAsync(d_ws, 0, 1 * MB + 8192, stream);     // WS + sum_w + rsum hdr

    if (ws_size >= NEED) {
        csqc_v3<<<128, 256, 0, stream>>>(C, csq, Chl);
        gram_s_v3<<<dim3(4, 4), 256, 0, stream>>>(Chl, csq, S, rsum);
        convert_xhl<<<8192, 256, 0, stream>>>(X, Xhl);
        logsm<<<512, 512, 0, stream>>>(Xhl, Chl, csq, assign, Abf, sum_w);
        wsum_v3<<<dim3(4, 4, 32), 256, 0, stream>>>(Abf, Xhl, WSp);
        reduce_ws32<<<256, 256, 0, stream>>>(WSp, WS);
        apply_update<<<512, 256, 0, stream>>>(C, M, S, rsum, WS, sum_w, outC, outM);
    } else {
        csq_only<<<128, 256, 0, stream>>>(C, csq);
        logits_mfma<<<dim3(256, 4), 256, 0, stream>>>(X, C, csq, assign);
        softmax_rows<<<512, 256, 0, stream>>>(assign, sum_w, nullptr);
        gemm_wsum<<<dim3(8, 8, 32), 256, 0, stream>>>(assign, X, WS);
        repulse_update<<<512, 256, 0, stream>>>(C, M, csq, WS, sum_w, outC, outM);
    }
}

// Round 11
// 146.595 us; speedup vs baseline: 4.2932x; 1.1739x over previous
//
#include <hip/hip_runtime.h>
#include <hip/hip_bf16.h>

#define EPSF 1e-7f

typedef __attribute__((ext_vector_type(8))) short bf16x8;
typedef __attribute__((ext_vector_type(4))) float f32x4v;

__device__ inline ushort f2bf_bits(float x) {
    union { __hip_bfloat16 b; ushort u; } cv;
    cv.b = __float2bfloat16(x);
    return cv.u;
}
__device__ inline float bfbits2f(ushort u) {
    union { ushort u; __hip_bfloat16 b; } cv;
    cv.u = u;
    return __bfloat162float(cv.b);
}
__device__ inline void split2(float x, ushort& h, ushort& l) {
    h = f2bf_bits(x);
    l = f2bf_bits(x - bfbits2f(h));
}
__device__ inline uint4 pack8(const ushort* h) {
    uint4 p;
    p.x = (uint)h[0] | ((uint)h[1] << 16);
    p.y = (uint)h[2] | ((uint)h[3] << 16);
    p.z = (uint)h[4] | ((uint)h[5] << 16);
    p.w = (uint)h[6] | ((uint)h[7] << 16);
    return p;
}

__device__ inline void gload_lds16(const ushort* g, ushort* l) {
    __builtin_amdgcn_global_load_lds(
        (const __attribute__((address_space(1))) unsigned int*)g,
        (__attribute__((address_space(3))) unsigned int*)l, 16, 0, 0);
}

// ---------------- csq + C -> Chl (interleaved hi/lo per 32-k chunk) ----------------
__global__ __launch_bounds__(256) void csqc_v3(const float* __restrict__ C,
                                               float* __restrict__ csq,
                                               ushort* __restrict__ Chl) {
    const int wave = threadIdx.x >> 6, lane = threadIdx.x & 63;
    const int row = blockIdx.x * 4 + wave;
    const int kc = lane >> 2, s = lane & 3;
    const float* p = C + row * 512 + lane * 8;
    float4 a = *(const float4*)p;
    float4 b = *(const float4*)(p + 4);
    float v[8] = {a.x, a.y, a.z, a.w, b.x, b.y, b.z, b.w};
    ushort h[8], l[8];
    float sqs = 0.f;
#pragma unroll
    for (int i = 0; i < 8; ++i) {
        sqs += v[i] * v[i];
        split2(v[i], h[i], l[i]);
    }
    ushort* base = Chl + (long)row * 1024 + kc * 64 + s * 8;
    *(uint4*)base = pack8(h);
    *(uint4*)(base + 32) = pack8(l);
#pragma unroll
    for (int off = 1; off < 64; off <<= 1) sqs += __shfl_xor(sqs, off, 64);
    if (lane == 0) csq[row] = sqs;
}

// ---------------- logsm v3: fused X-convert + logits GEMM + row softmax ----------------
// BM=64 rows, BN=512 (full row). 512 thr = 8 waves (2m x 4n); per-wave 32x128.
// A staged by in-reg fp32->hi/lo split (writes Xh byproduct for wsum);
// B (all of Chl) staged 64 KB/kc via global_load_lds. Epilogue: softmax+outputs.
__global__ __launch_bounds__(512) void logsm(const float* __restrict__ X,
                                             const ushort* __restrict__ Chl,
                                             const float* __restrict__ csq,
                                             float* __restrict__ assign,
                                             ushort* __restrict__ Abf,
                                             ushort* __restrict__ Xh,
                                             float* __restrict__ sum_w) {
    __shared__ __align__(16) ushort sA[64 * 64];      // 8 KB (hi|lo per kc)
    __shared__ __align__(16) ushort sB[512 * 64];     // 64 KB
    __shared__ float rmaxs[64][4];
    __shared__ float rsums[64][4];
    __shared__ float swacc[512];
    const int tid = threadIdx.x;
    // XCD-aware bijective swizzle over 512 m-tiles (512 % 8 == 0)
    const int m0 = ((blockIdx.x & 7) * 64 + (blockIdx.x >> 3)) * 64;
    const int wid = tid >> 6, lane = tid & 63;
    const int wm = wid >> 2, wn = wid & 3;
    const int lrow = lane & 15, lkb = lane >> 4;
    swacc[tid] = 0.f;
    f32x4v acc[2][8] = {};

    const int ar = tid >> 3, aq = tid & 7;   // A-stage task: row 0..63, quad 0..7

#pragma unroll 1
    for (int kc = 0; kc < 16; ++kc) {
        __syncthreads();
        {   // A: load fp32 quad, split to hi/lo, ds_write swizzled; write Xh byproduct
            float4 v = *(const float4*)(X + (long)(m0 + ar) * 512 + kc * 32 + aq * 4);
            ushort h[4], l[4];
            split2(v.x, h[0], l[0]);
            split2(v.y, h[1], l[1]);
            split2(v.z, h[2], l[2]);
            split2(v.w, h[3], l[3]);
            ushort4 hv = {h[0], h[1], h[2], h[3]};
            ushort4 lv = {l[0], l[1], l[2], l[3]};
            const int sh = (aq >> 1) ^ (ar & 7);        // physical slot of hi
            const int slo = ((aq >> 1) + 4) ^ (ar & 7); // physical slot of lo
            *(ushort4*)&sA[ar * 64 + (sh << 3) + (aq & 1) * 4] = hv;
            *(ushort4*)&sA[ar * 64 + (slo << 3) + (aq & 1) * 4] = lv;
            *(ushort4*)(Xh + (long)(m0 + ar) * 512 + kc * 32 + aq * 4) = hv;
        }
#pragma unroll
        for (int i = 0; i < 8; ++i) {   // B: 512 rows = 4096 slots, 8/thread
            const int sl = i * 512 + tid;
            const int r = sl >> 3, j = sl & 7;
            const int s = j ^ (r & 7);
            gload_lds16(Chl + (long)r * 1024 + kc * 64 + s * 8,
                        &sB[(i * 512 + wid * 64) * 8]);
        }
        __syncthreads();
        bf16x8 ah[2], al[2];
#pragma unroll
        for (int mi = 0; mi < 2; ++mi) {
            const int R = wm * 32 + mi * 16 + lrow;
            ah[mi] = *(const bf16x8*)&sA[R * 64 + ((lkb ^ (R & 7)) << 3)];
            al[mi] = *(const bf16x8*)&sA[R * 64 + (((lkb + 4) ^ (R & 7)) << 3)];
        }
#pragma unroll
        for (int ni = 0; ni < 8; ++ni) {
            const int Rn = wn * 128 + ni * 16 + lrow;
            bf16x8 bh = *(const bf16x8*)&sB[Rn * 64 + ((lkb ^ (Rn & 7)) << 3)];
            bf16x8 bl = *(const bf16x8*)&sB[Rn * 64 + (((lkb + 4) ^ (Rn & 7)) << 3)];
#pragma unroll
            for (int mi = 0; mi < 2; ++mi) {
                acc[mi][ni] = __builtin_amdgcn_mfma_f32_16x16x32_bf16(ah[mi], bh, acc[mi][ni], 0, 0, 0);
                acc[mi][ni] = __builtin_amdgcn_mfma_f32_16x16x32_bf16(ah[mi], bl, acc[mi][ni], 0, 0, 0);
                acc[mi][ni] = __builtin_amdgcn_mfma_f32_16x16x32_bf16(al[mi], bh, acc[mi][ni], 0, 0, 0);
            }
        }
    }
    // ---- epilogue: logits -> softmax -> outputs ----
    const int colb = wn * 128 + lrow;
    float cs[8];
#pragma unroll
    for (int ni = 0; ni < 8; ++ni) cs[ni] = csq[colb + ni * 16];
    float mx[2][4];
#pragma unroll
    for (int mi = 0; mi < 2; ++mi)
#pragma unroll
        for (int r = 0; r < 4; ++r) {
            float m = -3.0e38f;
#pragma unroll
            for (int ni = 0; ni < 8; ++ni) {
                float l = 2.0f * acc[mi][ni][r] - cs[ni];
                acc[mi][ni][r] = l;
                m = fmaxf(m, l);
            }
            mx[mi][r] = m;
        }
#pragma unroll
    for (int off = 1; off < 16; off <<= 1)
#pragma unroll
        for (int mi = 0; mi < 2; ++mi)
#pragma unroll
            for (int r = 0; r < 4; ++r) mx[mi][r] = fmaxf(mx[mi][r], __shfl_xor(mx[mi][r], off, 64));
    if (lrow == 0) {
#pragma unroll
        for (int mi = 0; mi < 2; ++mi)
#pragma unroll
            for (int r = 0; r < 4; ++r) rmaxs[wm * 32 + mi * 16 + lkb * 4 + r][wn] = mx[mi][r];
    }
    __syncthreads();
    float gmax[2][4];
#pragma unroll
    for (int mi = 0; mi < 2; ++mi)
#pragma unroll
        for (int r = 0; r < 4; ++r) {
            const int row = wm * 32 + mi * 16 + lkb * 4 + r;
            gmax[mi][r] = fmaxf(fmaxf(rmaxs[row][0], rmaxs[row][1]),
                                fmaxf(rmaxs[row][2], rmaxs[row][3]));
        }
    float sm[2][4] = {};
#pragma unroll
    for (int mi = 0; mi < 2; ++mi)
#pragma unroll
        for (int ni = 0; ni < 8; ++ni)
#pragma unroll
            for (int r = 0; r < 4; ++r) {
                float e = expf((acc[mi][ni][r] - gmax[mi][r]) * 10.0f);
                acc[mi][ni][r] = e;
                sm[mi][r] += e;
            }
#pragma unroll
    for (int off = 1; off < 16; off <<= 1)
#pragma unroll
        for (int mi = 0; mi < 2; ++mi)
#pragma unroll
            for (int r = 0; r < 4; ++r) sm[mi][r] += __shfl_xor(sm[mi][r], off, 64);
    if (lrow == 0) {
#pragma unroll
        for (int mi = 0; mi < 2; ++mi)
#pragma unroll
            for (int r = 0; r < 4; ++r) rsums[wm * 32 + mi * 16 + lkb * 4 + r][wn] = sm[mi][r];
    }
    __syncthreads();
    float inv[2][4];
#pragma unroll
    for (int mi = 0; mi < 2; ++mi)
#pragma unroll
        for (int r = 0; r < 4; ++r) {
            const int row = wm * 32 + mi * 16 + lkb * 4 + r;
            float t = rsums[row][0] + rsums[row][1] + rsums[row][2] + rsums[row][3];
            inv[mi][r] = 1.0f / (t + EPSF);
        }
    float csum[8] = {};
#pragma unroll
    for (int mi = 0; mi < 2; ++mi)
#pragma unroll
        for (int ni = 0; ni < 8; ++ni) {
            const int col = colb + ni * 16;
#pragma unroll
            for (int r = 0; r < 4; ++r) {
                const int row = wm * 32 + mi * 16 + lkb * 4 + r;
                float a = acc[mi][ni][r] * inv[mi][r];
                assign[(long)(m0 + row) * 512 + col] = a;
                Abf[(long)(m0 + row) * 512 + col] = f2bf_bits(a);
                csum[ni] += a;
            }
        }
#pragma unroll
    for (int off = 16; off < 64; off <<= 1)
#pragma unroll
        for (int ni = 0; ni < 8; ++ni) csum[ni] += __shfl_xor(csum[ni], off, 64);
    if (lkb == 0) {
#pragma unroll
        for (int ni = 0; ni < 8; ++ni) atomicAdd(&swacc[colb + ni * 16], csum[ni]);
    }
    __syncthreads();
    atomicAdd(&sum_w[tid], swacc[tid]);
}

// ---------------- gram -> S + rowsum, on Chl ----------------
__global__ __launch_bounds__(256) void gram_s_v3(const ushort* __restrict__ Chl,
                                                 const float* __restrict__ csq,
                                                 float* __restrict__ S,
                                                 float* __restrict__ rsum) {
    __shared__ __align__(16) ushort sA[128 * 64];
    __shared__ __align__(16) ushort sB[128 * 64];
    __shared__ float rs_s[128];
    const int tid = threadIdx.x;
    const int n0 = blockIdx.x * 128;
    const int m0 = blockIdx.y * 128;
    const int wid = tid >> 6, lane = tid & 63;
    const int wm = wid >> 1, wn = wid & 1;
    const int lrow = lane & 15, lkb = lane >> 4;
    f32x4v acc[4][4] = {};

#pragma unroll 1
    for (int kc = 0; kc < 16; ++kc) {
        __syncthreads();
#pragma unroll
        for (int i = 0; i < 4; ++i) {
            const int sl = wid * 256 + i * 64 + lane;
            const int r = sl >> 3, j = sl & 7;
            const int s = j ^ (r & 7);
            gload_lds16(Chl + (long)(m0 + r) * 1024 + kc * 64 + s * 8,
                        &sA[(wid * 256 + i * 64) * 8]);
            gload_lds16(Chl + (long)(n0 + r) * 1024 + kc * 64 + s * 8,
                        &sB[(wid * 256 + i * 64) * 8]);
        }
        __syncthreads();
        bf16x8 ah[4], al[4], bh[4], bl[4];
#pragma unroll
        for (int mi = 0; mi < 4; ++mi) {
            const int R = wm * 64 + mi * 16 + lrow;
            ah[mi] = *(const bf16x8*)&sA[R * 64 + ((lkb ^ (R & 7)) << 3)];
            al[mi] = *(const bf16x8*)&sA[R * 64 + (((lkb + 4) ^ (R & 7)) << 3)];
        }
#pragma unroll
        for (int ni = 0; ni < 4; ++ni) {
            const int R = wn * 64 + ni * 16 + lrow;
            bh[ni] = *(const bf16x8*)&sB[R * 64 + ((lkb ^ (R & 7)) << 3)];
            bl[ni] = *(const bf16x8*)&sB[R * 64 + (((lkb + 4) ^ (R & 7)) << 3)];
        }
#pragma unroll
        for (int mi = 0; mi < 4; ++mi)
#pragma unroll
            for (int ni = 0; ni < 4; ++ni) {
                acc[mi][ni] = __builtin_amdgcn_mfma_f32_16x16x32_bf16(ah[mi], bh[ni], acc[mi][ni], 0, 0, 0);
                acc[mi][ni] = __builtin_amdgcn_mfma_f32_16x16x32_bf16(ah[mi], bl[ni], acc[mi][ni], 0, 0, 0);
                acc[mi][ni] = __builtin_amdgcn_mfma_f32_16x16x32_bf16(al[mi], bh[ni], acc[mi][ni], 0, 0, 0);
            }
    }
    if (tid < 128) rs_s[tid] = 0.f;
    __syncthreads();
    const int colb = n0 + wn * 64 + lrow;
    float csj[4];
#pragma unroll
    for (int ni = 0; ni < 4; ++ni) csj[ni] = csq[colb + ni * 16];
#pragma unroll
    for (int mi = 0; mi < 4; ++mi) {
        const int rowb = m0 + wm * 64 + mi * 16 + lkb * 4;
#pragma unroll
        for (int r = 0; r < 4; ++r) {
            const int row = rowb + r;
            const float csi = csq[row];
            float rowpart = 0.f;
#pragma unroll
            for (int ni = 0; ni < 4; ++ni) {
                const int col = colb + ni * 16;
                float sq = csi + csj[ni] - 2.0f * acc[mi][ni][r];
                float dist = sqrtf(fmaxf(sq, 0.f) + EPSF);
                float w = fmaxf(0.f, 1.f - dist);
                float sval = (row == col) ? 0.f : (0.1f * w / (dist + EPSF));
                S[(long)row * 512 + col] = sval;
                rowpart += sval;
            }
            atomicAdd(&rs_s[row - m0], rowpart);
        }
    }
    __syncthreads();
    if (tid < 128) atomicAdd(&rsum[m0 + tid], rs_s[tid]);
}

// ---------------- wsum v3: bf16 sources (Abf, Xh), in-LDS transpose, XCD-swizzled ----------------
__global__ __launch_bounds__(256) void wsum_v3(const ushort* __restrict__ Abf,
                                               const ushort* __restrict__ Xh,
                                               float* __restrict__ WSp) {
    __shared__ __align__(16) ushort sA[128 * 64];   // [k][n] bf16, swizzled n-octs
    __shared__ __align__(16) ushort sB[128 * 64];   // [d][n]
    const int tid = threadIdx.x;
    // nwg=512: bijective swizzle, one z-chunk's 16 blocks -> same XCD
    const int lin = blockIdx.x + blockIdx.y * 4 + blockIdx.z * 16;
    const int T = (lin & 7) * 64 + (lin >> 3);
    const int k0 = (T & 3) * 128;
    const int d0 = ((T >> 2) & 3) * 128;
    const int zc = T >> 4;                 // 0..31
    const long n0 = (long)zc * 1024;
    const int wid = tid >> 6, lane = tid & 63;
    const int wm = wid >> 1, wn = wid & 1;
    const int lrow = lane & 15, lkb = lane >> 4;
    f32x4v acc[4][4] = {};

    for (int nc = 0; nc < 1024; nc += 64) {
        __syncthreads();
#pragma unroll
        for (int it = 0; it < 4; ++it) {
            const int idx = it * 256 + tid;
            const int c = idx & 127;
            const int no = idx >> 7;
            const long nb = n0 + nc + (long)no * 8;
            const int dd = d0 + c;
            ushort ha[8], hx[8];
#pragma unroll
            for (int jj = 0; jj < 8; ++jj) {
                ha[jj] = Abf[(nb + jj) * 512 + k0 + c];
                hx[jj] = Xh[(nb + jj) * 512 + dd];
            }
            const int sl = no ^ (c & 7);
            *(uint4*)&sA[c * 64 + sl * 8] = pack8(ha);
            *(uint4*)&sB[c * 64 + sl * 8] = pack8(hx);
        }
        __syncthreads();
#pragma unroll
        for (int kk = 0; kk < 2; ++kk) {
            const int j = kk * 4 + lkb;
            bf16x8 af[4], bfv[4];
#pragma unroll
            for (int mi = 0; mi < 4; ++mi) {
                const int R = wm * 64 + mi * 16 + lrow;
                af[mi] = *(const bf16x8*)&sA[R * 64 + ((j ^ (R & 7)) << 3)];
            }
#pragma unroll
            for (int ni = 0; ni < 4; ++ni) {
                const int R = wn * 64 + ni * 16 + lrow;
                bfv[ni] = *(const bf16x8*)&sB[R * 64 + ((j ^ (R & 7)) << 3)];
            }
#pragma unroll
            for (int mi = 0; mi < 4; ++mi)
#pragma unroll
                for (int ni = 0; ni < 4; ++ni)
                    acc[mi][ni] = __builtin_amdgcn_mfma_f32_16x16x32_bf16(af[mi], bfv[ni], acc[mi][ni], 0, 0, 0);
        }
    }
    float* dst = WSp + (size_t)zc * 262144;
#pragma unroll
    for (int mi = 0; mi < 4; ++mi) {
        const int k = k0 + wm * 64 + mi * 16 + lkb * 4;
#pragma unroll
        for (int ni = 0; ni < 4; ++ni) {
            const int d = d0 + wn * 64 + ni * 16 + lrow;
#pragma unroll
            for (int r = 0; r < 4; ++r)
                dst[(k + r) * 512 + d] = acc[mi][ni][r];
        }
    }
}

// ---------------- fused WSp-reduce + repulsion-apply + momentum update ----------------
__global__ __launch_bounds__(256) void apply_update(const float* __restrict__ Cent,
                                                    const float* __restrict__ Mom,
                                                    const float* __restrict__ S,
                                                    const float* __restrict__ rsum,
                                                    const float* __restrict__ WSp,
                                                    const float* __restrict__ sum_w,
                                                    float* __restrict__ outC,
                                                    float* __restrict__ outM) {
    const int i = blockIdx.x;
    __shared__ float srow[512];
    __shared__ int nz;
    const int tid = threadIdx.x;
    if (tid == 0) nz = 0;
    __syncthreads();
    float2 sv = *(const float2*)(S + (long)i * 512 + tid * 2);
    srow[tid * 2] = sv.x;
    srow[tid * 2 + 1] = sv.y;
    if (sv.x != 0.f || sv.y != 0.f) nz = 1;
    __syncthreads();
    const float rs = rsum[i];
    const float invw = 1.0f / (sum_w[i] + EPSF);
    const int d0 = tid * 2;
    // reduce WSp over 32 z-chunks (replaces reduce_ws kernel)
    float ws0 = 0.f, ws1 = 0.f;
#pragma unroll 4
    for (int z = 0; z < 32; ++z) {
        float2 w = *(const float2*)(WSp + (size_t)z * 262144 + (long)i * 512 + d0);
        ws0 += w.x;
        ws1 += w.y;
    }
    float sc0 = 0.f, sc1 = 0.f;
    if (nz) {
        for (int j = 0; j < 512; ++j) {
            const float s = srow[j];
            if (s != 0.f) {
                sc0 += s * Cent[(long)j * 512 + d0];
                sc1 += s * Cent[(long)j * 512 + d0 + 1];
            }
        }
    }
    float2 ci = *(const float2*)(Cent + (long)i * 512 + d0);
    float2 mo = *(const float2*)(Mom + (long)i * 512 + d0);
    float rep0 = rs * ci.x - sc0;
    float rep1 = rs * ci.y - sc1;
    float mn0 = 0.9f * mo.x + 0.1f * (ws0 * invw - ci.x + rep0);
    float mn1 = 0.9f * mo.y + 0.1f * (ws1 * invw - ci.y + rep1);
    float2 om = {mn0, mn1};
    float2 oc = {ci.x + 0.1f * mn0, ci.y + 0.1f * mn1};
    *(float2*)(outM + (long)i * 512 + d0) = om;
    *(float2*)(outC + (long)i * 512 + d0) = oc;
}

// ================= legacy fp32 fallback kernels (small-ws path) =================
__global__ __launch_bounds__(256) void csq_only(const float* __restrict__ C,
                                                float* __restrict__ csq) {
    const int wave = threadIdx.x >> 6, lane = threadIdx.x & 63;
    const int row = blockIdx.x * 4 + wave;
    const float* p = C + row * 512 + lane * 8;
    float4 a = *(const float4*)p;
    float4 b = *(const float4*)(p + 4);
    float s = a.x * a.x + a.y * a.y + a.z * a.z + a.w * a.w +
              b.x * b.x + b.y * b.y + b.z * b.z + b.w * b.w;
#pragma unroll
    for (int off = 1; off < 64; off <<= 1) s += __shfl_xor(s, off, 64);
    if (lane == 0) csq[row] = s;
}

__global__ __launch_bounds__(256) void logits_mfma(const float* __restrict__ X,
                                                   const float* __restrict__ Cm,
                                                   const float* __restrict__ csq,
                                                   float* __restrict__ L) {
    __shared__ ushort sAh[128][64];
    __shared__ ushort sAl[128][64];
    __shared__ ushort sBh[128][64];
    __shared__ ushort sBl[128][64];
    const int tid = threadIdx.x;
    const int m0 = blockIdx.x * 128;
    const int n0 = blockIdx.y * 128;
    const int wid = tid >> 6, lane = tid & 63;
    const int wm = wid >> 1, wn = wid & 1;
    const int lrow = lane & 15;
    const int lkb = lane >> 4;
    f32x4v acc[4][4] = {};
    for (int k0 = 0; k0 < 512; k0 += 64) {
        __syncthreads();
#pragma unroll
        for (int s = 0; s < 8; ++s) {
            const int idx = s * 256 + tid;
            const int r = idx >> 4;
            const int c4 = (idx & 15) << 2;
            const int e = c4 ^ ((r & 7) << 3);
            float4 va = *(const float4*)(X + (long)(m0 + r) * 512 + k0 + c4);
            ushort4 hh, ll;
            split2(va.x, hh.x, ll.x);
            split2(va.y, hh.y, ll.y);
            split2(va.z, hh.z, ll.z);
            split2(va.w, hh.w, ll.w);
            *(ushort4*)&sAh[r][e] = hh;
            *(ushort4*)&sAl[r][e] = ll;
            float4 vb = *(const float4*)(Cm + (long)(n0 + r) * 512 + k0 + c4);
            split2(vb.x, hh.x, ll.x);
            split2(vb.y, hh.y, ll.y);
            split2(vb.z, hh.z, ll.z);
            split2(vb.w, hh.w, ll.w);
            *(ushort4*)&sBh[r][e] = hh;
            *(ushort4*)&sBl[r][e] = ll;
        }
        __syncthreads();
#pragma unroll
        for (int kk = 0; kk < 2; ++kk) {
            const int ebase = kk * 32 + lkb * 8;
            bf16x8 ah[4], al[4], bh[4], bl[4];
#pragma unroll
            for (int mi = 0; mi < 4; ++mi) {
                const int R = wm * 64 + mi * 16 + lrow;
                const int e = ebase ^ ((R & 7) << 3);
                ah[mi] = *(const bf16x8*)&sAh[R][e];
                al[mi] = *(const bf16x8*)&sAl[R][e];
            }
#pragma unroll
            for (int ni = 0; ni < 4; ++ni) {
                const int Rn = wn * 64 + ni * 16 + lrow;
                const int e = ebase ^ ((Rn & 7) << 3);
                bh[ni] = *(const bf16x8*)&sBh[Rn][e];
                bl[ni] = *(const bf16x8*)&sBl[Rn][e];
            }
#pragma unroll
            for (int mi = 0; mi < 4; ++mi)
#pragma unroll
                for (int ni = 0; ni < 4; ++ni) {
                    acc[mi][ni] = __builtin_amdgcn_mfma_f32_16x16x32_bf16(ah[mi], bh[ni], acc[mi][ni], 0, 0, 0);
                    acc[mi][ni] = __builtin_amdgcn_mfma_f32_16x16x32_bf16(ah[mi], bl[ni], acc[mi][ni], 0, 0, 0);
                    acc[mi][ni] = __builtin_amdgcn_mfma_f32_16x16x32_bf16(al[mi], bh[ni], acc[mi][ni], 0, 0, 0);
                }
        }
    }
    const int colb = n0 + wn * 64 + lrow;
    float cs[4];
#pragma unroll
    for (int ni = 0; ni < 4; ++ni) cs[ni] = csq[colb + ni * 16];
#pragma unroll
    for (int mi = 0; mi < 4; ++mi) {
        const int rowb = m0 + wm * 64 + mi * 16 + lkb * 4;
#pragma unroll
        for (int r = 0; r < 4; ++r) {
            float* Lp = L + (long)(rowb + r) * 512 + colb;
#pragma unroll
            for (int ni = 0; ni < 4; ++ni)
                Lp[ni * 16] = 2.0f * acc[mi][ni][r] - cs[ni];
        }
    }
}

__global__ __launch_bounds__(256) void softmax_rows(float* __restrict__ L,
                                                    float* __restrict__ sum_w,
                                                    ushort* __restrict__ Abf) {
    __shared__ float swacc[512];
    const int tid = threadIdx.x;
    for (int i = tid; i < 512; i += 256) swacc[i] = 0.f;
    __syncthreads();
    const int wave = tid >> 6, lane = tid & 63;
    float racc[8] = {};
    for (int r = blockIdx.x * 4 + wave; r < 32768; r += 2048) {
        float* p = L + (long)r * 512 + lane * 8;
        float4 v0 = *(float4*)p;
        float4 v1 = *(float4*)(p + 4);
        float v[8] = {v0.x, v0.y, v0.z, v0.w, v1.x, v1.y, v1.z, v1.w};
        float m = v[0];
#pragma unroll
        for (int i = 1; i < 8; ++i) m = fmaxf(m, v[i]);
#pragma unroll
        for (int off = 1; off < 64; off <<= 1) m = fmaxf(m, __shfl_xor(m, off, 64));
        float e[8], s = 0.f;
#pragma unroll
        for (int i = 0; i < 8; ++i) {
            e[i] = expf((v[i] - m) * 10.0f);
            s += e[i];
        }
#pragma unroll
        for (int off = 1; off < 64; off <<= 1) s += __shfl_xor(s, off, 64);
        const float inv = 1.0f / (s + EPSF);
        ushort eb[8];
#pragma unroll
        for (int i = 0; i < 8; ++i) {
            e[i] *= inv;
            racc[i] += e[i];
            eb[i] = f2bf_bits(e[i]);
        }
        float4 o0 = {e[0], e[1], e[2], e[3]};
        float4 o1 = {e[4], e[5], e[6], e[7]};
        *(float4*)p = o0;
        *(float4*)(p + 4) = o1;
        if (Abf) *(uint4*)(Abf + (long)r * 512 + lane * 8) = pack8(eb);
    }
#pragma unroll
    for (int i = 0; i < 8; ++i) atomicAdd(&swacc[lane * 8 + i], racc[i]);
    __syncthreads();
    for (int i = tid; i < 512; i += 256) atomicAdd(&sum_w[i], swacc[i]);
}

__global__ __launch_bounds__(256) void gemm_wsum(const float* __restrict__ A,
                                                 const float* __restrict__ X,
                                                 float* __restrict__ WS) {
    __shared__ float As[16][64];
    __shared__ float Xs[16][64];
    const int tid = threadIdx.x;
    const int tx = tid & 15, ty = tid >> 4;
    const int lrow = tid >> 4;
    const int lcol = (tid & 15) << 2;
    const int k0 = blockIdx.x * 64;
    const int d0 = blockIdx.y * 64;
    const int n0 = blockIdx.z * 1024;
    float acc[4][4] = {};
    for (int nc = 0; nc < 1024; nc += 16) {
        const long nrow = n0 + nc + lrow;
        float4 av = *(const float4*)(A + nrow * 512 + k0 + lcol);
        float4 xv = *(const float4*)(X + nrow * 512 + d0 + lcol);
        __syncthreads();
        *(float4*)&As[lrow][lcol] = av;
        *(float4*)&Xs[lrow][lcol] = xv;
        __syncthreads();
#pragma unroll
        for (int nn = 0; nn < 16; ++nn) {
            float4 a = *(const float4*)&As[nn][ty << 2];
            float4 x = *(const float4*)&Xs[nn][tx << 2];
            float aa[4] = {a.x, a.y, a.z, a.w};
            float xx[4] = {x.x, x.y, x.z, x.w};
#pragma unroll
            for (int i = 0; i < 4; ++i)
#pragma unroll
                for (int j = 0; j < 4; ++j) acc[i][j] += aa[i] * xx[j];
        }
    }
#pragma unroll
    for (int i = 0; i < 4; ++i)
#pragma unroll
        for (int j = 0; j < 4; ++j)
            atomicAdd(&WS[(k0 + (ty << 2) + i) * 512 + d0 + (tx << 2) + j], acc[i][j]);
}

__global__ __launch_bounds__(256) void repulse_update(const float* __restrict__ Cent,
                                                      const float* __restrict__ Mom,
                                                      const float* __restrict__ csq,
                                                      const float* __restrict__ WS,
                                                      const float* __restrict__ sum_w,
                                                      float* __restrict__ outC,
                                                      float* __restrict__ outM) {
    const int i = blockIdx.x;
    __shared__ float ci[512];
    __shared__ float rep[512];
    const int tid = threadIdx.x, wave = tid >> 6, lane = tid & 63;
    for (int d = tid; d < 512; d += 256) {
        ci[d] = Cent[i * 512 + d];
        rep[d] = 0.f;
    }
    __syncthreads();
    float cil[8];
#pragma unroll
    for (int m = 0; m < 8; ++m) cil[m] = ci[lane * 8 + m];
    const float csqi = csq[i];
    float racc[8] = {};
    for (int j = wave; j < 512; j += 4) {
        if (j == i) continue;
        const float* cj = Cent + j * 512 + lane * 8;
        float4 c0 = *(const float4*)cj;
        float4 c1 = *(const float4*)(cj + 4);
        float cjl[8] = {c0.x, c0.y, c0.z, c0.w, c1.x, c1.y, c1.z, c1.w};
        float dot = 0.f;
#pragma unroll
        for (int m = 0; m < 8; ++m) dot += cil[m] * cjl[m];
#pragma unroll
        for (int off = 1; off < 64; off <<= 1) dot += __shfl_xor(dot, off, 64);
        float sq = csqi + csq[j] - 2.f * dot;
        float dist = sqrtf(fmaxf(sq, 0.f) + EPSF);
        float w = fmaxf(0.f, 1.f - dist);
        float scale = 0.1f * w / (dist + EPSF);
#pragma unroll
        for (int m = 0; m < 8; ++m) racc[m] += scale * (cil[m] - cjl[m]);
    }
#pragma unroll
    for (int m = 0; m < 8; ++m) atomicAdd(&rep[lane * 8 + m], racc[m]);
    __syncthreads();
    const float invw = 1.0f / (sum_w[i] + EPSF);
    for (int d = tid; d < 512; d += 256) {
        float nc = WS[i * 512 + d] * invw;
        float upd = nc - ci[d] + rep[d];
        float mn = 0.9f * Mom[i * 512 + d] + 0.1f * upd;
        outM[i * 512 + d] = mn;
        outC[i * 512 + d] = ci[d] + 0.1f * mn;
    }
}

extern "C" void kernel_launch(void* const* d_in, const int* in_sizes, int n_in,
                              void* d_out, int out_size, void* d_ws, size_t ws_size,
                              hipStream_t stream) {
    const float* X = (const float*)d_in[0];      // (32768, 512)
    const float* C = (const float*)d_in[1];      // (512, 512)
    const float* M = (const float*)d_in[2];      // (512, 512)
    float* out = (float*)d_out;
    float* assign = out;                          // 32768*512
    float* outC = out + 16777216;                 // 512*512
    float* outM = outC + 262144;                  // 512*512

    char* wsb = (char*)d_ws;
    const size_t MB = 1024ull * 1024ull;
    float* WS = (float*)wsb;                            // 1 MB (fallback only)
    float* sum_w = (float*)(wsb + 1 * MB);              // 2 KB
    float* rsum = (float*)(wsb + 1 * MB + 2048);        // 2 KB
    float* csq = (float*)(wsb + 1 * MB + 4096);         // 2 KB
    ushort* Chl = (ushort*)(wsb + 2 * MB);              // 1 MB (512 x 1024 bf16)
    float* S = (float*)(wsb + 3 * MB);                  // 1 MB
    float* WSp = (float*)(wsb + 4 * MB);                // 32 MB (z=32)
    ushort* Xh = (ushort*)(wsb + 36 * MB);              // 32 MB (bf16 hi of X)
    ushort* Abf = (ushort*)(wsb + 100 * MB);            // 32 MB
    const size_t NEED = 132 * MB;                       // proven available

    if (ws_size >= NEED) {
        hipMemsetAsync(wsb + 1 * MB, 0, 4096, stream);  // sum_w + rsum only
        csqc_v3<<<128, 256, 0, stream>>>(C, csq, Chl);
        gram_s_v3<<<dim3(4, 4), 256, 0, stream>>>(Chl, csq, S, rsum);
        logsm<<<512, 512, 0, stream>>>(X, Chl, csq, assign, Abf, Xh, sum_w);
        wsum_v3<<<dim3(4, 4, 32), 256, 0, stream>>>(Abf, Xh, WSp);
        apply_update<<<512, 256, 0, stream>>>(C, M, S, rsum, WSp, sum_w, outC, outM);
    } else {
        hipMemsetAsync(d_ws, 0, 1 * MB + 8192, stream);
        csq_only<<<128, 256, 0, stream>>>(C, csq);
        logits_mfma<<<dim3(256, 4), 256, 0, stream>>>(X, C, csq, assign);
        softmax_rows<<<512, 256, 0, stream>>>(assign, sum_w, nullptr);
        gemm_wsum<<<dim3(8, 8, 32), 256, 0, stream>>>(assign, X, WS);
        repulse_update<<<512, 256, 0, stream>>>(C, M, csq, WS, sum_w, outC, outM);
    }
}